// Round 2
// baseline (10958.048 us; speedup 1.0000x reference)
//
#include <hip/hip_runtime.h>
#include <math.h>

#define H 512
#define V 5000
#define BB 128
#define SS 64
#define TT 52

typedef __attribute__((ext_vector_type(8))) short bf16x8;
typedef __attribute__((ext_vector_type(4))) float f32x4;

__device__ __forceinline__ unsigned short f2b(float f) {
    unsigned u = __float_as_uint(f);
    return (unsigned short)((u + 0x7fffu + ((u >> 16) & 1u)) >> 16);
}

// ---------------------------------------------------------------------------
// prep: Wbig_bf16 [2560,1024] = [ Wa | 0 ; W_hh | W_ih_x ], Wc_bf16 [2048,512]
// = W_ih_ctx, bbig = [ba ; b_ih+b_hh]
// ---------------------------------------------------------------------------
__global__ __launch_bounds__(256)
void prep_w(const float* __restrict__ Wa, const float* __restrict__ Whh,
            const float* __restrict__ Wih,
            const float* __restrict__ ba, const float* __restrict__ bih,
            const float* __restrict__ bhh,
            unsigned short* __restrict__ Wbig, unsigned short* __restrict__ Wc,
            float* __restrict__ bbig)
{
    const int stride = gridDim.x * blockDim.x;
    for (int idx = blockIdx.x * blockDim.x + threadIdx.x; idx < 2560 * 1024; idx += stride) {
        const int j = idx >> 10, k = idx & 1023;
        float v;
        if (j < H) v = (k < H) ? Wa[j * H + k] : 0.f;
        else { const int n = j - H; v = (k < H) ? Whh[n * H + k] : Wih[n * 2 * H + (k - H)]; }
        Wbig[idx] = f2b(v);
    }
    for (int idx = blockIdx.x * blockDim.x + threadIdx.x; idx < 2048 * 512; idx += stride) {
        const int n = idx >> 9, k = idx & 511;
        Wc[idx] = f2b(Wih[n * 2 * H + H + k]);
    }
    for (int j = blockIdx.x * blockDim.x + threadIdx.x; j < 2560; j += stride)
        bbig[j] = (j < H) ? ba[j] : bih[j - H] + bhh[j - H];
}

// ---------------------------------------------------------------------------
// Pre-gather teacher-forced inputs for all steps: xall[t*B+b][k] = emb[tok][k]
// ---------------------------------------------------------------------------
__global__ __launch_bounds__(256)
void gather_x(const float* __restrict__ emb, const int* __restrict__ tgt,
              unsigned short* __restrict__ xall)
{
    const int stride = gridDim.x * blockDim.x;
    for (int idx = blockIdx.x * blockDim.x + threadIdx.x; idx < TT * BB * H; idx += stride) {
        const int k = idx & 511;
        const int row = idx >> 9;
        const int t = row >> 7, b = row & 127;
        const int tok = (t == 0) ? 0 : tgt[b * TT + t - 1];
        xall[idx] = f2b(emb[(size_t)tok * H + k]);
    }
}

// ---------------------------------------------------------------------------
// Generic fp32 tiled GEMM (kept from round 1 for keys + logits).
// ---------------------------------------------------------------------------
template<int TM>
__global__ __launch_bounds__(256)
void gemm_nt(const float* __restrict__ A,
             const float* __restrict__ Emb,
             const int* __restrict__ tgt, int tstep, int concat_mode,
             const float* __restrict__ W, int ldw,
             const float* __restrict__ bias1, const float* __restrict__ bias2,
             float* __restrict__ C, int ldc,
             int M, int N, int K, int permute)
{
    constexpr int RT = TM / 16;
    __shared__ float As[16][TM + 4];
    __shared__ float Ws[16][68];
    const int tid = threadIdx.x;
    const int kl  = tid & 15;
    const int rg  = tid >> 4;
    const int r0  = blockIdx.y * TM;
    const int n0  = blockIdx.x * 64;
    const int tmb = (tid >> 4) * RT;
    const int tnb = (tid & 15) * 4;

    float acc[RT][4];
#pragma unroll
    for (int i = 0; i < RT; ++i)
#pragma unroll
        for (int j = 0; j < 4; ++j) acc[i][j] = 0.f;

    for (int k0 = 0; k0 < K; k0 += 16) {
        const int kg = k0 + kl;
#pragma unroll
        for (int i = 0; i < TM / 16; ++i) {
            const int m = rg + i * 16;
            As[kl][m] = A[(size_t)(r0 + m) * H + kg];
        }
#pragma unroll
        for (int i = 0; i < 4; ++i) {
            const int n = rg + i * 16;
            int nn = n0 + n; if (nn >= N) nn = N - 1;
            Ws[kl][n] = W[(size_t)nn * ldw + kg];
        }
        __syncthreads();
#pragma unroll
        for (int kk = 0; kk < 16; ++kk) {
            float av[RT], wv[4];
#pragma unroll
            for (int i = 0; i < RT; ++i) av[i] = As[kk][tmb + i];
#pragma unroll
            for (int j = 0; j < 4; ++j) wv[j] = Ws[kk][tnb + j];
#pragma unroll
            for (int i = 0; i < RT; ++i)
#pragma unroll
                for (int j = 0; j < 4; ++j) acc[i][j] += av[i] * wv[j];
        }
        __syncthreads();
    }

#pragma unroll
    for (int i = 0; i < RT; ++i) {
        const int r = r0 + tmb + i;
        const size_t crow = permute ? (size_t)((r & (BB - 1)) * TT + (r >> 7)) : (size_t)r;
#pragma unroll
        for (int j = 0; j < 4; ++j) {
            const int n = n0 + tnb + j;
            if (n < N) {
                float v = acc[i][j];
                if (bias1) v += bias1[n];
                if (bias2) v += bias2[n];
                C[crow * (size_t)ldc + n] = v;
            }
        }
    }
}

// ---------------------------------------------------------------------------
// Grid barrier (plain launch, 256 blocks = 256 CUs, all resident).
// ---------------------------------------------------------------------------
__device__ __forceinline__ void gbar(unsigned* cnt, unsigned* gen)
{
    __syncthreads();
    if (threadIdx.x == 0) {
        const unsigned g = __hip_atomic_load(gen, __ATOMIC_RELAXED, __HIP_MEMORY_SCOPE_AGENT);
        const unsigned old = __hip_atomic_fetch_add(cnt, 1u, __ATOMIC_ACQ_REL, __HIP_MEMORY_SCOPE_AGENT);
        if (old == 255u) {
            __hip_atomic_store(cnt, 0u, __ATOMIC_RELAXED, __HIP_MEMORY_SCOPE_AGENT);
            __hip_atomic_fetch_add(gen, 1u, __ATOMIC_ACQ_REL, __HIP_MEMORY_SCOPE_AGENT);
        } else {
            while (__hip_atomic_load(gen, __ATOMIC_ACQUIRE, __HIP_MEMORY_SCOPE_AGENT) == g)
                __builtin_amdgcn_s_sleep(2);
        }
    }
    __syncthreads();
}

struct PParams {
    const float* enc;
    const float* h0;
    const float* c0;
    const float* keys;
    const float* Va;
    const float* bv;
    const float* bbig;
    const unsigned short* Wbig;   // [2560][1024] bf16
    const unsigned short* Wc;     // [2048][512]  bf16
    const unsigned short* xall;   // [T*B][512]   bf16
    unsigned short* hbf;          // [B][512] bf16 (current h)
    unsigned short* ctxb;         // [B][512] bf16
    float* Yt;                    // [2560][128]  (qa | gates_hx), transposed
    float* hall;                  // [T*B][512] fp32
    float* attn;                  // -> d_out attention block [B][T][S]
    float* out_h;
    float* out_c;
    unsigned* cnt;
    unsigned* gen;
};

// ---------------------------------------------------------------------------
// Persistent recurrence kernel. Per step:
//   P1 (blocks 0..159, 16 cols each): Y^T = ([h|x] @ Wbig^T + bbig)^T  [MFMA]
//   P2 (blocks 0..127, 1 per b): attention -> ctx (bf16), attn weights
//   P3 (blocks 0..127, j-quadruples {4B..4B+3}x4 gates): ctx@Wc^T [MFMA]
//        + LSTM update; c lives in LDS across steps.
// ---------------------------------------------------------------------------
__global__ __launch_bounds__(256, 1)
void persist(PParams p)
{
    __shared__ unsigned short WA[16][1032];   // P1 weight slice (rows j0..j0+15)
    __shared__ unsigned short WC[16][520];    // P3 weight slice (c-order)
    __shared__ float gbuf[16][128];
    __shared__ float cs[4][128];
    __shared__ float qa_s[H];
    __shared__ float va_s[H];
    __shared__ float part[SS][4];
    __shared__ float wbuf[SS];

    const int tid  = threadIdx.x;
    const int beta = blockIdx.x;

    // ---- prologue: h0 -> bf16, stage weight slices, init c ----
    for (int i = beta * 256 + tid; i < BB * H; i += 256 * 256)
        p.hbf[i] = f2b(p.h0[i]);
    if (beta < 160) {
        const int j0 = beta * 16;
        for (int idx = tid; idx < 16 * 128; idx += 256) {
            const int r = idx >> 7, ch = idx & 127;
            *(uint4*)&WA[r][ch * 8] = *(const uint4*)&p.Wbig[(size_t)(j0 + r) * 1024 + ch * 8];
        }
    }
    if (beta < 128) {
        for (int idx = tid; idx < 16 * 64; idx += 256) {
            const int c = idx >> 6, ch = idx & 63;
            const int n = (c >> 2) * 512 + beta * 4 + (c & 3);
            *(uint4*)&WC[c][ch * 8] = *(const uint4*)&p.Wc[(size_t)n * 512 + ch * 8];
        }
        for (int idx = tid; idx < 512; idx += 256) {
            const int jj = idx >> 7, b = idx & 127;
            cs[jj][b] = p.c0[b * H + beta * 4 + jj];
        }
        for (int i = tid; i < H; i += 256) va_s[i] = p.Va[i];
    }
    gbar(p.cnt, p.gen);

    for (int t = 0; t < TT; ++t) {
        // ---------------- P1: Y^T rows j0..j0+15 ----------------
        if (beta < 160) {
            const int j0 = beta * 16;
            const int wv = tid >> 6, lane = tid & 63;
            const int r = lane & 15, g = lane >> 4;
            const int b0 = wv * 32, b1 = b0 + 16;
            const int ko = g * 8;
            f32x4 acc0 = {0.f, 0.f, 0.f, 0.f};
            f32x4 acc1 = {0.f, 0.f, 0.f, 0.f};
            const unsigned short* h0p = p.hbf + (size_t)(b0 + r) * H;
            const unsigned short* h1p = p.hbf + (size_t)(b1 + r) * H;
            const unsigned short* x0p = p.xall + ((size_t)t * BB + b0 + r) * H;
            const unsigned short* x1p = p.xall + ((size_t)t * BB + b1 + r) * H;
#pragma unroll
            for (int ks = 0; ks < 16; ++ks) {
                const int kk = ks * 32 + ko;
                bf16x8 bf = *(const bf16x8*)&WA[r][kk];
                acc0 = __builtin_amdgcn_mfma_f32_16x16x32_bf16(*(const bf16x8*)&h0p[kk], bf, acc0, 0, 0, 0);
                acc1 = __builtin_amdgcn_mfma_f32_16x16x32_bf16(*(const bf16x8*)&h1p[kk], bf, acc1, 0, 0, 0);
            }
#pragma unroll
            for (int ks = 0; ks < 16; ++ks) {
                const int kk = ks * 32 + ko;
                bf16x8 bf = *(const bf16x8*)&WA[r][512 + kk];
                acc0 = __builtin_amdgcn_mfma_f32_16x16x32_bf16(*(const bf16x8*)&x0p[kk], bf, acc0, 0, 0, 0);
                acc1 = __builtin_amdgcn_mfma_f32_16x16x32_bf16(*(const bf16x8*)&x1p[kk], bf, acc1, 0, 0, 0);
            }
            const float bb = p.bbig[j0 + r];
            float* yr = p.Yt + (size_t)(j0 + r) * BB;
#pragma unroll
            for (int i = 0; i < 4; ++i) {
                yr[b0 + g * 4 + i] = acc0[i] + bb;
                yr[b1 + g * 4 + i] = acc1[i] + bb;
            }
        }
        gbar(p.cnt, p.gen);

        // ---------------- P2: attention for b = beta ----------------
        if (beta < 128) {
            const int b = beta;
            qa_s[tid]       = p.Yt[(size_t)tid * BB + b];
            qa_s[tid + 256] = p.Yt[(size_t)(tid + 256) * BB + b];
            __syncthreads();
            const int s = tid >> 2, q = tid & 3;
            const float* kp = p.keys + ((size_t)b * SS + s) * H + q * 128;
            const float* qp = qa_s + q * 128;
            const float* vp = va_s + q * 128;
            float a2 = 0.f;
#pragma unroll 4
            for (int i = 0; i < 128; ++i)
                a2 += tanhf(qp[i] + kp[i]) * vp[i];
            part[s][q] = a2;
            __syncthreads();
            if (tid < 64) {
                float sc = part[tid][0] + part[tid][1] + part[tid][2] + part[tid][3] + p.bv[0];
                float m = sc;
                for (int o = 32; o; o >>= 1) m = fmaxf(m, __shfl_xor(m, o));
                const float e = expf(sc - m);
                float ss = e;
                for (int o = 32; o; o >>= 1) ss += __shfl_xor(ss, o);
                const float w = e / ss;
                wbuf[tid] = w;
                p.attn[((size_t)b * TT + t) * SS + tid] = w;
            }
            __syncthreads();
            for (int k = tid; k < H; k += 256) {
                const float* eb = p.enc + (size_t)b * SS * H + k;
                float a3 = 0.f;
#pragma unroll 8
                for (int s2 = 0; s2 < SS; ++s2) a3 += wbuf[s2] * eb[(size_t)s2 * H];
                p.ctxb[b * H + k] = f2b(a3);
            }
        }
        gbar(p.cnt, p.gen);

        // ---------------- P3: gates_ctx + LSTM ----------------
        if (beta < 128) {
            const int wv = tid >> 6, lane = tid & 63;
            const int r = lane & 15, g = lane >> 4;
            const int b0 = wv * 32, b1 = b0 + 16;
            const int ko = g * 8;
            f32x4 acc0 = {0.f, 0.f, 0.f, 0.f};
            f32x4 acc1 = {0.f, 0.f, 0.f, 0.f};
            const unsigned short* c0p = p.ctxb + (size_t)(b0 + r) * H;
            const unsigned short* c1p = p.ctxb + (size_t)(b1 + r) * H;
#pragma unroll
            for (int ks = 0; ks < 16; ++ks) {
                const int kk = ks * 32 + ko;
                bf16x8 bf = *(const bf16x8*)&WC[r][kk];
                acc0 = __builtin_amdgcn_mfma_f32_16x16x32_bf16(*(const bf16x8*)&c0p[kk], bf, acc0, 0, 0, 0);
                acc1 = __builtin_amdgcn_mfma_f32_16x16x32_bf16(*(const bf16x8*)&c1p[kk], bf, acc1, 0, 0, 0);
            }
            const int n = (r >> 2) * 512 + beta * 4 + (r & 3);
            const float* yr = p.Yt + (size_t)(512 + n) * BB;
#pragma unroll
            for (int i = 0; i < 4; ++i) {
                gbuf[r][b0 + g * 4 + i] = acc0[i] + yr[b0 + g * 4 + i];
                gbuf[r][b1 + g * 4 + i] = acc1[i] + yr[b1 + g * 4 + i];
            }
            __syncthreads();
            const int last = (t == TT - 1);
            for (int cell = tid; cell < 512; cell += 256) {
                const int jj = cell >> 7, b = cell & 127;
                const float ig = gbuf[jj][b];
                const float fg = gbuf[4 + jj][b];
                const float gg = gbuf[8 + jj][b];
                const float og = gbuf[12 + jj][b];
                const float co = cs[jj][b];
                const float sf = 1.f / (1.f + expf(-fg));
                const float si = 1.f / (1.f + expf(-ig));
                const float so = 1.f / (1.f + expf(-og));
                const float cn = sf * co + si * tanhf(gg);
                const float hn = so * tanhf(cn);
                cs[jj][b] = cn;
                const int j = beta * 4 + jj;
                p.hbf[b * H + j] = f2b(hn);
                p.hall[((size_t)t * BB + b) * H + j] = hn;
                if (last) { p.out_h[b * H + j] = hn; p.out_c[b * H + j] = cn; }
            }
        }
        gbar(p.cnt, p.gen);
    }
}

// ---------------------------------------------------------------------------
// In-place log-softmax over each row of 5000 logits.
// ---------------------------------------------------------------------------
__global__ __launch_bounds__(256)
void logsoftmax_rows(float* __restrict__ P)
{
    __shared__ float red[256];
    float* p = P + (size_t)blockIdx.x * V;
    const int tid = threadIdx.x;
    float m = -1e30f;
    for (int i = tid; i < V; i += 256) m = fmaxf(m, p[i]);
    red[tid] = m; __syncthreads();
    for (int sft = 128; sft; sft >>= 1) {
        if (tid < sft) red[tid] = fmaxf(red[tid], red[tid + sft]);
        __syncthreads();
    }
    m = red[0]; __syncthreads();
    float ssum = 0.f;
    for (int i = tid; i < V; i += 256) ssum += expf(p[i] - m);
    red[tid] = ssum; __syncthreads();
    for (int sft = 128; sft; sft >>= 1) {
        if (tid < sft) red[tid] += red[tid + sft];
        __syncthreads();
    }
    const float lse = m + logf(red[0]);
    for (int i = tid; i < V; i += 256) p[i] -= lse;
}

// ---------------------------------------------------------------------------
extern "C" void kernel_launch(void* const* d_in, const int* in_sizes, int n_in,
                              void* d_out, int out_size, void* d_ws, size_t ws_size,
                              hipStream_t stream)
{
    (void)in_sizes; (void)n_in; (void)out_size; (void)ws_size;
    const float* enc  = (const float*)d_in[0];
    const float* h0   = (const float*)d_in[1];
    const float* c0   = (const float*)d_in[2];
    const int*   tgt  = (const int*)  d_in[3];
    const float* emb  = (const float*)d_in[4];
    const float* Wa   = (const float*)d_in[5];
    const float* ba   = (const float*)d_in[6];
    const float* Ua   = (const float*)d_in[7];
    const float* bu   = (const float*)d_in[8];
    const float* Va   = (const float*)d_in[9];
    const float* bv   = (const float*)d_in[10];
    const float* Wih  = (const float*)d_in[11];
    const float* Whh  = (const float*)d_in[12];
    const float* bih  = (const float*)d_in[13];
    const float* bhh  = (const float*)d_in[14];
    const float* Wout = (const float*)d_in[15];
    const float* bout = (const float*)d_in[16];

    float* ws   = (float*)d_ws;
    float* keys = ws;                                   // 4,194,304 f
    float* bbig = keys + 4194304;                       // 2,560 f
    float* Yt   = bbig + 2560;                          // 327,680 f
    float* hall = Yt + 327680;                          // 3,407,872 f
    unsigned* bar = (unsigned*)(hall + 3407872);        // 64 u32
    unsigned short* Wbig = (unsigned short*)(bar + 64); // 2,621,440 u16
    unsigned short* Wc   = Wbig + 2621440;              // 1,048,576 u16
    unsigned short* xall = Wc + 1048576;                // 3,407,872 u16
    unsigned short* hbf  = xall + 3407872;              // 65,536 u16
    unsigned short* ctxb = hbf + 65536;                 // 65,536 u16

    float* out    = (float*)d_out;
    float* out_h  = out + (size_t)BB * TT * V;
    float* out_c  = out_h + BB * H;
    float* out_at = out_c + BB * H;

    hipMemsetAsync(bar, 0, 256, stream);

    prep_w<<<dim3(1024), dim3(256), 0, stream>>>(Wa, Whh, Wih, ba, bih, bhh, Wbig, Wc, bbig);
    gather_x<<<dim3(512), dim3(256), 0, stream>>>(emb, tgt, xall);

    // keys_proj = enc @ Ua^T + bu   [8192,512]  (fp32, exact)
    gemm_nt<64><<<dim3(8, 128), dim3(256), 0, stream>>>(
        enc, nullptr, nullptr, 0, 0, Ua, H, bu, nullptr, keys, H, BB * SS, H, H, 0);

    PParams pp;
    pp.enc = enc; pp.h0 = h0; pp.c0 = c0; pp.keys = keys; pp.Va = Va; pp.bv = bv;
    pp.bbig = bbig; pp.Wbig = Wbig; pp.Wc = Wc; pp.xall = xall;
    pp.hbf = hbf; pp.ctxb = ctxb; pp.Yt = Yt; pp.hall = hall;
    pp.attn = out_at; pp.out_h = out_h; pp.out_c = out_c;
    pp.cnt = bar; pp.gen = bar + 32;
    persist<<<dim3(256), dim3(256), 0, stream>>>(pp);

    // logits: hall[6656,512] @ Wout^T + bout -> out[b,t,:], then log-softmax
    gemm_nt<64><<<dim3(79, 104), dim3(256), 0, stream>>>(
        hall, nullptr, nullptr, 0, 0, Wout, H, bout, nullptr, out, V, TT * BB, V, H, 1);
    logsoftmax_rows<<<dim3(BB * TT), dim3(256), 0, stream>>>(out);
}

// Round 3
// 4693.263 us; speedup vs baseline: 2.3348x; 2.3348x over previous
//
#include <hip/hip_runtime.h>
#include <math.h>

#define H 512
#define V 5000
#define BB 128
#define SS 64
#define TT 52
#define NB 160   // persistent grid size (2560/16 col-groups)

typedef __attribute__((ext_vector_type(8))) short bf16x8;
typedef __attribute__((ext_vector_type(4))) float f32x4;

__device__ __forceinline__ unsigned short f2b(float f) {
    unsigned u = __float_as_uint(f);
    return (unsigned short)((u + 0x7fffu + ((u >> 16) & 1u)) >> 16);
}
__device__ __forceinline__ float b2f(unsigned short u) {
    return __uint_as_float((unsigned)u << 16);
}
__device__ __forceinline__ float ftanh(float x) {
    return 1.f - 2.f / (1.f + __expf(2.f * x));
}
__device__ __forceinline__ float fsig(float x) {
    return 1.f / (1.f + __expf(-x));
}

// ---------------------------------------------------------------------------
// prep: Wbig_bf16 [2560,1024] = [ Wa | 0 ; W_hh | W_ih_x ], Wc_bf16 [2048,512]
// = W_ih_ctx, bbig = [ba ; b_ih+b_hh], plus bf16 copies of Ua, Wout, enc.
// ---------------------------------------------------------------------------
__global__ __launch_bounds__(256)
void prep_w(const float* __restrict__ Wa, const float* __restrict__ Whh,
            const float* __restrict__ Wih,
            const float* __restrict__ ba, const float* __restrict__ bih,
            const float* __restrict__ bhh,
            const float* __restrict__ Ua, const float* __restrict__ Wout,
            const float* __restrict__ enc,
            unsigned short* __restrict__ Wbig, unsigned short* __restrict__ Wc,
            unsigned short* __restrict__ Uab, unsigned short* __restrict__ Woutb,
            unsigned short* __restrict__ encb, float* __restrict__ bbig)
{
    const int stride = gridDim.x * blockDim.x;
    const int t0 = blockIdx.x * blockDim.x + threadIdx.x;
    for (int idx = t0; idx < 2560 * 1024; idx += stride) {
        const int j = idx >> 10, k = idx & 1023;
        float v;
        if (j < H) v = (k < H) ? Wa[j * H + k] : 0.f;
        else { const int n = j - H; v = (k < H) ? Whh[n * H + k] : Wih[n * 2 * H + (k - H)]; }
        Wbig[idx] = f2b(v);
    }
    for (int idx = t0; idx < 2048 * 512; idx += stride) {
        const int n = idx >> 9, k = idx & 511;
        Wc[idx] = f2b(Wih[n * 2 * H + H + k]);
    }
    for (int idx = t0; idx < 512 * 512; idx += stride)   Uab[idx]   = f2b(Ua[idx]);
    for (int idx = t0; idx < V * 512; idx += stride)     Woutb[idx] = f2b(Wout[idx]);
    for (int idx = t0; idx < BB * SS * H; idx += stride) encb[idx]  = f2b(enc[idx]);
    for (int j = t0; j < 2560; j += stride)
        bbig[j] = (j < H) ? ba[j] : bih[j - H] + bhh[j - H];
}

// ---------------------------------------------------------------------------
// Pre-gather teacher-forced inputs: xall[t*B+b][k] = emb[tok(t,b)][k] (bf16)
// ---------------------------------------------------------------------------
__global__ __launch_bounds__(256)
void gather_x(const float* __restrict__ emb, const int* __restrict__ tgt,
              unsigned short* __restrict__ xall)
{
    const int stride = gridDim.x * blockDim.x;
    for (int idx = blockIdx.x * blockDim.x + threadIdx.x; idx < TT * BB * H; idx += stride) {
        const int k = idx & 511;
        const int row = idx >> 9;
        const int t = row >> 7, b = row & 127;
        const int tok = (t == 0) ? 0 : tgt[b * TT + t - 1];
        xall[idx] = f2b(emb[(size_t)tok * H + k]);
    }
}

// ---------------------------------------------------------------------------
// bf16 MFMA NT-GEMM, K=512 fixed: C[m,n] = A[m,:]·B[n,:] + bias[n].
// 128x128 tile, 4 waves in 2x2 quadrants, BK=64 LDS staging.
// OUT_BF16: store bf16 into Cb (stride N). Else fp32 into Cf; PERMUTE maps
// row r=t*BB+b -> b*TT+t (logits layout).
// ---------------------------------------------------------------------------
template<int OUT_BF16, int PERMUTE>
__global__ __launch_bounds__(256, 2)
void gemm_mfma(const unsigned short* __restrict__ A,
               const unsigned short* __restrict__ B,
               const float* __restrict__ bias,
               float* __restrict__ Cf, unsigned short* __restrict__ Cb,
               int M, int N)
{
    __shared__ unsigned short As[128][72];
    __shared__ unsigned short Bs[128][72];
    const int tid = threadIdx.x;
    const int m0 = blockIdx.y * 128, n0 = blockIdx.x * 128;
    const int lane = tid & 63, wv = tid >> 6;
    const int qm = (wv >> 1) * 64, qn = (wv & 1) * 64;
    const int fr = lane & 15, fg = lane >> 4;
    f32x4 acc[4][4];
#pragma unroll
    for (int i = 0; i < 4; ++i)
#pragma unroll
        for (int j = 0; j < 4; ++j) acc[i][j] = (f32x4){0.f, 0.f, 0.f, 0.f};

    const int srow = tid >> 3, sc = (tid & 7) * 8;
    for (int k0 = 0; k0 < H; k0 += 64) {
#pragma unroll
        for (int u = 0; u < 4; ++u) {
            const int row = srow + u * 32;
            *(uint4*)&As[row][sc] = *(const uint4*)&A[(size_t)(m0 + row) * H + k0 + sc];
            int nr = n0 + row; if (nr > N - 1) nr = N - 1;
            *(uint4*)&Bs[row][sc] = *(const uint4*)&B[(size_t)nr * H + k0 + sc];
        }
        __syncthreads();
#pragma unroll
        for (int ks = 0; ks < 2; ++ks) {
            const int kk = ks * 32 + fg * 8;
            bf16x8 av[4], bv[4];
#pragma unroll
            for (int i = 0; i < 4; ++i) {
                av[i] = *(const bf16x8*)&As[qm + i * 16 + fr][kk];
                bv[i] = *(const bf16x8*)&Bs[qn + i * 16 + fr][kk];
            }
#pragma unroll
            for (int i = 0; i < 4; ++i)
#pragma unroll
                for (int j = 0; j < 4; ++j)
                    acc[i][j] = __builtin_amdgcn_mfma_f32_16x16x32_bf16(av[i], bv[j], acc[i][j], 0, 0, 0);
        }
        __syncthreads();
    }
#pragma unroll
    for (int i = 0; i < 4; ++i) {
        const int r0 = m0 + qm + i * 16 + fg * 4;
#pragma unroll
        for (int j = 0; j < 4; ++j) {
            const int col = n0 + qn + j * 16 + fr;
            if (col < N) {
                const float bi = bias[col];
#pragma unroll
                for (int v = 0; v < 4; ++v) {
                    const int r = r0 + v;
                    const float val = acc[i][j][v] + bi;
                    if (OUT_BF16) {
                        Cb[(size_t)r * N + col] = f2b(val);
                    } else {
                        const size_t orow = PERMUTE ? ((size_t)(r & (BB - 1)) * TT + (r >> 7))
                                                    : (size_t)r;
                        Cf[orow * (size_t)N + col] = val;
                    }
                }
            }
        }
    }
}

// ---------------------------------------------------------------------------
// Flag-based grid barrier: per-block padded arrival flags + one gen word.
// Arrival stores are parallel (distinct lines); block 0 aggregates; waiters
// poll gen only. Agent-scope acquire loads invalidate the CU's L1, giving
// cross-XCD visibility (same scheme validated in round 2, minus the RMW).
// ---------------------------------------------------------------------------
__device__ __forceinline__ void gbar(unsigned* flags, unsigned* gen, unsigned step)
{
    __syncthreads();
    if (blockIdx.x == 0) {
        for (int i = threadIdx.x; i < NB - 1; i += 256) {
            while (__hip_atomic_load(&flags[(i + 1) * 32], __ATOMIC_ACQUIRE,
                                     __HIP_MEMORY_SCOPE_AGENT) < step)
                __builtin_amdgcn_s_sleep(1);
        }
        __syncthreads();
        if (threadIdx.x == 0)
            __hip_atomic_store(gen, step, __ATOMIC_RELEASE, __HIP_MEMORY_SCOPE_AGENT);
    } else {
        if (threadIdx.x == 0) {
            __hip_atomic_store(&flags[blockIdx.x * 32], step, __ATOMIC_RELEASE,
                               __HIP_MEMORY_SCOPE_AGENT);
            while (__hip_atomic_load(gen, __ATOMIC_ACQUIRE,
                                     __HIP_MEMORY_SCOPE_AGENT) < step)
                __builtin_amdgcn_s_sleep(1);
        }
        __syncthreads();
    }
}

struct PParams {
    const float* h0;
    const float* c0;
    const unsigned short* keysb;  // [B*S][512] bf16
    const unsigned short* encb;   // [B*S][512] bf16
    const float* Va;
    const float* bv;
    const float* bbig;
    const unsigned short* Wbig;   // [2560][1024] bf16
    const unsigned short* Wc;     // [2048][512]  bf16
    const unsigned short* xall;   // [T*B][512]   bf16
    unsigned short* hbf;          // [B][512] bf16 (current h)
    unsigned short* ctxb;         // [B][512] bf16
    float* Yt;                    // [2560][128]  (qa | gates_hx), transposed
    unsigned short* hallb;        // [T*B][512] bf16
    float* attn;                  // -> d_out attention block [B][T][S]
    float* out_h;
    float* out_c;
    unsigned* flags;
    unsigned* gen;
};

// ---------------------------------------------------------------------------
// Persistent recurrence kernel (160 blocks, all resident). Per step:
//   P1 (blocks 0..159, 16 cols each): Y^T = ([h|x] @ Wbig^T + bbig)^T [MFMA]
//   P2 (blocks 0..127, 1 per b): attention -> ctx (bf16), attn weights
//   P3 (blocks 0..127): ctx@Wc^T [MFMA] + LSTM; c lives in LDS across steps.
// ---------------------------------------------------------------------------
__global__ __launch_bounds__(256, 1)
void persist(PParams p)
{
    __shared__ unsigned short WA[16][1032];
    __shared__ unsigned short WC[16][520];
    __shared__ float gbuf[16][128];
    __shared__ float cs[4][128];
    __shared__ float qa_s[H];
    __shared__ float va_s[H];
    __shared__ float part[SS][4];
    __shared__ float wbuf[SS];

    const int tid  = threadIdx.x;
    const int beta = blockIdx.x;
    unsigned bs = 1;

    // ---- prologue: h0 -> bf16, stage weight slices, init c ----
    for (int i = beta * 256 + tid; i < BB * H; i += NB * 256)
        p.hbf[i] = f2b(p.h0[i]);
    {
        const int j0 = beta * 16;
        for (int idx = tid; idx < 16 * 128; idx += 256) {
            const int r = idx >> 7, ch = idx & 127;
            *(uint4*)&WA[r][ch * 8] = *(const uint4*)&p.Wbig[(size_t)(j0 + r) * 1024 + ch * 8];
        }
    }
    if (beta < 128) {
        for (int idx = tid; idx < 16 * 64; idx += 256) {
            const int c = idx >> 6, ch = idx & 63;
            const int n = (c >> 2) * 512 + beta * 4 + (c & 3);
            *(uint4*)&WC[c][ch * 8] = *(const uint4*)&p.Wc[(size_t)n * 512 + ch * 8];
        }
        for (int idx = tid; idx < 512; idx += 256) {
            const int jj = idx >> 7, b = idx & 127;
            cs[jj][b] = p.c0[b * H + beta * 4 + jj];
        }
        for (int i = tid; i < H; i += 256) va_s[i] = p.Va[i];
    }
    gbar(p.flags, p.gen, bs++);

    for (int t = 0; t < TT; ++t) {
        // ---------------- P1: Y^T rows j0..j0+15 ----------------
        {
            const int j0 = beta * 16;
            const int wv = tid >> 6, lane = tid & 63;
            const int r = lane & 15, g = lane >> 4;
            const int b0 = wv * 32, b1 = b0 + 16;
            const int ko = g * 8;
            f32x4 acc0 = {0.f, 0.f, 0.f, 0.f};
            f32x4 acc1 = {0.f, 0.f, 0.f, 0.f};
            const unsigned short* h0p = p.hbf + (size_t)(b0 + r) * H;
            const unsigned short* h1p = p.hbf + (size_t)(b1 + r) * H;
            const unsigned short* x0p = p.xall + ((size_t)t * BB + b0 + r) * H;
            const unsigned short* x1p = p.xall + ((size_t)t * BB + b1 + r) * H;
#pragma unroll
            for (int ks = 0; ks < 16; ++ks) {
                const int kk = ks * 32 + ko;
                bf16x8 bf = *(const bf16x8*)&WA[r][kk];
                acc0 = __builtin_amdgcn_mfma_f32_16x16x32_bf16(*(const bf16x8*)&h0p[kk], bf, acc0, 0, 0, 0);
                acc1 = __builtin_amdgcn_mfma_f32_16x16x32_bf16(*(const bf16x8*)&h1p[kk], bf, acc1, 0, 0, 0);
            }
#pragma unroll
            for (int ks = 0; ks < 16; ++ks) {
                const int kk = ks * 32 + ko;
                bf16x8 bf = *(const bf16x8*)&WA[r][512 + kk];
                acc0 = __builtin_amdgcn_mfma_f32_16x16x32_bf16(*(const bf16x8*)&x0p[kk], bf, acc0, 0, 0, 0);
                acc1 = __builtin_amdgcn_mfma_f32_16x16x32_bf16(*(const bf16x8*)&x1p[kk], bf, acc1, 0, 0, 0);
            }
            const float bb = p.bbig[j0 + r];
            float* yr = p.Yt + (size_t)(j0 + r) * BB;
#pragma unroll
            for (int i = 0; i < 4; ++i) {
                yr[b0 + g * 4 + i] = acc0[i] + bb;
                yr[b1 + g * 4 + i] = acc1[i] + bb;
            }
        }
        gbar(p.flags, p.gen, bs++);

        // ---------------- P2: attention for b = beta ----------------
        if (beta < 128) {
            const int b = beta;
            qa_s[tid]       = p.Yt[(size_t)tid * BB + b];
            qa_s[tid + 256] = p.Yt[(size_t)(tid + 256) * BB + b];
            __syncthreads();
            const int s = tid >> 2, q = tid & 3;
            const unsigned short* kp = p.keysb + ((size_t)b * SS + s) * H + q * 128;
            const float* qp = qa_s + q * 128;
            const float* vp = va_s + q * 128;
            float a2 = 0.f;
#pragma unroll 4
            for (int i = 0; i < 128; ++i)
                a2 += ftanh(qp[i] + b2f(kp[i])) * vp[i];
            part[s][q] = a2;
            __syncthreads();
            if (tid < 64) {
                float sc = part[tid][0] + part[tid][1] + part[tid][2] + part[tid][3] + p.bv[0];
                float m = sc;
                for (int o = 32; o; o >>= 1) m = fmaxf(m, __shfl_xor(m, o));
                const float e = __expf(sc - m);
                float ss = e;
                for (int o = 32; o; o >>= 1) ss += __shfl_xor(ss, o);
                const float w = e / ss;
                wbuf[tid] = w;
                p.attn[((size_t)b * TT + t) * SS + tid] = w;
            }
            __syncthreads();
            for (int k = tid; k < H; k += 256) {
                const unsigned short* eb = p.encb + (size_t)b * SS * H + k;
                float a3 = 0.f;
#pragma unroll 8
                for (int s2 = 0; s2 < SS; ++s2) a3 += wbuf[s2] * b2f(eb[(size_t)s2 * H]);
                p.ctxb[b * H + k] = f2b(a3);
            }
        }
        gbar(p.flags, p.gen, bs++);

        // ---------------- P3: gates_ctx + LSTM ----------------
        if (beta < 128) {
            const int wv = tid >> 6, lane = tid & 63;
            const int r = lane & 15, g = lane >> 4;
            const int b0 = wv * 32, b1 = b0 + 16;
            const int ko = g * 8;
            f32x4 acc0 = {0.f, 0.f, 0.f, 0.f};
            f32x4 acc1 = {0.f, 0.f, 0.f, 0.f};
            const unsigned short* c0p = p.ctxb + (size_t)(b0 + r) * H;
            const unsigned short* c1p = p.ctxb + (size_t)(b1 + r) * H;
#pragma unroll
            for (int ks = 0; ks < 16; ++ks) {
                const int kk = ks * 32 + ko;
                bf16x8 bf = *(const bf16x8*)&WC[r][kk];
                acc0 = __builtin_amdgcn_mfma_f32_16x16x32_bf16(*(const bf16x8*)&c0p[kk], bf, acc0, 0, 0, 0);
                acc1 = __builtin_amdgcn_mfma_f32_16x16x32_bf16(*(const bf16x8*)&c1p[kk], bf, acc1, 0, 0, 0);
            }
            const int n = (r >> 2) * 512 + beta * 4 + (r & 3);
            const float* yr = p.Yt + (size_t)(512 + n) * BB;
#pragma unroll
            for (int i = 0; i < 4; ++i) {
                gbuf[r][b0 + g * 4 + i] = acc0[i] + yr[b0 + g * 4 + i];
                gbuf[r][b1 + g * 4 + i] = acc1[i] + yr[b1 + g * 4 + i];
            }
            __syncthreads();
            const int last = (t == TT - 1);
            for (int cell = tid; cell < 512; cell += 256) {
                const int jj = cell >> 7, b = cell & 127;
                const float ig = gbuf[jj][b];
                const float fg = gbuf[4 + jj][b];
                const float gg = gbuf[8 + jj][b];
                const float og = gbuf[12 + jj][b];
                const float co = cs[jj][b];
                const float cn = fsig(fg) * co + fsig(ig) * ftanh(gg);
                const float hn = fsig(og) * ftanh(cn);
                cs[jj][b] = cn;
                const int j = beta * 4 + jj;
                p.hbf[b * H + j] = f2b(hn);
                p.hallb[((size_t)t * BB + b) * H + j] = f2b(hn);
                if (last) { p.out_h[b * H + j] = hn; p.out_c[b * H + j] = cn; }
            }
        }
        gbar(p.flags, p.gen, bs++);
    }
}

// ---------------------------------------------------------------------------
// In-place log-softmax over each row of 5000 logits.
// ---------------------------------------------------------------------------
__global__ __launch_bounds__(256)
void logsoftmax_rows(float* __restrict__ P)
{
    __shared__ float red[256];
    float* p = P + (size_t)blockIdx.x * V;
    const int tid = threadIdx.x;
    float m = -1e30f;
    for (int i = tid; i < V; i += 256) m = fmaxf(m, p[i]);
    red[tid] = m; __syncthreads();
    for (int sft = 128; sft; sft >>= 1) {
        if (tid < sft) red[tid] = fmaxf(red[tid], red[tid + sft]);
        __syncthreads();
    }
    m = red[0]; __syncthreads();
    float ssum = 0.f;
    for (int i = tid; i < V; i += 256) ssum += __expf(p[i] - m);
    red[tid] = ssum; __syncthreads();
    for (int sft = 128; sft; sft >>= 1) {
        if (tid < sft) red[tid] += red[tid + sft];
        __syncthreads();
    }
    const float lse = m + __logf(red[0]);
    for (int i = tid; i < V; i += 256) p[i] -= lse;
}

// ---------------------------------------------------------------------------
extern "C" void kernel_launch(void* const* d_in, const int* in_sizes, int n_in,
                              void* d_out, int out_size, void* d_ws, size_t ws_size,
                              hipStream_t stream)
{
    (void)in_sizes; (void)n_in; (void)out_size; (void)ws_size;
    const float* enc  = (const float*)d_in[0];
    const float* h0   = (const float*)d_in[1];
    const float* c0   = (const float*)d_in[2];
    const int*   tgt  = (const int*)  d_in[3];
    const float* emb  = (const float*)d_in[4];
    const float* Wa   = (const float*)d_in[5];
    const float* ba   = (const float*)d_in[6];
    const float* Ua   = (const float*)d_in[7];
    const float* bu   = (const float*)d_in[8];
    const float* Va   = (const float*)d_in[9];
    const float* bv   = (const float*)d_in[10];
    const float* Wih  = (const float*)d_in[11];
    const float* Whh  = (const float*)d_in[12];
    const float* bih  = (const float*)d_in[13];
    const float* bhh  = (const float*)d_in[14];
    const float* Wout = (const float*)d_in[15];
    const float* bout = (const float*)d_in[16];

    float* ws = (float*)d_ws;
    float* Yt   = ws;                                      // 327,680 f32
    float* bbig = Yt + 327680;                             // 2,560 f32
    unsigned* flags = (unsigned*)(bbig + 2560);            // 5,184 u32 (incl gen)
    unsigned short* Wbig  = (unsigned short*)(flags + 5184);   // 2,621,440 u16
    unsigned short* Wc    = Wbig + 2621440;                // 1,048,576
    unsigned short* Uab   = Wc + 1048576;                  // 262,144
    unsigned short* Woutb = Uab + 262144;                  // 2,560,000
    unsigned short* encb  = Woutb + 2560000;               // 4,194,304
    unsigned short* keysb = encb + 4194304;                // 4,194,304
    unsigned short* xall  = keysb + 4194304;               // 3,407,872
    unsigned short* hallb = xall + 3407872;                // 3,407,872
    unsigned short* hbf   = hallb + 3407872;               // 65,536
    unsigned short* ctxb  = hbf + 65536;                   // 65,536

    float* out    = (float*)d_out;
    float* out_h  = out + (size_t)BB * TT * V;
    float* out_c  = out_h + BB * H;
    float* out_at = out_c + BB * H;

    hipMemsetAsync(flags, 0, 5184 * sizeof(unsigned), stream);

    prep_w<<<dim3(2048), dim3(256), 0, stream>>>(
        Wa, Whh, Wih, ba, bih, bhh, Ua, Wout, enc, Wbig, Wc, Uab, Woutb, encb, bbig);
    gather_x<<<dim3(512), dim3(256), 0, stream>>>(emb, tgt, xall);

    // keys_proj = enc @ Ua^T + bu  -> bf16 [8192,512]
    gemm_mfma<1, 0><<<dim3(4, 64), dim3(256), 0, stream>>>(
        encb, Uab, bu, nullptr, keysb, BB * SS, H);

    PParams pp;
    pp.h0 = h0; pp.c0 = c0; pp.keysb = keysb; pp.encb = encb;
    pp.Va = Va; pp.bv = bv; pp.bbig = bbig;
    pp.Wbig = Wbig; pp.Wc = Wc; pp.xall = xall;
    pp.hbf = hbf; pp.ctxb = ctxb; pp.Yt = Yt; pp.hallb = hallb;
    pp.attn = out_at; pp.out_h = out_h; pp.out_c = out_c;
    pp.flags = flags; pp.gen = flags + 5120;
    persist<<<dim3(NB), dim3(256), 0, stream>>>(pp);

    // logits: hallb[6656,512] @ Woutb^T + bout -> out[b,t,:], then log-softmax
    gemm_mfma<0, 1><<<dim3(40, 52), dim3(256), 0, stream>>>(
        hallb, Woutb, bout, out, nullptr, TT * BB, V);
    logsoftmax_rows<<<dim3(BB * TT), dim3(256), 0, stream>>>(out);
}

// Round 4
// 2911.293 us; speedup vs baseline: 3.7640x; 1.6121x over previous
//
#include <hip/hip_runtime.h>
#include <math.h>

#define H 512
#define V 5000
#define BB 128
#define SS 64
#define TT 52
#define NB 160   // persistent grid size (2560/16 col-groups)

typedef __attribute__((ext_vector_type(8))) short bf16x8;
typedef __attribute__((ext_vector_type(4))) float f32x4;

__device__ __forceinline__ unsigned short f2b(float f) {
    unsigned u = __float_as_uint(f);
    return (unsigned short)((u + 0x7fffu + ((u >> 16) & 1u)) >> 16);
}
__device__ __forceinline__ float b2f(unsigned short u) {
    return __uint_as_float((unsigned)u << 16);
}
__device__ __forceinline__ float ftanh(float x) {
    return 1.f - 2.f / (1.f + __expf(2.f * x));
}
__device__ __forceinline__ float fsig(float x) {
    return 1.f / (1.f + __expf(-x));
}

// ---------------------------------------------------------------------------
// prep: Wbig_bf16 [2560,1024] = [ Wa | 0 ; W_hh | W_ih_x ], Wc_bf16 [2048,512]
// = W_ih_ctx, bbig = [ba ; b_ih+b_hh], plus bf16 copies of Ua, Wout, enc.
// ---------------------------------------------------------------------------
__global__ __launch_bounds__(256)
void prep_w(const float* __restrict__ Wa, const float* __restrict__ Whh,
            const float* __restrict__ Wih,
            const float* __restrict__ ba, const float* __restrict__ bih,
            const float* __restrict__ bhh,
            const float* __restrict__ Ua, const float* __restrict__ Wout,
            const float* __restrict__ enc,
            unsigned short* __restrict__ Wbig, unsigned short* __restrict__ Wc,
            unsigned short* __restrict__ Uab, unsigned short* __restrict__ Woutb,
            unsigned short* __restrict__ encb, float* __restrict__ bbig)
{
    const int stride = gridDim.x * blockDim.x;
    const int t0 = blockIdx.x * blockDim.x + threadIdx.x;
    for (int idx = t0; idx < 2560 * 1024; idx += stride) {
        const int j = idx >> 10, k = idx & 1023;
        float v;
        if (j < H) v = (k < H) ? Wa[j * H + k] : 0.f;
        else { const int n = j - H; v = (k < H) ? Whh[n * H + k] : Wih[n * 2 * H + (k - H)]; }
        Wbig[idx] = f2b(v);
    }
    for (int idx = t0; idx < 2048 * 512; idx += stride) {
        const int n = idx >> 9, k = idx & 511;
        Wc[idx] = f2b(Wih[n * 2 * H + H + k]);
    }
    for (int idx = t0; idx < 512 * 512; idx += stride)   Uab[idx]   = f2b(Ua[idx]);
    for (int idx = t0; idx < V * 512; idx += stride)     Woutb[idx] = f2b(Wout[idx]);
    for (int idx = t0; idx < BB * SS * H; idx += stride) encb[idx]  = f2b(enc[idx]);
    for (int j = t0; j < 2560; j += stride)
        bbig[j] = (j < H) ? ba[j] : bih[j - H] + bhh[j - H];
}

// ---------------------------------------------------------------------------
// Pre-gather teacher-forced inputs: xall[t*B+b][k] = emb[tok(t,b)][k] (bf16)
// ---------------------------------------------------------------------------
__global__ __launch_bounds__(256)
void gather_x(const float* __restrict__ emb, const int* __restrict__ tgt,
              unsigned short* __restrict__ xall)
{
    const int stride = gridDim.x * blockDim.x;
    for (int idx = blockIdx.x * blockDim.x + threadIdx.x; idx < TT * BB * H; idx += stride) {
        const int k = idx & 511;
        const int row = idx >> 9;
        const int t = row >> 7, b = row & 127;
        const int tok = (t == 0) ? 0 : tgt[b * TT + t - 1];
        xall[idx] = f2b(emb[(size_t)tok * H + k]);
    }
}

// ---------------------------------------------------------------------------
// bf16 MFMA NT-GEMM, K=512 fixed: C[m,n] = A[m,:]·B[n,:] + bias[n].
// 128x128 tile, 4 waves in 2x2 quadrants, BK=64 LDS staging.
// ---------------------------------------------------------------------------
template<int OUT_BF16, int PERMUTE>
__global__ __launch_bounds__(256, 2)
void gemm_mfma(const unsigned short* __restrict__ A,
               const unsigned short* __restrict__ B,
               const float* __restrict__ bias,
               float* __restrict__ Cf, unsigned short* __restrict__ Cb,
               int M, int N)
{
    __shared__ unsigned short As[128][72];
    __shared__ unsigned short Bs[128][72];
    const int tid = threadIdx.x;
    const int m0 = blockIdx.y * 128, n0 = blockIdx.x * 128;
    const int lane = tid & 63, wv = tid >> 6;
    const int qm = (wv >> 1) * 64, qn = (wv & 1) * 64;
    const int fr = lane & 15, fg = lane >> 4;
    f32x4 acc[4][4];
#pragma unroll
    for (int i = 0; i < 4; ++i)
#pragma unroll
        for (int j = 0; j < 4; ++j) acc[i][j] = (f32x4){0.f, 0.f, 0.f, 0.f};

    const int srow = tid >> 3, sc = (tid & 7) * 8;
    for (int k0 = 0; k0 < H; k0 += 64) {
#pragma unroll
        for (int u = 0; u < 4; ++u) {
            const int row = srow + u * 32;
            *(uint4*)&As[row][sc] = *(const uint4*)&A[(size_t)(m0 + row) * H + k0 + sc];
            int nr = n0 + row; if (nr > N - 1) nr = N - 1;
            *(uint4*)&Bs[row][sc] = *(const uint4*)&B[(size_t)nr * H + k0 + sc];
        }
        __syncthreads();
#pragma unroll
        for (int ks = 0; ks < 2; ++ks) {
            const int kk = ks * 32 + fg * 8;
            bf16x8 av[4], bv[4];
#pragma unroll
            for (int i = 0; i < 4; ++i) {
                av[i] = *(const bf16x8*)&As[qm + i * 16 + fr][kk];
                bv[i] = *(const bf16x8*)&Bs[qn + i * 16 + fr][kk];
            }
#pragma unroll
            for (int i = 0; i < 4; ++i)
#pragma unroll
                for (int j = 0; j < 4; ++j)
                    acc[i][j] = __builtin_amdgcn_mfma_f32_16x16x32_bf16(av[i], bv[j], acc[i][j], 0, 0, 0);
        }
        __syncthreads();
    }
#pragma unroll
    for (int i = 0; i < 4; ++i) {
        const int r0 = m0 + qm + i * 16 + fg * 4;
#pragma unroll
        for (int j = 0; j < 4; ++j) {
            const int col = n0 + qn + j * 16 + fr;
            if (col < N) {
                const float bi = bias[col];
#pragma unroll
                for (int v = 0; v < 4; ++v) {
                    const int r = r0 + v;
                    const float val = acc[i][j][v] + bi;
                    if (OUT_BF16) {
                        Cb[(size_t)r * N + col] = f2b(val);
                    } else {
                        const size_t orow = PERMUTE ? ((size_t)(r & (BB - 1)) * TT + (r >> 7))
                                                    : (size_t)r;
                        Cf[orow * (size_t)N + col] = val;
                    }
                }
            }
        }
    }
}

// ---------------------------------------------------------------------------
// Grid barrier v3: RELAXED polls (no per-iteration cache invalidates) +
// ONE release fence before arrival and ONE acquire fence after observation.
// This is the cooperative-groups grid.sync idiom; round-3's ACQUIRE-per-poll
// emitted L1/L2 invalidates every poll iteration (~29us/barrier).
// ---------------------------------------------------------------------------
__device__ __forceinline__ void gbar(unsigned* flags, unsigned* gen, unsigned step)
{
    __syncthreads();   // all block threads done with phase (incl. vmcnt drain)
    if (blockIdx.x == 0) {
        for (int i = threadIdx.x; i < NB - 1; i += 256) {
            while (__hip_atomic_load(&flags[(i + 1) * 32], __ATOMIC_RELAXED,
                                     __HIP_MEMORY_SCOPE_AGENT) < step)
                __builtin_amdgcn_s_sleep(1);
        }
        __syncthreads();  // all flags observed
        if (threadIdx.x == 0) {
            // release: publish block 0's phase writes; acquire: see producers'
            __builtin_amdgcn_fence(__ATOMIC_ACQ_REL, "agent");
            __hip_atomic_store(gen, step, __ATOMIC_RELAXED, __HIP_MEMORY_SCOPE_AGENT);
        }
        __syncthreads();  // no block-0 thread reads before the fence above
    } else {
        if (threadIdx.x == 0) {
            __builtin_amdgcn_fence(__ATOMIC_RELEASE, "agent");  // publish writes
            __hip_atomic_store(&flags[blockIdx.x * 32], step, __ATOMIC_RELAXED,
                               __HIP_MEMORY_SCOPE_AGENT);
            while (__hip_atomic_load(gen, __ATOMIC_RELAXED,
                                     __HIP_MEMORY_SCOPE_AGENT) < step)
                __builtin_amdgcn_s_sleep(1);
            __builtin_amdgcn_fence(__ATOMIC_ACQUIRE, "agent"); // invalidate stale
        }
        __syncthreads();
    }
}

struct PParams {
    const float* h0;
    const float* c0;
    const unsigned short* keysb;  // [B*S][512] bf16
    const unsigned short* encb;   // [B*S][512] bf16
    const float* Va;
    const float* bv;
    const float* bbig;
    const unsigned short* Wbig;   // [2560][1024] bf16
    const unsigned short* Wc;     // [2048][512]  bf16
    const unsigned short* xall;   // [T*B][512]   bf16
    unsigned short* hbf;          // [B][512] bf16 (current h)
    unsigned short* ctxb;         // [B][512] bf16
    float* Yt;                    // [2560][128]  (qa | gates_hx), transposed
    unsigned short* hallb;        // [T*B][512] bf16
    float* attn;                  // -> d_out attention block [B][T][S]
    float* out_h;
    float* out_c;
    unsigned* flags;
    unsigned* gen;
};

// ---------------------------------------------------------------------------
// Persistent recurrence kernel (160 blocks, all resident). Per step:
//   P1 (blocks 0..159, 16 cols each): Y^T = ([h|x] @ Wbig^T + bbig)^T [MFMA]
//   P2 (blocks 0..127, 1 per b): attention -> ctx (bf16), attn weights
//   P3 (blocks 0..127): ctx@Wc^T [MFMA] + LSTM; c lives in LDS across steps.
// ---------------------------------------------------------------------------
__global__ __launch_bounds__(256, 1)
void persist(PParams p)
{
    __shared__ unsigned short WA[16][1032];
    __shared__ unsigned short WC[16][520];
    __shared__ float gbuf[16][128];
    __shared__ float cs[4][128];
    __shared__ float qa_s[H];
    __shared__ float va_s[H];
    __shared__ float part[SS][4];
    __shared__ float wbuf[SS];

    const int tid  = threadIdx.x;
    const int beta = blockIdx.x;
    unsigned bs = 1;

    // ---- prologue: h0 -> bf16, stage weight slices, init c ----
    for (int i = beta * 256 + tid; i < BB * H; i += NB * 256)
        p.hbf[i] = f2b(p.h0[i]);
    {
        const int j0 = beta * 16;
        for (int idx = tid; idx < 16 * 128; idx += 256) {
            const int r = idx >> 7, ch = idx & 127;
            *(uint4*)&WA[r][ch * 8] = *(const uint4*)&p.Wbig[(size_t)(j0 + r) * 1024 + ch * 8];
        }
    }
    if (beta < 128) {
        for (int idx = tid; idx < 16 * 64; idx += 256) {
            const int c = idx >> 6, ch = idx & 63;
            const int n = (c >> 2) * 512 + beta * 4 + (c & 3);
            *(uint4*)&WC[c][ch * 8] = *(const uint4*)&p.Wc[(size_t)n * 512 + ch * 8];
        }
        for (int idx = tid; idx < 512; idx += 256) {
            const int jj = idx >> 7, b = idx & 127;
            cs[jj][b] = p.c0[b * H + beta * 4 + jj];
        }
        for (int i = tid; i < H; i += 256) va_s[i] = p.Va[i];
    }
    gbar(p.flags, p.gen, bs++);

    for (int t = 0; t < TT; ++t) {
        // ---------------- P1: Y^T rows j0..j0+15 ----------------
        {
            const int j0 = beta * 16;
            const int wv = tid >> 6, lane = tid & 63;
            const int r = lane & 15, g = lane >> 4;
            const int b0 = wv * 32, b1 = b0 + 16;
            const int ko = g * 8;
            f32x4 acc0 = {0.f, 0.f, 0.f, 0.f};
            f32x4 acc1 = {0.f, 0.f, 0.f, 0.f};
            const unsigned short* h0p = p.hbf + (size_t)(b0 + r) * H;
            const unsigned short* h1p = p.hbf + (size_t)(b1 + r) * H;
            const unsigned short* x0p = p.xall + ((size_t)t * BB + b0 + r) * H;
            const unsigned short* x1p = p.xall + ((size_t)t * BB + b1 + r) * H;
#pragma unroll
            for (int ks = 0; ks < 16; ++ks) {
                const int kk = ks * 32 + ko;
                bf16x8 bf = *(const bf16x8*)&WA[r][kk];
                acc0 = __builtin_amdgcn_mfma_f32_16x16x32_bf16(*(const bf16x8*)&h0p[kk], bf, acc0, 0, 0, 0);
                acc1 = __builtin_amdgcn_mfma_f32_16x16x32_bf16(*(const bf16x8*)&h1p[kk], bf, acc1, 0, 0, 0);
            }
#pragma unroll
            for (int ks = 0; ks < 16; ++ks) {
                const int kk = ks * 32 + ko;
                bf16x8 bf = *(const bf16x8*)&WA[r][512 + kk];
                acc0 = __builtin_amdgcn_mfma_f32_16x16x32_bf16(*(const bf16x8*)&x0p[kk], bf, acc0, 0, 0, 0);
                acc1 = __builtin_amdgcn_mfma_f32_16x16x32_bf16(*(const bf16x8*)&x1p[kk], bf, acc1, 0, 0, 0);
            }
            const float bb = p.bbig[j0 + r];
            float* yr = p.Yt + (size_t)(j0 + r) * BB;
#pragma unroll
            for (int i = 0; i < 4; ++i) {
                yr[b0 + g * 4 + i] = acc0[i] + bb;
                yr[b1 + g * 4 + i] = acc1[i] + bb;
            }
        }
        gbar(p.flags, p.gen, bs++);

        // ---------------- P2: attention for b = beta ----------------
        if (beta < 128) {
            const int b = beta;
            qa_s[tid]       = p.Yt[(size_t)tid * BB + b];
            qa_s[tid + 256] = p.Yt[(size_t)(tid + 256) * BB + b];
            __syncthreads();
            const int s = tid >> 2, q = tid & 3;
            const unsigned short* kp = p.keysb + ((size_t)b * SS + s) * H + q * 128;
            const float* qp = qa_s + q * 128;
            const float* vp = va_s + q * 128;
            float a2 = 0.f;
#pragma unroll 4
            for (int i = 0; i < 128; ++i)
                a2 += ftanh(qp[i] + b2f(kp[i])) * vp[i];
            part[s][q] = a2;
            __syncthreads();
            if (tid < 64) {
                float sc = part[tid][0] + part[tid][1] + part[tid][2] + part[tid][3] + p.bv[0];
                float m = sc;
                for (int o = 32; o; o >>= 1) m = fmaxf(m, __shfl_xor(m, o));
                const float e = __expf(sc - m);
                float ss = e;
                for (int o = 32; o; o >>= 1) ss += __shfl_xor(ss, o);
                const float w = e / ss;
                wbuf[tid] = w;
                p.attn[((size_t)b * TT + t) * SS + tid] = w;
            }
            __syncthreads();
            for (int k = tid; k < H; k += 256) {
                const unsigned short* eb = p.encb + (size_t)b * SS * H + k;
                float a3 = 0.f;
#pragma unroll 8
                for (int s2 = 0; s2 < SS; ++s2) a3 += wbuf[s2] * b2f(eb[(size_t)s2 * H]);
                p.ctxb[b * H + k] = f2b(a3);
            }
        }
        gbar(p.flags, p.gen, bs++);

        // ---------------- P3: gates_ctx + LSTM ----------------
        if (beta < 128) {
            const int wv = tid >> 6, lane = tid & 63;
            const int r = lane & 15, g = lane >> 4;
            const int b0 = wv * 32, b1 = b0 + 16;
            const int ko = g * 8;
            f32x4 acc0 = {0.f, 0.f, 0.f, 0.f};
            f32x4 acc1 = {0.f, 0.f, 0.f, 0.f};
            const unsigned short* c0p = p.ctxb + (size_t)(b0 + r) * H;
            const unsigned short* c1p = p.ctxb + (size_t)(b1 + r) * H;
#pragma unroll
            for (int ks = 0; ks < 16; ++ks) {
                const int kk = ks * 32 + ko;
                bf16x8 bf = *(const bf16x8*)&WC[r][kk];
                acc0 = __builtin_amdgcn_mfma_f32_16x16x32_bf16(*(const bf16x8*)&c0p[kk], bf, acc0, 0, 0, 0);
                acc1 = __builtin_amdgcn_mfma_f32_16x16x32_bf16(*(const bf16x8*)&c1p[kk], bf, acc1, 0, 0, 0);
            }
            const int n = (r >> 2) * 512 + beta * 4 + (r & 3);
            const float* yr = p.Yt + (size_t)(512 + n) * BB;
#pragma unroll
            for (int i = 0; i < 4; ++i) {
                gbuf[r][b0 + g * 4 + i] = acc0[i] + yr[b0 + g * 4 + i];
                gbuf[r][b1 + g * 4 + i] = acc1[i] + yr[b1 + g * 4 + i];
            }
            __syncthreads();
            const int last = (t == TT - 1);
            for (int cell = tid; cell < 512; cell += 256) {
                const int jj = cell >> 7, b = cell & 127;
                const float ig = gbuf[jj][b];
                const float fg = gbuf[4 + jj][b];
                const float gg = gbuf[8 + jj][b];
                const float og = gbuf[12 + jj][b];
                const float co = cs[jj][b];
                const float cn = fsig(fg) * co + fsig(ig) * ftanh(gg);
                const float hn = fsig(og) * ftanh(cn);
                cs[jj][b] = cn;
                const int j = beta * 4 + jj;
                p.hbf[b * H + j] = f2b(hn);
                p.hallb[((size_t)t * BB + b) * H + j] = f2b(hn);
                if (last) { p.out_h[b * H + j] = hn; p.out_c[b * H + j] = cn; }
            }
        }
        gbar(p.flags, p.gen, bs++);
    }
}

// ---------------------------------------------------------------------------
// In-place log-softmax over each row of 5000 logits.
// ---------------------------------------------------------------------------
__global__ __launch_bounds__(256)
void logsoftmax_rows(float* __restrict__ P)
{
    __shared__ float red[256];
    float* p = P + (size_t)blockIdx.x * V;
    const int tid = threadIdx.x;
    float m = -1e30f;
    for (int i = tid; i < V; i += 256) m = fmaxf(m, p[i]);
    red[tid] = m; __syncthreads();
    for (int sft = 128; sft; sft >>= 1) {
        if (tid < sft) red[tid] = fmaxf(red[tid], red[tid + sft]);
        __syncthreads();
    }
    m = red[0]; __syncthreads();
    float ssum = 0.f;
    for (int i = tid; i < V; i += 256) ssum += __expf(p[i] - m);
    red[tid] = ssum; __syncthreads();
    for (int sft = 128; sft; sft >>= 1) {
        if (tid < sft) red[tid] += red[tid + sft];
        __syncthreads();
    }
    const float lse = m + __logf(red[0]);
    for (int i = tid; i < V; i += 256) p[i] -= lse;
}

// ---------------------------------------------------------------------------
extern "C" void kernel_launch(void* const* d_in, const int* in_sizes, int n_in,
                              void* d_out, int out_size, void* d_ws, size_t ws_size,
                              hipStream_t stream)
{
    (void)in_sizes; (void)n_in; (void)out_size; (void)ws_size;
    const float* enc  = (const float*)d_in[0];
    const float* h0   = (const float*)d_in[1];
    const float* c0   = (const float*)d_in[2];
    const int*   tgt  = (const int*)  d_in[3];
    const float* emb  = (const float*)d_in[4];
    const float* Wa   = (const float*)d_in[5];
    const float* ba   = (const float*)d_in[6];
    const float* Ua   = (const float*)d_in[7];
    const float* bu   = (const float*)d_in[8];
    const float* Va   = (const float*)d_in[9];
    const float* bv   = (const float*)d_in[10];
    const float* Wih  = (const float*)d_in[11];
    const float* Whh  = (const float*)d_in[12];
    const float* bih  = (const float*)d_in[13];
    const float* bhh  = (const float*)d_in[14];
    const float* Wout = (const float*)d_in[15];
    const float* bout = (const float*)d_in[16];

    float* ws = (float*)d_ws;
    float* Yt   = ws;                                      // 327,680 f32
    float* bbig = Yt + 327680;                             // 2,560 f32
    unsigned* flags = (unsigned*)(bbig + 2560);            // 5,184 u32 (incl gen)
    unsigned short* Wbig  = (unsigned short*)(flags + 5184);   // 2,621,440 u16
    unsigned short* Wc    = Wbig + 2621440;                // 1,048,576
    unsigned short* Uab   = Wc + 1048576;                  // 262,144
    unsigned short* Woutb = Uab + 262144;                  // 2,560,000
    unsigned short* encb  = Woutb + 2560000;               // 4,194,304
    unsigned short* keysb = encb + 4194304;                // 4,194,304
    unsigned short* xall  = keysb + 4194304;               // 3,407,872
    unsigned short* hallb = xall + 3407872;                // 3,407,872
    unsigned short* hbf   = hallb + 3407872;               // 65,536
    unsigned short* ctxb  = hbf + 65536;                   // 65,536

    float* out    = (float*)d_out;
    float* out_h  = out + (size_t)BB * TT * V;
    float* out_c  = out_h + BB * H;
    float* out_at = out_c + BB * H;

    hipMemsetAsync(flags, 0, 5184 * sizeof(unsigned), stream);

    prep_w<<<dim3(2048), dim3(256), 0, stream>>>(
        Wa, Whh, Wih, ba, bih, bhh, Ua, Wout, enc, Wbig, Wc, Uab, Woutb, encb, bbig);
    gather_x<<<dim3(512), dim3(256), 0, stream>>>(emb, tgt, xall);

    // keys_proj = enc @ Ua^T + bu  -> bf16 [8192,512]
    gemm_mfma<1, 0><<<dim3(4, 64), dim3(256), 0, stream>>>(
        encb, Uab, bu, nullptr, keysb, BB * SS, H);

    PParams pp;
    pp.h0 = h0; pp.c0 = c0; pp.keysb = keysb; pp.encb = encb;
    pp.Va = Va; pp.bv = bv; pp.bbig = bbig;
    pp.Wbig = Wbig; pp.Wc = Wc; pp.xall = xall;
    pp.hbf = hbf; pp.ctxb = ctxb; pp.Yt = Yt; pp.hallb = hallb;
    pp.attn = out_at; pp.out_h = out_h; pp.out_c = out_c;
    pp.flags = flags; pp.gen = flags + 5120;
    persist<<<dim3(NB), dim3(256), 0, stream>>>(pp);

    // logits: hallb[6656,512] @ Woutb^T + bout -> out[b,t,:], then log-softmax
    gemm_mfma<0, 1><<<dim3(40, 52), dim3(256), 0, stream>>>(
        hallb, Woutb, bout, out, nullptr, TT * BB, V);
    logsoftmax_rows<<<dim3(BB * TT), dim3(256), 0, stream>>>(out);
}

// Round 5
// 2066.346 us; speedup vs baseline: 5.3031x; 1.4089x over previous
//
#include <hip/hip_runtime.h>
#include <math.h>

#define H 512
#define V 5000
#define BB 128
#define SS 64
#define TT 52
#define NB 160   // persistent grid size (2560/16 col-groups)

typedef __attribute__((ext_vector_type(8))) short bf16x8;
typedef __attribute__((ext_vector_type(4))) float f32x4;

__device__ __forceinline__ unsigned short f2b(float f) {
    unsigned u = __float_as_uint(f);
    return (unsigned short)((u + 0x7fffu + ((u >> 16) & 1u)) >> 16);
}
__device__ __forceinline__ float b2f(unsigned short u) {
    return __uint_as_float((unsigned)u << 16);
}
__device__ __forceinline__ float ftanh(float x) {
    return 1.f - 2.f / (1.f + __expf(2.f * x));
}
__device__ __forceinline__ float fsig(float x) {
    return 1.f / (1.f + __expf(-x));
}

// ---------------------------------------------------------------------------
// Coherent (L1/L2-bypassing, L3-coherence-point) accesses. The per-XCD L2s
// are not coherent; these sc0 sc1 accesses read/write the device-coherent
// memory side, so NO cache-maintenance fences (buffer_wbl2/inv, ~13us each)
// are needed around the grid barrier. Loads carry their own waitcnt so the
// result is valid when the asm block returns (batched 16-deep to pay one
// round trip, not sixteen).
// ---------------------------------------------------------------------------
__device__ __forceinline__ void cld_row16(const unsigned short* p, bf16x8* r)
{
    asm volatile(
        "global_load_dwordx4 %0, %16, off sc0 sc1\n\t"
        "global_load_dwordx4 %1, %16, off offset:64 sc0 sc1\n\t"
        "global_load_dwordx4 %2, %16, off offset:128 sc0 sc1\n\t"
        "global_load_dwordx4 %3, %16, off offset:192 sc0 sc1\n\t"
        "global_load_dwordx4 %4, %16, off offset:256 sc0 sc1\n\t"
        "global_load_dwordx4 %5, %16, off offset:320 sc0 sc1\n\t"
        "global_load_dwordx4 %6, %16, off offset:384 sc0 sc1\n\t"
        "global_load_dwordx4 %7, %16, off offset:448 sc0 sc1\n\t"
        "global_load_dwordx4 %8, %16, off offset:512 sc0 sc1\n\t"
        "global_load_dwordx4 %9, %16, off offset:576 sc0 sc1\n\t"
        "global_load_dwordx4 %10, %16, off offset:640 sc0 sc1\n\t"
        "global_load_dwordx4 %11, %16, off offset:704 sc0 sc1\n\t"
        "global_load_dwordx4 %12, %16, off offset:768 sc0 sc1\n\t"
        "global_load_dwordx4 %13, %16, off offset:832 sc0 sc1\n\t"
        "global_load_dwordx4 %14, %16, off offset:896 sc0 sc1\n\t"
        "global_load_dwordx4 %15, %16, off offset:960 sc0 sc1\n\t"
        "s_waitcnt vmcnt(0)"
        : "=v"(r[0]), "=v"(r[1]), "=v"(r[2]), "=v"(r[3]),
          "=v"(r[4]), "=v"(r[5]), "=v"(r[6]), "=v"(r[7]),
          "=v"(r[8]), "=v"(r[9]), "=v"(r[10]), "=v"(r[11]),
          "=v"(r[12]), "=v"(r[13]), "=v"(r[14]), "=v"(r[15])
        : "v"(p) : "memory");
}
__device__ __forceinline__ void cld_f_2(const float* p0, const float* p1,
                                        float& a, float& b)
{
    asm volatile(
        "global_load_dword %0, %2, off sc0 sc1\n\t"
        "global_load_dword %1, %3, off sc0 sc1\n\t"
        "s_waitcnt vmcnt(0)"
        : "=v"(a), "=v"(b) : "v"(p0), "v"(p1) : "memory");
}
__device__ __forceinline__ void cld_f4x2(const float* p, f32x4& a, f32x4& b)
{
    asm volatile(
        "global_load_dwordx4 %0, %2, off sc0 sc1\n\t"
        "global_load_dwordx4 %1, %2, off offset:64 sc0 sc1\n\t"
        "s_waitcnt vmcnt(0)"
        : "=v"(a), "=v"(b) : "v"(p) : "memory");
}
__device__ __forceinline__ void cst_f4(float* p, f32x4 v)
{
    asm volatile("global_store_dwordx4 %0, %1, off sc0 sc1"
                 :: "v"(p), "v"(v) : "memory");
}
__device__ __forceinline__ void cst_h(unsigned short* p, unsigned short v)
{
    unsigned vv = v;
    asm volatile("global_store_short %0, %1, off sc0 sc1"
                 :: "v"(p), "v"(vv) : "memory");
}

// ---------------------------------------------------------------------------
// prep: Wbig_bf16 [2560,1024] = [ Wa | 0 ; W_hh | W_ih_x ], Wc_bf16 [2048,512]
// = W_ih_ctx, bbig = [ba ; b_ih+b_hh], plus bf16 copies of Ua, Wout, enc.
// ---------------------------------------------------------------------------
__global__ __launch_bounds__(256)
void prep_w(const float* __restrict__ Wa, const float* __restrict__ Whh,
            const float* __restrict__ Wih,
            const float* __restrict__ ba, const float* __restrict__ bih,
            const float* __restrict__ bhh,
            const float* __restrict__ Ua, const float* __restrict__ Wout,
            const float* __restrict__ enc,
            unsigned short* __restrict__ Wbig, unsigned short* __restrict__ Wc,
            unsigned short* __restrict__ Uab, unsigned short* __restrict__ Woutb,
            unsigned short* __restrict__ encb, float* __restrict__ bbig)
{
    const int stride = gridDim.x * blockDim.x;
    const int t0 = blockIdx.x * blockDim.x + threadIdx.x;
    for (int idx = t0; idx < 2560 * 1024; idx += stride) {
        const int j = idx >> 10, k = idx & 1023;
        float v;
        if (j < H) v = (k < H) ? Wa[j * H + k] : 0.f;
        else { const int n = j - H; v = (k < H) ? Whh[n * H + k] : Wih[n * 2 * H + (k - H)]; }
        Wbig[idx] = f2b(v);
    }
    for (int idx = t0; idx < 2048 * 512; idx += stride) {
        const int n = idx >> 9, k = idx & 511;
        Wc[idx] = f2b(Wih[n * 2 * H + H + k]);
    }
    for (int idx = t0; idx < 512 * 512; idx += stride)   Uab[idx]   = f2b(Ua[idx]);
    for (int idx = t0; idx < V * 512; idx += stride)     Woutb[idx] = f2b(Wout[idx]);
    for (int idx = t0; idx < BB * SS * H; idx += stride) encb[idx]  = f2b(enc[idx]);
    for (int j = t0; j < 2560; j += stride)
        bbig[j] = (j < H) ? ba[j] : bih[j - H] + bhh[j - H];
}

// ---------------------------------------------------------------------------
// Pre-gather teacher-forced inputs: xall[t*B+b][k] = emb[tok(t,b)][k] (bf16)
// ---------------------------------------------------------------------------
__global__ __launch_bounds__(256)
void gather_x(const float* __restrict__ emb, const int* __restrict__ tgt,
              unsigned short* __restrict__ xall)
{
    const int stride = gridDim.x * blockDim.x;
    for (int idx = blockIdx.x * blockDim.x + threadIdx.x; idx < TT * BB * H; idx += stride) {
        const int k = idx & 511;
        const int row = idx >> 9;
        const int t = row >> 7, b = row & 127;
        const int tok = (t == 0) ? 0 : tgt[b * TT + t - 1];
        xall[idx] = f2b(emb[(size_t)tok * H + k]);
    }
}

// ---------------------------------------------------------------------------
// bf16 MFMA NT-GEMM, K=512 fixed (unchanged from round 3).
// ---------------------------------------------------------------------------
template<int OUT_BF16, int PERMUTE>
__global__ __launch_bounds__(256, 2)
void gemm_mfma(const unsigned short* __restrict__ A,
               const unsigned short* __restrict__ B,
               const float* __restrict__ bias,
               float* __restrict__ Cf, unsigned short* __restrict__ Cb,
               int M, int N)
{
    __shared__ unsigned short As[128][72];
    __shared__ unsigned short Bs[128][72];
    const int tid = threadIdx.x;
    const int m0 = blockIdx.y * 128, n0 = blockIdx.x * 128;
    const int lane = tid & 63, wv = tid >> 6;
    const int qm = (wv >> 1) * 64, qn = (wv & 1) * 64;
    const int fr = lane & 15, fg = lane >> 4;
    f32x4 acc[4][4];
#pragma unroll
    for (int i = 0; i < 4; ++i)
#pragma unroll
        for (int j = 0; j < 4; ++j) acc[i][j] = (f32x4){0.f, 0.f, 0.f, 0.f};

    const int srow = tid >> 3, sc = (tid & 7) * 8;
    for (int k0 = 0; k0 < H; k0 += 64) {
#pragma unroll
        for (int u = 0; u < 4; ++u) {
            const int row = srow + u * 32;
            *(uint4*)&As[row][sc] = *(const uint4*)&A[(size_t)(m0 + row) * H + k0 + sc];
            int nr = n0 + row; if (nr > N - 1) nr = N - 1;
            *(uint4*)&Bs[row][sc] = *(const uint4*)&B[(size_t)nr * H + k0 + sc];
        }
        __syncthreads();
#pragma unroll
        for (int ks = 0; ks < 2; ++ks) {
            const int kk = ks * 32 + fg * 8;
            bf16x8 av[4], bv[4];
#pragma unroll
            for (int i = 0; i < 4; ++i) {
                av[i] = *(const bf16x8*)&As[qm + i * 16 + fr][kk];
                bv[i] = *(const bf16x8*)&Bs[qn + i * 16 + fr][kk];
            }
#pragma unroll
            for (int i = 0; i < 4; ++i)
#pragma unroll
                for (int j = 0; j < 4; ++j)
                    acc[i][j] = __builtin_amdgcn_mfma_f32_16x16x32_bf16(av[i], bv[j], acc[i][j], 0, 0, 0);
        }
        __syncthreads();
    }
#pragma unroll
    for (int i = 0; i < 4; ++i) {
        const int r0 = m0 + qm + i * 16 + fg * 4;
#pragma unroll
        for (int j = 0; j < 4; ++j) {
            const int col = n0 + qn + j * 16 + fr;
            if (col < N) {
                const float bi = bias[col];
#pragma unroll
                for (int v = 0; v < 4; ++v) {
                    const int r = r0 + v;
                    const float val = acc[i][j][v] + bi;
                    if (OUT_BF16) {
                        Cb[(size_t)r * N + col] = f2b(val);
                    } else {
                        const size_t orow = PERMUTE ? ((size_t)(r & (BB - 1)) * TT + (r >> 7))
                                                    : (size_t)r;
                        Cf[orow * (size_t)N + col] = val;
                    }
                }
            }
        }
    }
}

// ---------------------------------------------------------------------------
// Grid barrier v4: FENCE-FREE. Relaxed flag/gen protocol only. Ordering:
// __syncthreads() drains vmcnt(0) for every thread's sc0sc1 write-through
// data stores (visible at the coherent L3) BEFORE thread 0 publishes the
// flag; consumers' data reads bypass L1/L2 so they can't see stale lines.
// No buffer_wbl2 / buffer_inv -> read-only data stays L2-resident.
// ---------------------------------------------------------------------------
__device__ __forceinline__ void gbar(unsigned* flags, unsigned* gen, unsigned step)
{
    __syncthreads();
    if (blockIdx.x == 0) {
        for (int i = threadIdx.x; i < NB - 1; i += 256) {
            while (__hip_atomic_load(&flags[(i + 1) * 32], __ATOMIC_RELAXED,
                                     __HIP_MEMORY_SCOPE_AGENT) < step)
                __builtin_amdgcn_s_sleep(1);
        }
        __syncthreads();
        if (threadIdx.x == 0)
            __hip_atomic_store(gen, step, __ATOMIC_RELAXED, __HIP_MEMORY_SCOPE_AGENT);
        __syncthreads();
    } else {
        if (threadIdx.x == 0) {
            __hip_atomic_store(&flags[blockIdx.x * 32], step, __ATOMIC_RELAXED,
                               __HIP_MEMORY_SCOPE_AGENT);
            while (__hip_atomic_load(gen, __ATOMIC_RELAXED,
                                     __HIP_MEMORY_SCOPE_AGENT) < step)
                __builtin_amdgcn_s_sleep(1);
        }
        __syncthreads();
    }
}

struct PParams {
    const float* h0;
    const float* c0;
    const unsigned short* keysb;  // [B*S][512] bf16 (read-only, L2-cached)
    const unsigned short* encb;   // [B*S][512] bf16 (read-only, L2-cached)
    const float* Va;
    const float* bv;
    const float* bbig;
    const unsigned short* Wbig;   // [2560][1024] bf16
    const unsigned short* Wc;     // [2048][512]  bf16
    const unsigned short* xall;   // [T*B][512]   bf16 (read-only)
    unsigned short* hbf;          // [B][512] bf16   -- coherent (cross-block)
    unsigned short* ctxb;         // [B][512] bf16   -- coherent (cross-block)
    float* Yt;                    // [2560][128]     -- coherent (cross-block)
    unsigned short* hallb;        // [T*B][512] bf16 (consumed post-kernel)
    float* attn;                  // -> d_out attention block [B][T][S]
    float* out_h;
    float* out_c;
    unsigned* flags;
    unsigned* gen;
};

// ---------------------------------------------------------------------------
// Persistent recurrence kernel (160 blocks, all resident). Per step:
//   P1 (blocks 0..159, 16 cols each): Y^T = ([h|x] @ Wbig^T + bbig)^T [MFMA]
//   P2 (blocks 0..127, 1 per b): attention -> ctx (bf16), attn weights
//   P3 (blocks 0..127): ctx@Wc^T [MFMA] + LSTM; c lives in LDS across steps.
// Cross-block arrays (hbf, ctxb, Yt) use coherent sc0sc1 accesses.
// ---------------------------------------------------------------------------
__global__ __launch_bounds__(256, 1)
void persist(PParams p)
{
    __shared__ unsigned short WA[16][1032];
    __shared__ unsigned short WC[16][520];
    __shared__ float gbuf[16][128];
    __shared__ float cs[4][128];
    __shared__ float qa_s[H];
    __shared__ float va_s[H];
    __shared__ float part[SS][4];
    __shared__ float wbuf[SS];

    const int tid  = threadIdx.x;
    const int beta = blockIdx.x;
    unsigned bs = 1;

    // ---- prologue: h0 -> bf16 (coherent), stage weight slices, init c ----
    for (int i = beta * 256 + tid; i < BB * H; i += NB * 256)
        cst_h(&p.hbf[i], f2b(p.h0[i]));
    {
        const int j0 = beta * 16;
        for (int idx = tid; idx < 16 * 128; idx += 256) {
            const int r = idx >> 7, ch = idx & 127;
            *(uint4*)&WA[r][ch * 8] = *(const uint4*)&p.Wbig[(size_t)(j0 + r) * 1024 + ch * 8];
        }
    }
    if (beta < 128) {
        for (int idx = tid; idx < 16 * 64; idx += 256) {
            const int c = idx >> 6, ch = idx & 63;
            const int n = (c >> 2) * 512 + beta * 4 + (c & 3);
            *(uint4*)&WC[c][ch * 8] = *(const uint4*)&p.Wc[(size_t)n * 512 + ch * 8];
        }
        for (int idx = tid; idx < 512; idx += 256) {
            const int jj = idx >> 7, b = idx & 127;
            cs[jj][b] = p.c0[b * H + beta * 4 + jj];
        }
        for (int i = tid; i < H; i += 256) va_s[i] = p.Va[i];
    }
    gbar(p.flags, p.gen, bs++);

    for (int t = 0; t < TT; ++t) {
        // ---------------- P1: Y^T rows j0..j0+15 ----------------
        {
            const int j0 = beta * 16;
            const int wv = tid >> 6, lane = tid & 63;
            const int r = lane & 15, g = lane >> 4;
            const int b0 = wv * 32, b1 = b0 + 16;
            const int ko = g * 8;
            bf16x8 hr0[16], hr1[16];
            cld_row16(p.hbf + (size_t)(b0 + r) * H + ko, hr0);
            cld_row16(p.hbf + (size_t)(b1 + r) * H + ko, hr1);
            f32x4 acc0 = {0.f, 0.f, 0.f, 0.f};
            f32x4 acc1 = {0.f, 0.f, 0.f, 0.f};
#pragma unroll
            for (int ks = 0; ks < 16; ++ks) {
                bf16x8 bf = *(const bf16x8*)&WA[r][ks * 32 + ko];
                acc0 = __builtin_amdgcn_mfma_f32_16x16x32_bf16(hr0[ks], bf, acc0, 0, 0, 0);
                acc1 = __builtin_amdgcn_mfma_f32_16x16x32_bf16(hr1[ks], bf, acc1, 0, 0, 0);
            }
            const unsigned short* x0p = p.xall + ((size_t)t * BB + b0 + r) * H + ko;
            const unsigned short* x1p = p.xall + ((size_t)t * BB + b1 + r) * H + ko;
#pragma unroll
            for (int ks = 0; ks < 16; ++ks) {
                bf16x8 bf = *(const bf16x8*)&WA[r][512 + ks * 32 + ko];
                acc0 = __builtin_amdgcn_mfma_f32_16x16x32_bf16(*(const bf16x8*)&x0p[ks * 32], bf, acc0, 0, 0, 0);
                acc1 = __builtin_amdgcn_mfma_f32_16x16x32_bf16(*(const bf16x8*)&x1p[ks * 32], bf, acc1, 0, 0, 0);
            }
            const float bb = p.bbig[j0 + r];
            float* yr = p.Yt + (size_t)(j0 + r) * BB;
            f32x4 o0, o1;
#pragma unroll
            for (int i = 0; i < 4; ++i) { o0[i] = acc0[i] + bb; o1[i] = acc1[i] + bb; }
            cst_f4(yr + b0 + g * 4, o0);
            cst_f4(yr + b1 + g * 4, o1);
        }
        gbar(p.flags, p.gen, bs++);

        // ---------------- P2: attention for b = beta ----------------
        if (beta < 128) {
            const int b = beta;
            cld_f_2(p.Yt + (size_t)tid * BB + b, p.Yt + (size_t)(tid + 256) * BB + b,
                    qa_s[tid], qa_s[tid + 256]);
            __syncthreads();
            const int s = tid >> 2, q = tid & 3;
            const unsigned short* kp = p.keysb + ((size_t)b * SS + s) * H + q * 128;
            const float* qp = qa_s + q * 128;
            const float* vp = va_s + q * 128;
            float a2 = 0.f;
#pragma unroll 4
            for (int i = 0; i < 128; ++i)
                a2 += ftanh(qp[i] + b2f(kp[i])) * vp[i];
            part[s][q] = a2;
            __syncthreads();
            if (tid < 64) {
                float sc = part[tid][0] + part[tid][1] + part[tid][2] + part[tid][3] + p.bv[0];
                float m = sc;
                for (int o = 32; o; o >>= 1) m = fmaxf(m, __shfl_xor(m, o));
                const float e = __expf(sc - m);
                float ss = e;
                for (int o = 32; o; o >>= 1) ss += __shfl_xor(ss, o);
                const float w = e / ss;
                wbuf[tid] = w;
                p.attn[((size_t)b * TT + t) * SS + tid] = w;
            }
            __syncthreads();
            for (int k = tid; k < H; k += 256) {
                const unsigned short* eb = p.encb + (size_t)b * SS * H + k;
                float a3 = 0.f;
#pragma unroll 8
                for (int s2 = 0; s2 < SS; ++s2) a3 += wbuf[s2] * b2f(eb[(size_t)s2 * H]);
                cst_h(&p.ctxb[b * H + k], f2b(a3));
            }
        }
        gbar(p.flags, p.gen, bs++);

        // ---------------- P3: gates_ctx + LSTM ----------------
        if (beta < 128) {
            const int wv = tid >> 6, lane = tid & 63;
            const int r = lane & 15, g = lane >> 4;
            const int b0 = wv * 32, b1 = b0 + 16;
            const int ko = g * 8;
            bf16x8 cr0[16], cr1[16];
            cld_row16(p.ctxb + (size_t)(b0 + r) * H + ko, cr0);
            cld_row16(p.ctxb + (size_t)(b1 + r) * H + ko, cr1);
            f32x4 acc0 = {0.f, 0.f, 0.f, 0.f};
            f32x4 acc1 = {0.f, 0.f, 0.f, 0.f};
#pragma unroll
            for (int ks = 0; ks < 16; ++ks) {
                bf16x8 bf = *(const bf16x8*)&WC[r][ks * 32 + ko];
                acc0 = __builtin_amdgcn_mfma_f32_16x16x32_bf16(cr0[ks], bf, acc0, 0, 0, 0);
                acc1 = __builtin_amdgcn_mfma_f32_16x16x32_bf16(cr1[ks], bf, acc1, 0, 0, 0);
            }
            const int n = (r >> 2) * 512 + beta * 4 + (r & 3);
            const float* yr = p.Yt + (size_t)(512 + n) * BB;
            f32x4 y0, y1;
            cld_f4x2(yr + b0 + g * 4, y0, y1);
#pragma unroll
            for (int i = 0; i < 4; ++i) {
                gbuf[r][b0 + g * 4 + i] = acc0[i] + y0[i];
                gbuf[r][b1 + g * 4 + i] = acc1[i] + y1[i];
            }
            __syncthreads();
            const int last = (t == TT - 1);
            for (int cell = tid; cell < 512; cell += 256) {
                const int jj = cell >> 7, b = cell & 127;
                const float ig = gbuf[jj][b];
                const float fg = gbuf[4 + jj][b];
                const float gg = gbuf[8 + jj][b];
                const float og = gbuf[12 + jj][b];
                const float co = cs[jj][b];
                const float cn = fsig(fg) * co + fsig(ig) * ftanh(gg);
                const float hn = fsig(og) * ftanh(cn);
                cs[jj][b] = cn;
                const int j = beta * 4 + jj;
                const unsigned short hb = f2b(hn);
                cst_h(&p.hbf[b * H + j], hb);
                p.hallb[((size_t)t * BB + b) * H + j] = hb;
                if (last) { p.out_h[b * H + j] = hn; p.out_c[b * H + j] = cn; }
            }
        }
        gbar(p.flags, p.gen, bs++);
    }
}

// ---------------------------------------------------------------------------
// In-place log-softmax over each row of 5000 logits.
// ---------------------------------------------------------------------------
__global__ __launch_bounds__(256)
void logsoftmax_rows(float* __restrict__ P)
{
    __shared__ float red[256];
    float* p = P + (size_t)blockIdx.x * V;
    const int tid = threadIdx.x;
    float m = -1e30f;
    for (int i = tid; i < V; i += 256) m = fmaxf(m, p[i]);
    red[tid] = m; __syncthreads();
    for (int sft = 128; sft; sft >>= 1) {
        if (tid < sft) red[tid] = fmaxf(red[tid], red[tid + sft]);
        __syncthreads();
    }
    m = red[0]; __syncthreads();
    float ssum = 0.f;
    for (int i = tid; i < V; i += 256) ssum += __expf(p[i] - m);
    red[tid] = ssum; __syncthreads();
    for (int sft = 128; sft; sft >>= 1) {
        if (tid < sft) red[tid] += red[tid + sft];
        __syncthreads();
    }
    const float lse = m + __logf(red[0]);
    for (int i = tid; i < V; i += 256) p[i] -= lse;
}

// ---------------------------------------------------------------------------
extern "C" void kernel_launch(void* const* d_in, const int* in_sizes, int n_in,
                              void* d_out, int out_size, void* d_ws, size_t ws_size,
                              hipStream_t stream)
{
    (void)in_sizes; (void)n_in; (void)out_size; (void)ws_size;
    const float* enc  = (const float*)d_in[0];
    const float* h0   = (const float*)d_in[1];
    const float* c0   = (const float*)d_in[2];
    const int*   tgt  = (const int*)  d_in[3];
    const float* emb  = (const float*)d_in[4];
    const float* Wa   = (const float*)d_in[5];
    const float* ba   = (const float*)d_in[6];
    const float* Ua   = (const float*)d_in[7];
    const float* bu   = (const float*)d_in[8];
    const float* Va   = (const float*)d_in[9];
    const float* bv   = (const float*)d_in[10];
    const float* Wih  = (const float*)d_in[11];
    const float* Whh  = (const float*)d_in[12];
    const float* bih  = (const float*)d_in[13];
    const float* bhh  = (const float*)d_in[14];
    const float* Wout = (const float*)d_in[15];
    const float* bout = (const float*)d_in[16];

    float* ws = (float*)d_ws;
    float* Yt   = ws;                                      // 327,680 f32
    float* bbig = Yt + 327680;                             // 2,560 f32
    unsigned* flags = (unsigned*)(bbig + 2560);            // 5,184 u32 (incl gen)
    unsigned short* Wbig  = (unsigned short*)(flags + 5184);   // 2,621,440 u16
    unsigned short* Wc    = Wbig + 2621440;                // 1,048,576
    unsigned short* Uab   = Wc + 1048576;                  // 262,144
    unsigned short* Woutb = Uab + 262144;                  // 2,560,000
    unsigned short* encb  = Woutb + 2560000;               // 4,194,304
    unsigned short* keysb = encb + 4194304;                // 4,194,304
    unsigned short* xall  = keysb + 4194304;               // 3,407,872
    unsigned short* hallb = xall + 3407872;                // 3,407,872
    unsigned short* hbf   = hallb + 3407872;               // 65,536
    unsigned short* ctxb  = hbf + 65536;                   // 65,536

    float* out    = (float*)d_out;
    float* out_h  = out + (size_t)BB * TT * V;
    float* out_c  = out_h + BB * H;
    float* out_at = out_c + BB * H;

    hipMemsetAsync(flags, 0, 5184 * sizeof(unsigned), stream);

    prep_w<<<dim3(2048), dim3(256), 0, stream>>>(
        Wa, Whh, Wih, ba, bih, bhh, Ua, Wout, enc, Wbig, Wc, Uab, Woutb, encb, bbig);
    gather_x<<<dim3(512), dim3(256), 0, stream>>>(emb, tgt, xall);

    // keys_proj = enc @ Ua^T + bu  -> bf16 [8192,512]
    gemm_mfma<1, 0><<<dim3(4, 64), dim3(256), 0, stream>>>(
        encb, Uab, bu, nullptr, keysb, BB * SS, H);

    PParams pp;
    pp.h0 = h0; pp.c0 = c0; pp.keysb = keysb; pp.encb = encb;
    pp.Va = Va; pp.bv = bv; pp.bbig = bbig;
    pp.Wbig = Wbig; pp.Wc = Wc; pp.xall = xall;
    pp.hbf = hbf; pp.ctxb = ctxb; pp.Yt = Yt; pp.hallb = hallb;
    pp.attn = out_at; pp.out_h = out_h; pp.out_c = out_c;
    pp.flags = flags; pp.gen = flags + 5120;
    persist<<<dim3(NB), dim3(256), 0, stream>>>(pp);

    // logits: hallb[6656,512] @ Woutb^T + bout -> out[b,t,:], then log-softmax
    gemm_mfma<0, 1><<<dim3(40, 52), dim3(256), 0, stream>>>(
        hallb, Woutb, bout, out, nullptr, TT * BB, V);
    logsoftmax_rows<<<dim3(BB * TT), dim3(256), 0, stream>>>(out);
}

// Round 6
// 1785.227 us; speedup vs baseline: 6.1382x; 1.1575x over previous
//
#include <hip/hip_runtime.h>
#include <math.h>

#define H 512
#define V 5000
#define BB 128
#define SS 64
#define TT 52
#define NB 160   // persistent grid size (2560/16 col-groups)

typedef __attribute__((ext_vector_type(8))) short bf16x8;
typedef __attribute__((ext_vector_type(4))) float f32x4;

__device__ __forceinline__ unsigned short f2b(float f) {
    unsigned u = __float_as_uint(f);
    return (unsigned short)((u + 0x7fffu + ((u >> 16) & 1u)) >> 16);
}
__device__ __forceinline__ float b2f(unsigned short u) {
    return __uint_as_float((unsigned)u << 16);
}
__device__ __forceinline__ float ftanh(float x) {
    return 1.f - 2.f / (1.f + __expf(2.f * x));
}
__device__ __forceinline__ float fsig(float x) {
    return 1.f / (1.f + __expf(-x));
}

// ---------------------------------------------------------------------------
// Coherent (L1/L2-bypassing, L3-coherence-point) accesses; no cache-
// maintenance fences needed around the grid barrier (validated r4->r5).
// ---------------------------------------------------------------------------
__device__ __forceinline__ void cld_row16(const unsigned short* p, bf16x8* r)
{
    asm volatile(
        "global_load_dwordx4 %0, %16, off sc0 sc1\n\t"
        "global_load_dwordx4 %1, %16, off offset:64 sc0 sc1\n\t"
        "global_load_dwordx4 %2, %16, off offset:128 sc0 sc1\n\t"
        "global_load_dwordx4 %3, %16, off offset:192 sc0 sc1\n\t"
        "global_load_dwordx4 %4, %16, off offset:256 sc0 sc1\n\t"
        "global_load_dwordx4 %5, %16, off offset:320 sc0 sc1\n\t"
        "global_load_dwordx4 %6, %16, off offset:384 sc0 sc1\n\t"
        "global_load_dwordx4 %7, %16, off offset:448 sc0 sc1\n\t"
        "global_load_dwordx4 %8, %16, off offset:512 sc0 sc1\n\t"
        "global_load_dwordx4 %9, %16, off offset:576 sc0 sc1\n\t"
        "global_load_dwordx4 %10, %16, off offset:640 sc0 sc1\n\t"
        "global_load_dwordx4 %11, %16, off offset:704 sc0 sc1\n\t"
        "global_load_dwordx4 %12, %16, off offset:768 sc0 sc1\n\t"
        "global_load_dwordx4 %13, %16, off offset:832 sc0 sc1\n\t"
        "global_load_dwordx4 %14, %16, off offset:896 sc0 sc1\n\t"
        "global_load_dwordx4 %15, %16, off offset:960 sc0 sc1\n\t"
        "s_waitcnt vmcnt(0)"
        : "=v"(r[0]), "=v"(r[1]), "=v"(r[2]), "=v"(r[3]),
          "=v"(r[4]), "=v"(r[5]), "=v"(r[6]), "=v"(r[7]),
          "=v"(r[8]), "=v"(r[9]), "=v"(r[10]), "=v"(r[11]),
          "=v"(r[12]), "=v"(r[13]), "=v"(r[14]), "=v"(r[15])
        : "v"(p) : "memory");
}
__device__ __forceinline__ void cld_f_2(const float* p0, const float* p1,
                                        float& a, float& b)
{
    asm volatile(
        "global_load_dword %0, %2, off sc0 sc1\n\t"
        "global_load_dword %1, %3, off sc0 sc1\n\t"
        "s_waitcnt vmcnt(0)"
        : "=v"(a), "=v"(b) : "v"(p0), "v"(p1) : "memory");
}
__device__ __forceinline__ void cld_f4p(const float* p, f32x4& a, f32x4& b)
{
    asm volatile(
        "global_load_dwordx4 %0, %2, off sc0 sc1\n\t"
        "global_load_dwordx4 %1, %2, off offset:16 sc0 sc1\n\t"
        "s_waitcnt vmcnt(0)"
        : "=v"(a), "=v"(b) : "v"(p) : "memory");
}
__device__ __forceinline__ void cst_f(float* p, float v)
{
    asm volatile("global_store_dword %0, %1, off sc0 sc1"
                 :: "v"(p), "v"(v) : "memory");
}
__device__ __forceinline__ void cst_u32(unsigned* p, unsigned v)
{
    asm volatile("global_store_dword %0, %1, off sc0 sc1"
                 :: "v"(p), "v"(v) : "memory");
}
__device__ __forceinline__ void cst_h(unsigned short* p, unsigned short v)
{
    unsigned vv = v;
    asm volatile("global_store_short %0, %1, off sc0 sc1"
                 :: "v"(p), "v"(vv) : "memory");
}

// ---------------------------------------------------------------------------
// prep: Wbig_bf16 [2560,1024] = [ Wa | 0 ; W_hh | W_ih_x ], Wc_bf16 [2048,512]
// = W_ih_ctx, bbig = [ba ; b_ih+b_hh], plus bf16 copies of Ua, Wout, enc.
// ---------------------------------------------------------------------------
__global__ __launch_bounds__(256)
void prep_w(const float* __restrict__ Wa, const float* __restrict__ Whh,
            const float* __restrict__ Wih,
            const float* __restrict__ ba, const float* __restrict__ bih,
            const float* __restrict__ bhh,
            const float* __restrict__ Ua, const float* __restrict__ Wout,
            const float* __restrict__ enc,
            unsigned short* __restrict__ Wbig, unsigned short* __restrict__ Wc,
            unsigned short* __restrict__ Uab, unsigned short* __restrict__ Woutb,
            unsigned short* __restrict__ encb, float* __restrict__ bbig)
{
    const int stride = gridDim.x * blockDim.x;
    const int t0 = blockIdx.x * blockDim.x + threadIdx.x;
    for (int idx = t0; idx < 2560 * 1024; idx += stride) {
        const int j = idx >> 10, k = idx & 1023;
        float v;
        if (j < H) v = (k < H) ? Wa[j * H + k] : 0.f;
        else { const int n = j - H; v = (k < H) ? Whh[n * H + k] : Wih[n * 2 * H + (k - H)]; }
        Wbig[idx] = f2b(v);
    }
    for (int idx = t0; idx < 2048 * 512; idx += stride) {
        const int n = idx >> 9, k = idx & 511;
        Wc[idx] = f2b(Wih[n * 2 * H + H + k]);
    }
    for (int idx = t0; idx < 512 * 512; idx += stride)   Uab[idx]   = f2b(Ua[idx]);
    for (int idx = t0; idx < V * 512; idx += stride)     Woutb[idx] = f2b(Wout[idx]);
    for (int idx = t0; idx < BB * SS * H; idx += stride) encb[idx]  = f2b(enc[idx]);
    for (int j = t0; j < 2560; j += stride)
        bbig[j] = (j < H) ? ba[j] : bih[j - H] + bhh[j - H];
}

// ---------------------------------------------------------------------------
// Pre-gather teacher-forced inputs: xall[t*B+b][k] = emb[tok(t,b)][k] (bf16)
// ---------------------------------------------------------------------------
__global__ __launch_bounds__(256)
void gather_x(const float* __restrict__ emb, const int* __restrict__ tgt,
              unsigned short* __restrict__ xall)
{
    const int stride = gridDim.x * blockDim.x;
    for (int idx = blockIdx.x * blockDim.x + threadIdx.x; idx < TT * BB * H; idx += stride) {
        const int k = idx & 511;
        const int row = idx >> 9;
        const int t = row >> 7, b = row & 127;
        const int tok = (t == 0) ? 0 : tgt[b * TT + t - 1];
        xall[idx] = f2b(emb[(size_t)tok * H + k]);
    }
}

// ---------------------------------------------------------------------------
// bf16 MFMA NT-GEMM, K=512 fixed: C[m,n] = A[m,:]·B[n,:] (+bias[n] if given).
// ---------------------------------------------------------------------------
template<int OUT_BF16, int PERMUTE>
__global__ __launch_bounds__(256, 2)
void gemm_mfma(const unsigned short* __restrict__ A,
               const unsigned short* __restrict__ B,
               const float* __restrict__ bias,
               float* __restrict__ Cf, unsigned short* __restrict__ Cb,
               int M, int N)
{
    __shared__ unsigned short As[128][72];
    __shared__ unsigned short Bs[128][72];
    const int tid = threadIdx.x;
    const int m0 = blockIdx.y * 128, n0 = blockIdx.x * 128;
    const int lane = tid & 63, wv = tid >> 6;
    const int qm = (wv >> 1) * 64, qn = (wv & 1) * 64;
    const int fr = lane & 15, fg = lane >> 4;
    f32x4 acc[4][4];
#pragma unroll
    for (int i = 0; i < 4; ++i)
#pragma unroll
        for (int j = 0; j < 4; ++j) acc[i][j] = (f32x4){0.f, 0.f, 0.f, 0.f};

    const int srow = tid >> 3, sc = (tid & 7) * 8;
    for (int k0 = 0; k0 < H; k0 += 64) {
#pragma unroll
        for (int u = 0; u < 4; ++u) {
            const int row = srow + u * 32;
            *(uint4*)&As[row][sc] = *(const uint4*)&A[(size_t)(m0 + row) * H + k0 + sc];
            int nr = n0 + row; if (nr > N - 1) nr = N - 1;
            *(uint4*)&Bs[row][sc] = *(const uint4*)&B[(size_t)nr * H + k0 + sc];
        }
        __syncthreads();
#pragma unroll
        for (int ks = 0; ks < 2; ++ks) {
            const int kk = ks * 32 + fg * 8;
            bf16x8 av[4], bv[4];
#pragma unroll
            for (int i = 0; i < 4; ++i) {
                av[i] = *(const bf16x8*)&As[qm + i * 16 + fr][kk];
                bv[i] = *(const bf16x8*)&Bs[qn + i * 16 + fr][kk];
            }
#pragma unroll
            for (int i = 0; i < 4; ++i)
#pragma unroll
                for (int j = 0; j < 4; ++j)
                    acc[i][j] = __builtin_amdgcn_mfma_f32_16x16x32_bf16(av[i], bv[j], acc[i][j], 0, 0, 0);
        }
        __syncthreads();
    }
#pragma unroll
    for (int i = 0; i < 4; ++i) {
        const int r0 = m0 + qm + i * 16 + fg * 4;
#pragma unroll
        for (int j = 0; j < 4; ++j) {
            const int col = n0 + qn + j * 16 + fr;
            if (col < N) {
                const float bi = bias ? bias[col] : 0.f;
#pragma unroll
                for (int v = 0; v < 4; ++v) {
                    const int r = r0 + v;
                    const float val = acc[i][j][v] + bi;
                    if (OUT_BF16) {
                        Cb[(size_t)r * N + col] = f2b(val);
                    } else {
                        const size_t orow = PERMUTE ? ((size_t)(r & (BB - 1)) * TT + (r >> 7))
                                                    : (size_t)r;
                        Cf[orow * (size_t)N + col] = val;
                    }
                }
            }
        }
    }
}

// ---------------------------------------------------------------------------
// Grid barrier v5: fence-free relaxed protocol; gen REPLICATED on 8 cache
// lines so only ~20 waiters poll each line (round-5's single line had 159
// pollers serializing at the L3 bank, delaying the update they awaited).
// ---------------------------------------------------------------------------
__device__ __forceinline__ void gbar(unsigned* flags, unsigned* gens, unsigned step)
{
    __syncthreads();
    if (blockIdx.x == 0) {
        for (int i = threadIdx.x; i < NB - 1; i += 256) {
            while (__hip_atomic_load(&flags[(i + 1) * 32], __ATOMIC_RELAXED,
                                     __HIP_MEMORY_SCOPE_AGENT) < step)
                __builtin_amdgcn_s_sleep(1);
        }
        __syncthreads();
        if (threadIdx.x < 8)
            __hip_atomic_store(&gens[threadIdx.x * 32], step, __ATOMIC_RELAXED,
                               __HIP_MEMORY_SCOPE_AGENT);
        __syncthreads();
    } else {
        if (threadIdx.x == 0) {
            __hip_atomic_store(&flags[blockIdx.x * 32], step, __ATOMIC_RELAXED,
                               __HIP_MEMORY_SCOPE_AGENT);
            while (__hip_atomic_load(&gens[(blockIdx.x & 7) * 32], __ATOMIC_RELAXED,
                                     __HIP_MEMORY_SCOPE_AGENT) < step)
                __builtin_amdgcn_s_sleep(1);
        }
        __syncthreads();
    }
}

struct PParams {
    const float* h0;
    const float* c0;
    const unsigned short* keysb;  // [B*S][512] bf16 (read-only, L2-cached)
    const unsigned short* encW;   // [B*S][2048] bf16 (read-only, L2-cached)
    const float* Va;
    const float* bv;
    const float* bbig;
    const unsigned short* Wbig;   // [2560][1024] bf16
    const unsigned short* xall;   // [T*B][512]   bf16 (read-only)
    unsigned short* hbf;          // [B][512] bf16   -- coherent (cross-block)
    float* Y;                     // [B][2560] f32   -- coherent (cross-block)
    unsigned short* hallb;        // [T*B][512] bf16 (consumed post-kernel)
    float* attn;                  // -> d_out attention block [B][T][S]
    float* out_h;
    float* out_c;
    unsigned* flags;
    unsigned* gens;
};

// ---------------------------------------------------------------------------
// Persistent recurrence kernel (160 blocks, all resident). Per step, TWO
// phases / TWO barriers:
//   P1 (all 160 blocks, 16 j-cols each): Y[b][j] = ([h|x] @ Wbig^T + bbig)
//   P2 (blocks 0..127 = batch b): attention scores+softmax, then
//       gates[n] = Y[b][512+n] + sum_s w[s]*encW[b,s,n]  (encW precomputed),
//       then LSTM with c[b] resident in LDS; h -> hbf (coherent) + hallb.
// ---------------------------------------------------------------------------
__global__ __launch_bounds__(256, 1)
void persist(PParams p)
{
    __shared__ unsigned short WA[16][1032];
    __shared__ float qa_s[H];
    __shared__ float va_s[H];
    __shared__ float part[SS][4];
    __shared__ float wbuf[SS];
    __shared__ float gbuf[4 * H];
    __shared__ float cs[H];

    const int tid  = threadIdx.x;
    const int beta = blockIdx.x;
    unsigned bs = 1;

    // ---- prologue: h0 -> bf16 (coherent), stage weight slice, init c ----
    for (int i = beta * 256 + tid; i < BB * H; i += NB * 256)
        cst_h(&p.hbf[i], f2b(p.h0[i]));
    {
        const int j0 = beta * 16;
        for (int idx = tid; idx < 16 * 128; idx += 256) {
            const int r = idx >> 7, ch = idx & 127;
            *(uint4*)&WA[r][ch * 8] = *(const uint4*)&p.Wbig[(size_t)(j0 + r) * 1024 + ch * 8];
        }
    }
    if (beta < 128) {
        for (int j = tid; j < H; j += 256) cs[j] = p.c0[beta * H + j];
        for (int i = tid; i < H; i += 256) va_s[i] = p.Va[i];
    }
    gbar(p.flags, p.gens, bs++);

    for (int t = 0; t < TT; ++t) {
        // ---------------- P1: Y[b][j0..j0+15] for all b ----------------
        {
            const int j0 = beta * 16;
            const int wv = tid >> 6, lane = tid & 63;
            const int r = lane & 15, g = lane >> 4;
            const int b0 = wv * 32, b1 = b0 + 16;
            const int ko = g * 8;
            bf16x8 hr0[16], hr1[16];
            cld_row16(p.hbf + (size_t)(b0 + r) * H + ko, hr0);
            cld_row16(p.hbf + (size_t)(b1 + r) * H + ko, hr1);
            f32x4 acc0 = {0.f, 0.f, 0.f, 0.f};
            f32x4 acc1 = {0.f, 0.f, 0.f, 0.f};
#pragma unroll
            for (int ks = 0; ks < 16; ++ks) {
                bf16x8 bf = *(const bf16x8*)&WA[r][ks * 32 + ko];
                acc0 = __builtin_amdgcn_mfma_f32_16x16x32_bf16(hr0[ks], bf, acc0, 0, 0, 0);
                acc1 = __builtin_amdgcn_mfma_f32_16x16x32_bf16(hr1[ks], bf, acc1, 0, 0, 0);
            }
            const unsigned short* x0p = p.xall + ((size_t)t * BB + b0 + r) * H + ko;
            const unsigned short* x1p = p.xall + ((size_t)t * BB + b1 + r) * H + ko;
#pragma unroll
            for (int ks = 0; ks < 16; ++ks) {
                bf16x8 bf = *(const bf16x8*)&WA[r][512 + ks * 32 + ko];
                acc0 = __builtin_amdgcn_mfma_f32_16x16x32_bf16(*(const bf16x8*)&x0p[ks * 32], bf, acc0, 0, 0, 0);
                acc1 = __builtin_amdgcn_mfma_f32_16x16x32_bf16(*(const bf16x8*)&x1p[ks * 32], bf, acc1, 0, 0, 0);
            }
            const float bb = p.bbig[j0 + r];
#pragma unroll
            for (int i = 0; i < 4; ++i) {
                cst_f(p.Y + (size_t)(b0 + g * 4 + i) * 2560 + j0 + r, acc0[i] + bb);
                cst_f(p.Y + (size_t)(b1 + g * 4 + i) * 2560 + j0 + r, acc1[i] + bb);
            }
        }
        gbar(p.flags, p.gens, bs++);

        // ------- P2: attention + ctx-gates + LSTM for batch b = beta -------
        if (beta < 128) {
            const int b = beta;
            const float* yrow = p.Y + (size_t)b * 2560;
            cld_f_2(yrow + tid, yrow + 256 + tid, qa_s[tid], qa_s[tid + 256]);
            __syncthreads();
            // scores
            const int s = tid >> 2, q = tid & 3;
            const unsigned short* kp = p.keysb + ((size_t)b * SS + s) * H + q * 128;
            const float* qp = qa_s + q * 128;
            const float* vp = va_s + q * 128;
            float a2 = 0.f;
#pragma unroll 4
            for (int i = 0; i < 128; ++i)
                a2 += ftanh(qp[i] + b2f(kp[i])) * vp[i];
            part[s][q] = a2;
            __syncthreads();
            if (tid < 64) {
                float sc = part[tid][0] + part[tid][1] + part[tid][2] + part[tid][3] + p.bv[0];
                float m = sc;
                for (int o = 32; o; o >>= 1) m = fmaxf(m, __shfl_xor(m, o));
                const float e = __expf(sc - m);
                float ss = e;
                for (int o = 32; o; o >>= 1) ss += __shfl_xor(ss, o);
                const float w = e / ss;
                wbuf[tid] = w;
                p.attn[((size_t)b * TT + t) * SS + tid] = w;
            }
            __syncthreads();
            // gates_ctx via encW weighted sum; n-chunk of 8 per thread
            {
                float gc[8] = {0.f, 0.f, 0.f, 0.f, 0.f, 0.f, 0.f, 0.f};
                const unsigned short* ew = p.encW + (size_t)b * SS * 2048 + tid * 8;
#pragma unroll 4
                for (int s2 = 0; s2 < SS; ++s2) {
                    const float w2 = wbuf[s2];
                    bf16x8 e = *(const bf16x8*)&ew[(size_t)s2 * 2048];
#pragma unroll
                    for (int i = 0; i < 8; ++i)
                        gc[i] += w2 * b2f((unsigned short)e[i]);
                }
                f32x4 y0, y1;
                cld_f4p(yrow + 512 + tid * 8, y0, y1);
#pragma unroll
                for (int i = 0; i < 4; ++i) {
                    gbuf[tid * 8 + i]     = gc[i] + y0[i];
                    gbuf[tid * 8 + 4 + i] = gc[4 + i] + y1[i];
                }
            }
            __syncthreads();
            // LSTM: cells 2*tid, 2*tid+1
            {
                const int last = (t == TT - 1);
                unsigned hpack = 0;
                float hn2[2], cn2[2];
#pragma unroll
                for (int u = 0; u < 2; ++u) {
                    const int j = tid * 2 + u;
                    const float ig = gbuf[j];
                    const float fg = gbuf[512 + j];
                    const float gg = gbuf[1024 + j];
                    const float og = gbuf[1536 + j];
                    const float co = cs[j];
                    const float cn = fsig(fg) * co + fsig(ig) * ftanh(gg);
                    const float hn = fsig(og) * ftanh(cn);
                    cs[j] = cn;
                    hn2[u] = hn; cn2[u] = cn;
                    hpack |= ((unsigned)f2b(hn)) << (16 * u);
                }
                cst_u32((unsigned*)&p.hbf[b * H + tid * 2], hpack);
                *(unsigned*)&p.hallb[((size_t)t * BB + b) * H + tid * 2] = hpack;
                if (last) {
#pragma unroll
                    for (int u = 0; u < 2; ++u) {
                        p.out_h[b * H + tid * 2 + u] = hn2[u];
                        p.out_c[b * H + tid * 2 + u] = cn2[u];
                    }
                }
            }
        }
        gbar(p.flags, p.gens, bs++);
    }
}

// ---------------------------------------------------------------------------
// In-place log-softmax over each row of 5000 logits.
// ---------------------------------------------------------------------------
__global__ __launch_bounds__(256)
void logsoftmax_rows(float* __restrict__ P)
{
    __shared__ float red[256];
    float* p = P + (size_t)blockIdx.x * V;
    const int tid = threadIdx.x;
    float m = -1e30f;
    for (int i = tid; i < V; i += 256) m = fmaxf(m, p[i]);
    red[tid] = m; __syncthreads();
    for (int sft = 128; sft; sft >>= 1) {
        if (tid < sft) red[tid] = fmaxf(red[tid], red[tid + sft]);
        __syncthreads();
    }
    m = red[0]; __syncthreads();
    float ssum = 0.f;
    for (int i = tid; i < V; i += 256) ssum += __expf(p[i] - m);
    red[tid] = ssum; __syncthreads();
    for (int sft = 128; sft; sft >>= 1) {
        if (tid < sft) red[tid] += red[tid + sft];
        __syncthreads();
    }
    const float lse = m + __logf(red[0]);
    for (int i = tid; i < V; i += 256) p[i] -= lse;
}

// ---------------------------------------------------------------------------
extern "C" void kernel_launch(void* const* d_in, const int* in_sizes, int n_in,
                              void* d_out, int out_size, void* d_ws, size_t ws_size,
                              hipStream_t stream)
{
    (void)in_sizes; (void)n_in; (void)out_size; (void)ws_size;
    const float* enc  = (const float*)d_in[0];
    const float* h0   = (const float*)d_in[1];
    const float* c0   = (const float*)d_in[2];
    const int*   tgt  = (const int*)  d_in[3];
    const float* emb  = (const float*)d_in[4];
    const float* Wa   = (const float*)d_in[5];
    const float* ba   = (const float*)d_in[6];
    const float* Ua   = (const float*)d_in[7];
    const float* bu   = (const float*)d_in[8];
    const float* Va   = (const float*)d_in[9];
    const float* bv   = (const float*)d_in[10];
    const float* Wih  = (const float*)d_in[11];
    const float* Whh  = (const float*)d_in[12];
    const float* bih  = (const float*)d_in[13];
    const float* bhh  = (const float*)d_in[14];
    const float* Wout = (const float*)d_in[15];
    const float* bout = (const float*)d_in[16];

    float* ws = (float*)d_ws;
    float* Y    = ws;                                      // 327,680 f32
    float* bbig = Y + 327680;                              // 2,560 f32
    unsigned* flags = (unsigned*)(bbig + 2560);            // 5,504 u32 (incl gens)
    unsigned short* Wbig  = (unsigned short*)(flags + 5504);   // 2,621,440 u16
    unsigned short* Wc    = Wbig + 2621440;                // 1,048,576
    unsigned short* Uab   = Wc + 1048576;                  // 262,144
    unsigned short* Woutb = Uab + 262144;                  // 2,560,000
    unsigned short* encb  = Woutb + 2560000;               // 4,194,304
    unsigned short* keysb = encb + 4194304;                // 4,194,304
    unsigned short* xall  = keysb + 4194304;               // 3,407,872
    unsigned short* hallb = xall + 3407872;                // 3,407,872
    unsigned short* hbf   = hallb + 3407872;               // 65,536
    unsigned short* encW  = hbf + 65536;                   // 16,777,216 u16 (33.5MB)

    float* out    = (float*)d_out;
    float* out_h  = out + (size_t)BB * TT * V;
    float* out_c  = out_h + BB * H;
    float* out_at = out_c + BB * H;

    hipMemsetAsync(flags, 0, 5504 * sizeof(unsigned), stream);

    prep_w<<<dim3(2048), dim3(256), 0, stream>>>(
        Wa, Whh, Wih, ba, bih, bhh, Ua, Wout, enc, Wbig, Wc, Uab, Woutb, encb, bbig);
    gather_x<<<dim3(512), dim3(256), 0, stream>>>(emb, tgt, xall);

    // keys_proj = enc @ Ua^T + bu  -> bf16 [8192,512]
    gemm_mfma<1, 0><<<dim3(4, 64), dim3(256), 0, stream>>>(
        encb, Uab, bu, nullptr, keysb, BB * SS, H);
    // encW = enc @ Wc^T -> bf16 [8192,2048]  (hoists per-step ctx@Wc^T GEMM)
    gemm_mfma<1, 0><<<dim3(16, 64), dim3(256), 0, stream>>>(
        encb, Wc, nullptr, nullptr, encW, BB * SS, 2048);

    PParams pp;
    pp.h0 = h0; pp.c0 = c0; pp.keysb = keysb; pp.encW = encW;
    pp.Va = Va; pp.bv = bv; pp.bbig = bbig;
    pp.Wbig = Wbig; pp.xall = xall;
    pp.hbf = hbf; pp.Y = Y; pp.hallb = hallb;
    pp.attn = out_at; pp.out_h = out_h; pp.out_c = out_c;
    pp.flags = flags; pp.gens = flags + 5120;
    persist<<<dim3(NB), dim3(256), 0, stream>>>(pp);

    // logits: hallb[6656,512] @ Woutb^T + bout -> out[b,t,:], then log-softmax
    gemm_mfma<0, 1><<<dim3(40, 52), dim3(256), 0, stream>>>(
        hallb, Woutb, bout, out, nullptr, TT * BB, V);
    logsoftmax_rows<<<dim3(BB * TT), dim3(256), 0, stream>>>(out);
}

// Round 7
// 1597.056 us; speedup vs baseline: 6.8614x; 1.1178x over previous
//
#include <hip/hip_runtime.h>
#include <math.h>

#define H 512
#define V 5000
#define BB 128
#define SS 64
#define TT 52
#define NB 160   // persistent grid size (2560/16 col-groups)

typedef __attribute__((ext_vector_type(8))) short bf16x8;
typedef __attribute__((ext_vector_type(4))) float f32x4;
typedef __attribute__((ext_vector_type(2))) float f32x2;

__device__ __forceinline__ unsigned short f2b(float f) {
    unsigned u = __float_as_uint(f);
    return (unsigned short)((u + 0x7fffu + ((u >> 16) & 1u)) >> 16);
}
__device__ __forceinline__ float b2f(unsigned short u) {
    return __uint_as_float((unsigned)u << 16);
}
__device__ __forceinline__ float ftanh(float x) {
    return 1.f - 2.f / (1.f + __expf(2.f * x));
}
__device__ __forceinline__ float fsig(float x) {
    return 1.f / (1.f + __expf(-x));
}
__device__ __forceinline__ unsigned char f2fp8(float f) {
    return (unsigned char)__builtin_amdgcn_cvt_pk_fp8_f32(f, f, 0, 0);
}

// ---------------------------------------------------------------------------
// Coherent (L1/L2-bypassing, L3-coherence-point) accesses; no cache-
// maintenance fences needed around the grid barrier (validated r4->r5).
// ---------------------------------------------------------------------------
__device__ __forceinline__ void cld_row16(const unsigned short* p, bf16x8* r)
{
    asm volatile(
        "global_load_dwordx4 %0, %16, off sc0 sc1\n\t"
        "global_load_dwordx4 %1, %16, off offset:64 sc0 sc1\n\t"
        "global_load_dwordx4 %2, %16, off offset:128 sc0 sc1\n\t"
        "global_load_dwordx4 %3, %16, off offset:192 sc0 sc1\n\t"
        "global_load_dwordx4 %4, %16, off offset:256 sc0 sc1\n\t"
        "global_load_dwordx4 %5, %16, off offset:320 sc0 sc1\n\t"
        "global_load_dwordx4 %6, %16, off offset:384 sc0 sc1\n\t"
        "global_load_dwordx4 %7, %16, off offset:448 sc0 sc1\n\t"
        "global_load_dwordx4 %8, %16, off offset:512 sc0 sc1\n\t"
        "global_load_dwordx4 %9, %16, off offset:576 sc0 sc1\n\t"
        "global_load_dwordx4 %10, %16, off offset:640 sc0 sc1\n\t"
        "global_load_dwordx4 %11, %16, off offset:704 sc0 sc1\n\t"
        "global_load_dwordx4 %12, %16, off offset:768 sc0 sc1\n\t"
        "global_load_dwordx4 %13, %16, off offset:832 sc0 sc1\n\t"
        "global_load_dwordx4 %14, %16, off offset:896 sc0 sc1\n\t"
        "global_load_dwordx4 %15, %16, off offset:960 sc0 sc1\n\t"
        "s_waitcnt vmcnt(0)"
        : "=v"(r[0]), "=v"(r[1]), "=v"(r[2]), "=v"(r[3]),
          "=v"(r[4]), "=v"(r[5]), "=v"(r[6]), "=v"(r[7]),
          "=v"(r[8]), "=v"(r[9]), "=v"(r[10]), "=v"(r[11]),
          "=v"(r[12]), "=v"(r[13]), "=v"(r[14]), "=v"(r[15])
        : "v"(p) : "memory");
}
__device__ __forceinline__ void cld_f_2(const float* p0, const float* p1,
                                        float& a, float& b)
{
    asm volatile(
        "global_load_dword %0, %2, off sc0 sc1\n\t"
        "global_load_dword %1, %3, off sc0 sc1\n\t"
        "s_waitcnt vmcnt(0)"
        : "=v"(a), "=v"(b) : "v"(p0), "v"(p1) : "memory");
}
__device__ __forceinline__ void cld_f4p(const float* p, f32x4& a, f32x4& b)
{
    asm volatile(
        "global_load_dwordx4 %0, %2, off sc0 sc1\n\t"
        "global_load_dwordx4 %1, %2, off offset:16 sc0 sc1\n\t"
        "s_waitcnt vmcnt(0)"
        : "=v"(a), "=v"(b) : "v"(p) : "memory");
}
__device__ __forceinline__ void cst_f(float* p, float v)
{
    asm volatile("global_store_dword %0, %1, off sc0 sc1"
                 :: "v"(p), "v"(v) : "memory");
}
__device__ __forceinline__ void cst_u32(unsigned* p, unsigned v)
{
    asm volatile("global_store_dword %0, %1, off sc0 sc1"
                 :: "v"(p), "v"(v) : "memory");
}
__device__ __forceinline__ void cst_h(unsigned short* p, unsigned short v)
{
    unsigned vv = v;
    asm volatile("global_store_short %0, %1, off sc0 sc1"
                 :: "v"(p), "v"(vv) : "memory");
}

// ---------------------------------------------------------------------------
// prep: Wbig_bf16 [2560,1024] = [ Wa | 0 ; W_hh | W_ih_x ], Wc_bf16 [2048,512]
// = W_ih_ctx, bbig = [ba ; b_ih+b_hh], plus bf16 copies of Ua, Wout, enc.
// ---------------------------------------------------------------------------
__global__ __launch_bounds__(256)
void prep_w(const float* __restrict__ Wa, const float* __restrict__ Whh,
            const float* __restrict__ Wih,
            const float* __restrict__ ba, const float* __restrict__ bih,
            const float* __restrict__ bhh,
            const float* __restrict__ Ua, const float* __restrict__ Wout,
            const float* __restrict__ enc,
            unsigned short* __restrict__ Wbig, unsigned short* __restrict__ Wc,
            unsigned short* __restrict__ Uab, unsigned short* __restrict__ Woutb,
            unsigned short* __restrict__ encb, float* __restrict__ bbig)
{
    const int stride = gridDim.x * blockDim.x;
    const int t0 = blockIdx.x * blockDim.x + threadIdx.x;
    for (int idx = t0; idx < 2560 * 1024; idx += stride) {
        const int j = idx >> 10, k = idx & 1023;
        float v;
        if (j < H) v = (k < H) ? Wa[j * H + k] : 0.f;
        else { const int n = j - H; v = (k < H) ? Whh[n * H + k] : Wih[n * 2 * H + (k - H)]; }
        Wbig[idx] = f2b(v);
    }
    for (int idx = t0; idx < 2048 * 512; idx += stride) {
        const int n = idx >> 9, k = idx & 511;
        Wc[idx] = f2b(Wih[n * 2 * H + H + k]);
    }
    for (int idx = t0; idx < 512 * 512; idx += stride)   Uab[idx]   = f2b(Ua[idx]);
    for (int idx = t0; idx < V * 512; idx += stride)     Woutb[idx] = f2b(Wout[idx]);
    for (int idx = t0; idx < BB * SS * H; idx += stride) encb[idx]  = f2b(enc[idx]);
    for (int j = t0; j < 2560; j += stride)
        bbig[j] = (j < H) ? ba[j] : bih[j - H] + bhh[j - H];
}

// ---------------------------------------------------------------------------
// Pre-gather teacher-forced inputs: xall[t*B+b][k] = emb[tok(t,b)][k] (bf16)
// ---------------------------------------------------------------------------
__global__ __launch_bounds__(256)
void gather_x(const float* __restrict__ emb, const int* __restrict__ tgt,
              unsigned short* __restrict__ xall)
{
    const int stride = gridDim.x * blockDim.x;
    for (int idx = blockIdx.x * blockDim.x + threadIdx.x; idx < TT * BB * H; idx += stride) {
        const int k = idx & 511;
        const int row = idx >> 9;
        const int t = row >> 7, b = row & 127;
        const int tok = (t == 0) ? 0 : tgt[b * TT + t - 1];
        xall[idx] = f2b(emb[(size_t)tok * H + k]);
    }
}

// ---------------------------------------------------------------------------
// bf16 MFMA NT-GEMM, K=512 fixed: C[m,n] = A[m,:]·B[n,:] (+bias[n] if given).
// OUT_MODE: 0 = f32 (PERMUTE maps r=t*B+b -> b*T+t), 1 = bf16, 2 = fp8 e4m3.
// ---------------------------------------------------------------------------
template<int OUT_MODE, int PERMUTE>
__global__ __launch_bounds__(256, 2)
void gemm_mfma(const unsigned short* __restrict__ A,
               const unsigned short* __restrict__ B,
               const float* __restrict__ bias,
               float* __restrict__ Cf, unsigned short* __restrict__ Cb,
               unsigned char* __restrict__ C8,
               int M, int N)
{
    __shared__ unsigned short As[128][72];
    __shared__ unsigned short Bs[128][72];
    const int tid = threadIdx.x;
    const int m0 = blockIdx.y * 128, n0 = blockIdx.x * 128;
    const int lane = tid & 63, wv = tid >> 6;
    const int qm = (wv >> 1) * 64, qn = (wv & 1) * 64;
    const int fr = lane & 15, fg = lane >> 4;
    f32x4 acc[4][4];
#pragma unroll
    for (int i = 0; i < 4; ++i)
#pragma unroll
        for (int j = 0; j < 4; ++j) acc[i][j] = (f32x4){0.f, 0.f, 0.f, 0.f};

    const int srow = tid >> 3, sc = (tid & 7) * 8;
    for (int k0 = 0; k0 < H; k0 += 64) {
#pragma unroll
        for (int u = 0; u < 4; ++u) {
            const int row = srow + u * 32;
            *(uint4*)&As[row][sc] = *(const uint4*)&A[(size_t)(m0 + row) * H + k0 + sc];
            int nr = n0 + row; if (nr > N - 1) nr = N - 1;
            *(uint4*)&Bs[row][sc] = *(const uint4*)&B[(size_t)nr * H + k0 + sc];
        }
        __syncthreads();
#pragma unroll
        for (int ks = 0; ks < 2; ++ks) {
            const int kk = ks * 32 + fg * 8;
            bf16x8 av[4], bv[4];
#pragma unroll
            for (int i = 0; i < 4; ++i) {
                av[i] = *(const bf16x8*)&As[qm + i * 16 + fr][kk];
                bv[i] = *(const bf16x8*)&Bs[qn + i * 16 + fr][kk];
            }
#pragma unroll
            for (int i = 0; i < 4; ++i)
#pragma unroll
                for (int j = 0; j < 4; ++j)
                    acc[i][j] = __builtin_amdgcn_mfma_f32_16x16x32_bf16(av[i], bv[j], acc[i][j], 0, 0, 0);
        }
        __syncthreads();
    }
#pragma unroll
    for (int i = 0; i < 4; ++i) {
        const int r0 = m0 + qm + i * 16 + fg * 4;
#pragma unroll
        for (int j = 0; j < 4; ++j) {
            const int col = n0 + qn + j * 16 + fr;
            if (col < N) {
                const float bi = bias ? bias[col] : 0.f;
#pragma unroll
                for (int v = 0; v < 4; ++v) {
                    const int r = r0 + v;
                    const float val = acc[i][j][v] + bi;
                    if (OUT_MODE == 1) {
                        Cb[(size_t)r * N + col] = f2b(val);
                    } else if (OUT_MODE == 2) {
                        C8[(size_t)r * N + col] = f2fp8(val);
                    } else {
                        const size_t orow = PERMUTE ? ((size_t)(r & (BB - 1)) * TT + (r >> 7))
                                                    : (size_t)r;
                        Cf[orow * (size_t)N + col] = val;
                    }
                }
            }
        }
    }
}

// ---------------------------------------------------------------------------
// Grid barrier: fence-free relaxed protocol, per-block flag lines, gen
// replicated on 8 lines (~20 pollers each).
// ---------------------------------------------------------------------------
__device__ __forceinline__ void gbar(unsigned* flags, unsigned* gens, unsigned step)
{
    __syncthreads();
    if (blockIdx.x == 0) {
        for (int i = threadIdx.x; i < NB - 1; i += 256) {
            while (__hip_atomic_load(&flags[(i + 1) * 32], __ATOMIC_RELAXED,
                                     __HIP_MEMORY_SCOPE_AGENT) < step)
                __builtin_amdgcn_s_sleep(1);
        }
        __syncthreads();
        if (threadIdx.x < 8)
            __hip_atomic_store(&gens[threadIdx.x * 32], step, __ATOMIC_RELAXED,
                               __HIP_MEMORY_SCOPE_AGENT);
        __syncthreads();
    } else {
        if (threadIdx.x == 0) {
            __hip_atomic_store(&flags[blockIdx.x * 32], step, __ATOMIC_RELAXED,
                               __HIP_MEMORY_SCOPE_AGENT);
            while (__hip_atomic_load(&gens[(blockIdx.x & 7) * 32], __ATOMIC_RELAXED,
                                     __HIP_MEMORY_SCOPE_AGENT) < step)
                __builtin_amdgcn_s_sleep(1);
        }
        __syncthreads();
    }
}

struct PParams {
    const float* h0;
    const float* c0;
    const unsigned short* keysb;  // [B*S][512] bf16 (read-only, L2-cached)
    const unsigned char* encW8;   // [B*S][2048] fp8 (read-only, L2-RESIDENT)
    const float* Va;
    const float* bv;
    const float* bbig;
    const unsigned short* Wbig;   // [2560][1024] bf16
    const unsigned short* xall;   // [T*B][512]   bf16 (read-only)
    unsigned short* hbf;          // [B][512] bf16   -- coherent (cross-block)
    float* Y;                     // [B][2560] f32   -- coherent (cross-block)
    unsigned short* hallb;        // [T*B][512] bf16 (consumed post-kernel)
    float* attn;                  // -> d_out attention block [B][T][S]
    float* out_h;
    float* out_c;
    unsigned* flags;
    unsigned* gens;
};

// ---------------------------------------------------------------------------
// Persistent recurrence kernel (160 blocks, all resident). Per step, TWO
// phases / TWO barriers:
//   P1 (all 160 blocks, 16 j-cols each): Y[b][j] = ([h|x] @ Wbig^T + bbig)
//   P2 (blocks 0..127 = batch b): attention scores+softmax, then
//       gates[n] = Y[b][512+n] + sum_s w[s]*encW8[b,s,n]  (fp8, L2-resident),
//       then LSTM with c[b] resident in LDS; h -> hbf (coherent) + hallb.
// ---------------------------------------------------------------------------
__global__ __launch_bounds__(256, 1)
void persist(PParams p)
{
    __shared__ unsigned short WA[16][1032];
    __shared__ float qa_s[H];
    __shared__ float va_s[H];
    __shared__ float part[SS][4];
    __shared__ float wbuf[SS];
    __shared__ float gbuf[4 * H];
    __shared__ float cs[H];

    const int tid  = threadIdx.x;
    const int beta = blockIdx.x;
    unsigned bs = 1;

    // ---- prologue: h0 -> bf16 (coherent), stage weight slice, init c ----
    for (int i = beta * 256 + tid; i < BB * H; i += NB * 256)
        cst_h(&p.hbf[i], f2b(p.h0[i]));
    {
        const int j0 = beta * 16;
        for (int idx = tid; idx < 16 * 128; idx += 256) {
            const int r = idx >> 7, ch = idx & 127;
            *(uint4*)&WA[r][ch * 8] = *(const uint4*)&p.Wbig[(size_t)(j0 + r) * 1024 + ch * 8];
        }
    }
    if (beta < 128) {
        for (int j = tid; j < H; j += 256) cs[j] = p.c0[beta * H + j];
        for (int i = tid; i < H; i += 256) va_s[i] = p.Va[i];
    }
    gbar(p.flags, p.gens, bs++);

    for (int t = 0; t < TT; ++t) {
        // ---------------- P1: Y[b][j0..j0+15] for all b ----------------
        {
            const int j0 = beta * 16;
            const int wv = tid >> 6, lane = tid & 63;
            const int r = lane & 15, g = lane >> 4;
            const int b0 = wv * 32, b1 = b0 + 16;
            const int ko = g * 8;
            bf16x8 hr0[16], hr1[16];
            cld_row16(p.hbf + (size_t)(b0 + r) * H + ko, hr0);
            cld_row16(p.hbf + (size_t)(b1 + r) * H + ko, hr1);
            f32x4 acc0 = {0.f, 0.f, 0.f, 0.f};
            f32x4 acc1 = {0.f, 0.f, 0.f, 0.f};
#pragma unroll
            for (int ks = 0; ks < 16; ++ks) {
                bf16x8 bf = *(const bf16x8*)&WA[r][ks * 32 + ko];
                acc0 = __builtin_amdgcn_mfma_f32_16x16x32_bf16(hr0[ks], bf, acc0, 0, 0, 0);
                acc1 = __builtin_amdgcn_mfma_f32_16x16x32_bf16(hr1[ks], bf, acc1, 0, 0, 0);
            }
            const unsigned short* x0p = p.xall + ((size_t)t * BB + b0 + r) * H + ko;
            const unsigned short* x1p = p.xall + ((size_t)t * BB + b1 + r) * H + ko;
#pragma unroll
            for (int ks = 0; ks < 16; ++ks) {
                bf16x8 bf = *(const bf16x8*)&WA[r][512 + ks * 32 + ko];
                acc0 = __builtin_amdgcn_mfma_f32_16x16x32_bf16(*(const bf16x8*)&x0p[ks * 32], bf, acc0, 0, 0, 0);
                acc1 = __builtin_amdgcn_mfma_f32_16x16x32_bf16(*(const bf16x8*)&x1p[ks * 32], bf, acc1, 0, 0, 0);
            }
            const float bb = p.bbig[j0 + r];
#pragma unroll
            for (int i = 0; i < 4; ++i) {
                cst_f(p.Y + (size_t)(b0 + g * 4 + i) * 2560 + j0 + r, acc0[i] + bb);
                cst_f(p.Y + (size_t)(b1 + g * 4 + i) * 2560 + j0 + r, acc1[i] + bb);
            }
        }
        gbar(p.flags, p.gens, bs++);

        // ------- P2: attention + ctx-gates + LSTM for batch b = beta -------
        if (beta < 128) {
            const int b = beta;
            const float* yrow = p.Y + (size_t)b * 2560;
            cld_f_2(yrow + tid, yrow + 256 + tid, qa_s[tid], qa_s[tid + 256]);
            __syncthreads();
            // scores
            const int s = tid >> 2, q = tid & 3;
            const unsigned short* kp = p.keysb + ((size_t)b * SS + s) * H + q * 128;
            const float* qp = qa_s + q * 128;
            const float* vp = va_s + q * 128;
            float a2 = 0.f;
#pragma unroll 4
            for (int i = 0; i < 128; ++i)
                a2 += ftanh(qp[i] + b2f(kp[i])) * vp[i];
            part[s][q] = a2;
            __syncthreads();
            if (tid < 64) {
                float sc = part[tid][0] + part[tid][1] + part[tid][2] + part[tid][3] + p.bv[0];
                float m = sc;
                for (int o = 32; o; o >>= 1) m = fmaxf(m, __shfl_xor(m, o));
                const float e = __expf(sc - m);
                float ss = e;
                for (int o = 32; o; o >>= 1) ss += __shfl_xor(ss, o);
                const float w = e / ss;
                wbuf[tid] = w;
                p.attn[((size_t)b * TT + t) * SS + tid] = w;
            }
            __syncthreads();
            // gates_ctx via fp8 encW weighted sum; 8 n per thread, s unrolled
            {
                float gc[8] = {0.f, 0.f, 0.f, 0.f, 0.f, 0.f, 0.f, 0.f};
                const unsigned char* ew = p.encW8 + (size_t)b * SS * 2048 + tid * 8;
#pragma unroll 8
                for (int s2 = 0; s2 < SS; ++s2) {
                    const float w2 = wbuf[s2];
                    const uint2 u = *(const uint2*)(ew + (size_t)s2 * 2048);
                    const f32x2 e01 = __builtin_amdgcn_cvt_pk_f32_fp8(u.x, 0);
                    const f32x2 e23 = __builtin_amdgcn_cvt_pk_f32_fp8(u.x, 1);
                    const f32x2 e45 = __builtin_amdgcn_cvt_pk_f32_fp8(u.y, 0);
                    const f32x2 e67 = __builtin_amdgcn_cvt_pk_f32_fp8(u.y, 1);
                    gc[0] += w2 * e01[0]; gc[1] += w2 * e01[1];
                    gc[2] += w2 * e23[0]; gc[3] += w2 * e23[1];
                    gc[4] += w2 * e45[0]; gc[5] += w2 * e45[1];
                    gc[6] += w2 * e67[0]; gc[7] += w2 * e67[1];
                }
                f32x4 y0, y1;
                cld_f4p(yrow + 512 + tid * 8, y0, y1);
#pragma unroll
                for (int i = 0; i < 4; ++i) {
                    gbuf[tid * 8 + i]     = gc[i] + y0[i];
                    gbuf[tid * 8 + 4 + i] = gc[4 + i] + y1[i];
                }
            }
            __syncthreads();
            // LSTM: cells 2*tid, 2*tid+1
            {
                const int last = (t == TT - 1);
                unsigned hpack = 0;
                float hn2[2], cn2[2];
#pragma unroll
                for (int u = 0; u < 2; ++u) {
                    const int j = tid * 2 + u;
                    const float ig = gbuf[j];
                    const float fg = gbuf[512 + j];
                    const float gg = gbuf[1024 + j];
                    const float og = gbuf[1536 + j];
                    const float co = cs[j];
                    const float cn = fsig(fg) * co + fsig(ig) * ftanh(gg);
                    const float hn = fsig(og) * ftanh(cn);
                    cs[j] = cn;
                    hn2[u] = hn; cn2[u] = cn;
                    hpack |= ((unsigned)f2b(hn)) << (16 * u);
                }
                cst_u32((unsigned*)&p.hbf[b * H + tid * 2], hpack);
                *(unsigned*)&p.hallb[((size_t)t * BB + b) * H + tid * 2] = hpack;
                if (last) {
#pragma unroll
                    for (int u = 0; u < 2; ++u) {
                        p.out_h[b * H + tid * 2 + u] = hn2[u];
                        p.out_c[b * H + tid * 2 + u] = cn2[u];
                    }
                }
            }
        }
        gbar(p.flags, p.gens, bs++);
    }
}

// ---------------------------------------------------------------------------
// In-place log-softmax over each row of 5000 logits.
// ---------------------------------------------------------------------------
__global__ __launch_bounds__(256)
void logsoftmax_rows(float* __restrict__ P)
{
    __shared__ float red[256];
    float* p = P + (size_t)blockIdx.x * V;
    const int tid = threadIdx.x;
    float m = -1e30f;
    for (int i = tid; i < V; i += 256) m = fmaxf(m, p[i]);
    red[tid] = m; __syncthreads();
    for (int sft = 128; sft; sft >>= 1) {
        if (tid < sft) red[tid] = fmaxf(red[tid], red[tid + sft]);
        __syncthreads();
    }
    m = red[0]; __syncthreads();
    float ssum = 0.f;
    for (int i = tid; i < V; i += 256) ssum += __expf(p[i] - m);
    red[tid] = ssum; __syncthreads();
    for (int sft = 128; sft; sft >>= 1) {
        if (tid < sft) red[tid] += red[tid + sft];
        __syncthreads();
    }
    const float lse = m + __logf(red[0]);
    for (int i = tid; i < V; i += 256) p[i] -= lse;
}

// ---------------------------------------------------------------------------
extern "C" void kernel_launch(void* const* d_in, const int* in_sizes, int n_in,
                              void* d_out, int out_size, void* d_ws, size_t ws_size,
                              hipStream_t stream)
{
    (void)in_sizes; (void)n_in; (void)out_size; (void)ws_size;
    const float* enc  = (const float*)d_in[0];
    const float* h0   = (const float*)d_in[1];
    const float* c0   = (const float*)d_in[2];
    const int*   tgt  = (const int*)  d_in[3];
    const float* emb  = (const float*)d_in[4];
    const float* Wa   = (const float*)d_in[5];
    const float* ba   = (const float*)d_in[6];
    const float* Ua   = (const float*)d_in[7];
    const float* bu   = (const float*)d_in[8];
    const float* Va   = (const float*)d_in[9];
    const float* bv   = (const float*)d_in[10];
    const float* Wih  = (const float*)d_in[11];
    const float* Whh  = (const float*)d_in[12];
    const float* bih  = (const float*)d_in[13];
    const float* bhh  = (const float*)d_in[14];
    const float* Wout = (const float*)d_in[15];
    const float* bout = (const float*)d_in[16];

    float* ws = (float*)d_ws;
    float* Y    = ws;                                      // 327,680 f32
    float* bbig = Y + 327680;                              // 2,560 f32
    unsigned* flags = (unsigned*)(bbig + 2560);            // 5,504 u32 (incl gens)
    unsigned short* Wbig  = (unsigned short*)(flags + 5504);   // 2,621,440 u16
    unsigned short* Wc    = Wbig + 2621440;                // 1,048,576
    unsigned short* Uab   = Wc + 1048576;                  // 262,144
    unsigned short* Woutb = Uab + 262144;                  // 2,560,000
    unsigned short* encb  = Woutb + 2560000;               // 4,194,304
    unsigned short* keysb = encb + 4194304;                // 4,194,304
    unsigned short* xall  = keysb + 4194304;               // 3,407,872
    unsigned short* hallb = xall + 3407872;                // 3,407,872
    unsigned short* hbf   = hallb + 3407872;               // 65,536
    unsigned char*  encW8 = (unsigned char*)(hbf + 65536); // 16,777,216 u8

    float* out    = (float*)d_out;
    float* out_h  = out + (size_t)BB * TT * V;
    float* out_c  = out_h + BB * H;
    float* out_at = out_c + BB * H;

    hipMemsetAsync(flags, 0, 5504 * sizeof(unsigned), stream);

    prep_w<<<dim3(2048), dim3(256), 0, stream>>>(
        Wa, Whh, Wih, ba, bih, bhh, Ua, Wout, enc, Wbig, Wc, Uab, Woutb, encb, bbig);
    gather_x<<<dim3(512), dim3(256), 0, stream>>>(emb, tgt, xall);

    // keys_proj = enc @ Ua^T + bu  -> bf16 [8192,512]
    gemm_mfma<1, 0><<<dim3(4, 64), dim3(256), 0, stream>>>(
        encb, Uab, bu, nullptr, keysb, nullptr, BB * SS, H);
    // encW8 = enc @ Wc^T -> fp8 [8192,2048]  (L2-resident per-XCD slices)
    gemm_mfma<2, 0><<<dim3(16, 64), dim3(256), 0, stream>>>(
        encb, Wc, nullptr, nullptr, nullptr, encW8, BB * SS, 2048);

    PParams pp;
    pp.h0 = h0; pp.c0 = c0; pp.keysb = keysb; pp.encW8 = encW8;
    pp.Va = Va; pp.bv = bv; pp.bbig = bbig;
    pp.Wbig = Wbig; pp.xall = xall;
    pp.hbf = hbf; pp.Y = Y; pp.hallb = hallb;
    pp.attn = out_at; pp.out_h = out_h; pp.out_c = out_c;
    pp.flags = flags; pp.gens = flags + 5120;
    persist<<<dim3(NB), dim3(256), 0, stream>>>(pp);

    // logits: hallb[6656,512] @ Woutb^T + bout -> out[b,t,:], then log-softmax
    gemm_mfma<0, 1><<<dim3(40, 52), dim3(256), 0, stream>>>(
        hallb, Woutb, bout, out, nullptr, nullptr, TT * BB, V);
    logsoftmax_rows<<<dim3(BB * TT), dim3(256), 0, stream>>>(out);
}

// Round 8
// 1465.152 us; speedup vs baseline: 7.4791x; 1.0900x over previous
//
#include <hip/hip_runtime.h>
#include <math.h>

#define H 512
#define V 5000
#define BB 128
#define SS 64
#define TT 52
#define NB 160   // persistent grid size (2560/16 col-groups)

typedef __attribute__((ext_vector_type(8))) short bf16x8;
typedef __attribute__((ext_vector_type(4))) float f32x4;
typedef __attribute__((ext_vector_type(2))) float f32x2;

__device__ __forceinline__ unsigned short f2b(float f) {
    unsigned u = __float_as_uint(f);
    return (unsigned short)((u + 0x7fffu + ((u >> 16) & 1u)) >> 16);
}
__device__ __forceinline__ float b2f(unsigned short u) {
    return __uint_as_float((unsigned)u << 16);
}
__device__ __forceinline__ float ftanh(float x) {
    return 1.f - 2.f / (1.f + __expf(2.f * x));
}
__device__ __forceinline__ float fsig(float x) {
    return 1.f / (1.f + __expf(-x));
}
__device__ __forceinline__ unsigned char f2fp8(float f) {
    return (unsigned char)__builtin_amdgcn_cvt_pk_fp8_f32(f, f, 0, 0);
}

// ---------------------------------------------------------------------------
// Coherent (L1/L2-bypassing, L3-coherence-point) accesses; no cache-
// maintenance fences needed around the grid barrier (validated r4->r7).
// ---------------------------------------------------------------------------
__device__ __forceinline__ void cld_row16(const unsigned short* p, bf16x8* r)
{
    asm volatile(
        "global_load_dwordx4 %0, %16, off sc0 sc1\n\t"
        "global_load_dwordx4 %1, %16, off offset:64 sc0 sc1\n\t"
        "global_load_dwordx4 %2, %16, off offset:128 sc0 sc1\n\t"
        "global_load_dwordx4 %3, %16, off offset:192 sc0 sc1\n\t"
        "global_load_dwordx4 %4, %16, off offset:256 sc0 sc1\n\t"
        "global_load_dwordx4 %5, %16, off offset:320 sc0 sc1\n\t"
        "global_load_dwordx4 %6, %16, off offset:384 sc0 sc1\n\t"
        "global_load_dwordx4 %7, %16, off offset:448 sc0 sc1\n\t"
        "global_load_dwordx4 %8, %16, off offset:512 sc0 sc1\n\t"
        "global_load_dwordx4 %9, %16, off offset:576 sc0 sc1\n\t"
        "global_load_dwordx4 %10, %16, off offset:640 sc0 sc1\n\t"
        "global_load_dwordx4 %11, %16, off offset:704 sc0 sc1\n\t"
        "global_load_dwordx4 %12, %16, off offset:768 sc0 sc1\n\t"
        "global_load_dwordx4 %13, %16, off offset:832 sc0 sc1\n\t"
        "global_load_dwordx4 %14, %16, off offset:896 sc0 sc1\n\t"
        "global_load_dwordx4 %15, %16, off offset:960 sc0 sc1\n\t"
        "s_waitcnt vmcnt(0)"
        : "=v"(r[0]), "=v"(r[1]), "=v"(r[2]), "=v"(r[3]),
          "=v"(r[4]), "=v"(r[5]), "=v"(r[6]), "=v"(r[7]),
          "=v"(r[8]), "=v"(r[9]), "=v"(r[10]), "=v"(r[11]),
          "=v"(r[12]), "=v"(r[13]), "=v"(r[14]), "=v"(r[15])
        : "v"(p) : "memory");
}
__device__ __forceinline__ void cld_f_2(const float* p0, const float* p1,
                                        float& a, float& b)
{
    asm volatile(
        "global_load_dword %0, %2, off sc0 sc1\n\t"
        "global_load_dword %1, %3, off sc0 sc1\n\t"
        "s_waitcnt vmcnt(0)"
        : "=v"(a), "=v"(b) : "v"(p0), "v"(p1) : "memory");
}
__device__ __forceinline__ void cld_f4p(const float* p, f32x4& a, f32x4& b)
{
    asm volatile(
        "global_load_dwordx4 %0, %2, off sc0 sc1\n\t"
        "global_load_dwordx4 %1, %2, off offset:16 sc0 sc1\n\t"
        "s_waitcnt vmcnt(0)"
        : "=v"(a), "=v"(b) : "v"(p) : "memory");
}
__device__ __forceinline__ void cst_f(float* p, float v)
{
    asm volatile("global_store_dword %0, %1, off sc0 sc1"
                 :: "v"(p), "v"(v) : "memory");
}
__device__ __forceinline__ void cst_u32(unsigned* p, unsigned v)
{
    asm volatile("global_store_dword %0, %1, off sc0 sc1"
                 :: "v"(p), "v"(v) : "memory");
}
__device__ __forceinline__ void cst_h(unsigned short* p, unsigned short v)
{
    unsigned vv = v;
    asm volatile("global_store_short %0, %1, off sc0 sc1"
                 :: "v"(p), "v"(vv) : "memory");
}

// ---------------------------------------------------------------------------
// prep: Wbig_bf16 [2560,1024] = [ Wa | 0 ; W_hh | W_ih_x ], Wc_bf16 [2048,512]
// = W_ih_ctx, bbig = [ba ; b_ih+b_hh], plus bf16 copies of Ua, Wout, enc.
// ---------------------------------------------------------------------------
__global__ __launch_bounds__(256)
void prep_w(const float* __restrict__ Wa, const float* __restrict__ Whh,
            const float* __restrict__ Wih,
            const float* __restrict__ ba, const float* __restrict__ bih,
            const float* __restrict__ bhh,
            const float* __restrict__ Ua, const float* __restrict__ Wout,
            const float* __restrict__ enc,
            unsigned short* __restrict__ Wbig, unsigned short* __restrict__ Wc,
            unsigned short* __restrict__ Uab, unsigned short* __restrict__ Woutb,
            unsigned short* __restrict__ encb, float* __restrict__ bbig)
{
    const int stride = gridDim.x * blockDim.x;
    const int t0 = blockIdx.x * blockDim.x + threadIdx.x;
    for (int idx = t0; idx < 2560 * 1024; idx += stride) {
        const int j = idx >> 10, k = idx & 1023;
        float v;
        if (j < H) v = (k < H) ? Wa[j * H + k] : 0.f;
        else { const int n = j - H; v = (k < H) ? Whh[n * H + k] : Wih[n * 2 * H + (k - H)]; }
        Wbig[idx] = f2b(v);
    }
    for (int idx = t0; idx < 2048 * 512; idx += stride) {
        const int n = idx >> 9, k = idx & 511;
        Wc[idx] = f2b(Wih[n * 2 * H + H + k]);
    }
    for (int idx = t0; idx < 512 * 512; idx += stride)   Uab[idx]   = f2b(Ua[idx]);
    for (int idx = t0; idx < V * 512; idx += stride)     Woutb[idx] = f2b(Wout[idx]);
    for (int idx = t0; idx < BB * SS * H; idx += stride) encb[idx]  = f2b(enc[idx]);
    for (int j = t0; j < 2560; j += stride)
        bbig[j] = (j < H) ? ba[j] : bih[j - H] + bhh[j - H];
}

// ---------------------------------------------------------------------------
// Pre-gather teacher-forced inputs: xall[t*B+b][k] = emb[tok(t,b)][k] (bf16)
// ---------------------------------------------------------------------------
__global__ __launch_bounds__(256)
void gather_x(const float* __restrict__ emb, const int* __restrict__ tgt,
              unsigned short* __restrict__ xall)
{
    const int stride = gridDim.x * blockDim.x;
    for (int idx = blockIdx.x * blockDim.x + threadIdx.x; idx < TT * BB * H; idx += stride) {
        const int k = idx & 511;
        const int row = idx >> 9;
        const int t = row >> 7, b = row & 127;
        const int tok = (t == 0) ? 0 : tgt[b * TT + t - 1];
        xall[idx] = f2b(emb[(size_t)tok * H + k]);
    }
}

// ---------------------------------------------------------------------------
// bf16 MFMA NT-GEMM, K=512 fixed: C[m,n] = A[m,:]·B[n,:] (+bias[n] if given).
// OUT_MODE: 0 = f32 (PERMUTE maps r=t*B+b -> b*T+t), 1 = bf16, 2 = fp8 e4m3.
// ---------------------------------------------------------------------------
template<int OUT_MODE, int PERMUTE>
__global__ __launch_bounds__(256, 2)
void gemm_mfma(const unsigned short* __restrict__ A,
               const unsigned short* __restrict__ B,
               const float* __restrict__ bias,
               float* __restrict__ Cf, unsigned short* __restrict__ Cb,
               unsigned char* __restrict__ C8,
               int M, int N)
{
    __shared__ unsigned short As[128][72];
    __shared__ unsigned short Bs[128][72];
    const int tid = threadIdx.x;
    const int m0 = blockIdx.y * 128, n0 = blockIdx.x * 128;
    const int lane = tid & 63, wv = tid >> 6;
    const int qm = (wv >> 1) * 64, qn = (wv & 1) * 64;
    const int fr = lane & 15, fg = lane >> 4;
    f32x4 acc[4][4];
#pragma unroll
    for (int i = 0; i < 4; ++i)
#pragma unroll
        for (int j = 0; j < 4; ++j) acc[i][j] = (f32x4){0.f, 0.f, 0.f, 0.f};

    const int srow = tid >> 3, sc = (tid & 7) * 8;
    for (int k0 = 0; k0 < H; k0 += 64) {
#pragma unroll
        for (int u = 0; u < 4; ++u) {
            const int row = srow + u * 32;
            *(uint4*)&As[row][sc] = *(const uint4*)&A[(size_t)(m0 + row) * H + k0 + sc];
            int nr = n0 + row; if (nr > N - 1) nr = N - 1;
            *(uint4*)&Bs[row][sc] = *(const uint4*)&B[(size_t)nr * H + k0 + sc];
        }
        __syncthreads();
#pragma unroll
        for (int ks = 0; ks < 2; ++ks) {
            const int kk = ks * 32 + fg * 8;
            bf16x8 av[4], bv[4];
#pragma unroll
            for (int i = 0; i < 4; ++i) {
                av[i] = *(const bf16x8*)&As[qm + i * 16 + fr][kk];
                bv[i] = *(const bf16x8*)&Bs[qn + i * 16 + fr][kk];
            }
#pragma unroll
            for (int i = 0; i < 4; ++i)
#pragma unroll
                for (int j = 0; j < 4; ++j)
                    acc[i][j] = __builtin_amdgcn_mfma_f32_16x16x32_bf16(av[i], bv[j], acc[i][j], 0, 0, 0);
        }
        __syncthreads();
    }
#pragma unroll
    for (int i = 0; i < 4; ++i) {
        const int r0 = m0 + qm + i * 16 + fg * 4;
#pragma unroll
        for (int j = 0; j < 4; ++j) {
            const int col = n0 + qn + j * 16 + fr;
            if (col < N) {
                const float bi = bias ? bias[col] : 0.f;
#pragma unroll
                for (int v = 0; v < 4; ++v) {
                    const int r = r0 + v;
                    const float val = acc[i][j][v] + bi;
                    if (OUT_MODE == 1) {
                        Cb[(size_t)r * N + col] = f2b(val);
                    } else if (OUT_MODE == 2) {
                        C8[(size_t)r * N + col] = f2fp8(val);
                    } else {
                        const size_t orow = PERMUTE ? ((size_t)(r & (BB - 1)) * TT + (r >> 7))
                                                    : (size_t)r;
                        Cf[orow * (size_t)N + col] = val;
                    }
                }
            }
        }
    }
}

// ---------------------------------------------------------------------------
// Single-hop barrier primitives (v6). flags[i*32] is block i's monotonic step
// counter. signal: publish my flag (after __syncthreads drains my stores).
// wait_flags: all 256 threads directly poll a range of flags -- no central
// aggregator hop (round-7's two-hop protocol paid 2 poll-discovery latencies).
// Split waits let P2 overlap its scores compute with the slower producers.
// ---------------------------------------------------------------------------
__device__ __forceinline__ void signal_flag(unsigned* flags, unsigned step)
{
    __syncthreads();   // all my threads' phase stores drained (vmcnt 0)
    if (threadIdx.x == 0)
        __hip_atomic_store(&flags[blockIdx.x * 32], step, __ATOMIC_RELAXED,
                           __HIP_MEMORY_SCOPE_AGENT);
}
__device__ __forceinline__ void wait_flags(unsigned* flags, int lo, int hi,
                                           unsigned step)
{
    for (int i = lo + (int)threadIdx.x; i < hi; i += 256) {
        while (__hip_atomic_load(&flags[i * 32], __ATOMIC_RELAXED,
                                 __HIP_MEMORY_SCOPE_AGENT) < step)
            __builtin_amdgcn_s_sleep(1);
    }
    __syncthreads();
}

struct PParams {
    const float* h0;
    const float* c0;
    const unsigned short* keysb;  // [B*S][512] bf16 (read-only, L2-cached)
    const unsigned char* encW8;   // [B*S][2048] fp8 (read-only, L2-resident)
    const float* Va;
    const float* bv;
    const float* bbig;
    const unsigned short* Wbig;   // [2560][1024] bf16
    const unsigned short* xall;   // [T*B][512]   bf16 (read-only)
    unsigned short* hbf;          // [B][512] bf16   -- coherent (cross-block)
    float* Y;                     // [B][2560] f32   -- coherent (cross-block)
    unsigned short* hallb;        // [T*B][512] bf16 (consumed post-kernel)
    float* attn;                  // -> d_out attention block [B][T][S]
    float* out_h;
    float* out_c;
    unsigned* flags;
};

// ---------------------------------------------------------------------------
// Persistent recurrence kernel (160 blocks, all resident). Per step:
//   P1 (all 160 blocks, 16 j-cols each): Y[b][j] = ([h|x] @ Wbig^T + bbig)
//   signal -> P2 blocks wait qa-producers (0..31), compute scores/softmax,
//   wait gate-producers (32..159), gates + LSTM, signal -> full wait.
// ---------------------------------------------------------------------------
__global__ __launch_bounds__(256, 1)
void persist(PParams p)
{
    __shared__ unsigned short WA[16][1032];
    __shared__ float qa_s[H];
    __shared__ float va_s[H];
    __shared__ float part[SS][4];
    __shared__ float wbuf[SS];
    __shared__ float gbuf[4 * H];
    __shared__ float cs[H];

    const int tid  = threadIdx.x;
    const int beta = blockIdx.x;
    unsigned bs = 1;

    // ---- prologue: h0 -> bf16 (coherent), stage weight slice, init c ----
    for (int i = beta * 256 + tid; i < BB * H; i += NB * 256)
        cst_h(&p.hbf[i], f2b(p.h0[i]));
    {
        const int j0 = beta * 16;
        for (int idx = tid; idx < 16 * 128; idx += 256) {
            const int r = idx >> 7, ch = idx & 127;
            *(uint4*)&WA[r][ch * 8] = *(const uint4*)&p.Wbig[(size_t)(j0 + r) * 1024 + ch * 8];
        }
    }
    if (beta < 128) {
        for (int j = tid; j < H; j += 256) cs[j] = p.c0[beta * H + j];
        for (int i = tid; i < H; i += 256) va_s[i] = p.Va[i];
    }
    signal_flag(p.flags, bs);
    wait_flags(p.flags, 0, NB, bs);
    ++bs;

    for (int t = 0; t < TT; ++t) {
        // ---------------- P1: Y[b][j0..j0+15] for all b ----------------
        {
            const int j0 = beta * 16;
            const int wv = tid >> 6, lane = tid & 63;
            const int r = lane & 15, g = lane >> 4;
            const int b0 = wv * 32, b1 = b0 + 16;
            const int ko = g * 8;
            bf16x8 hr0[16], hr1[16];
            cld_row16(p.hbf + (size_t)(b0 + r) * H + ko, hr0);
            cld_row16(p.hbf + (size_t)(b1 + r) * H + ko, hr1);
            f32x4 acc0 = {0.f, 0.f, 0.f, 0.f};
            f32x4 acc1 = {0.f, 0.f, 0.f, 0.f};
#pragma unroll
            for (int ks = 0; ks < 16; ++ks) {
                bf16x8 bf = *(const bf16x8*)&WA[r][ks * 32 + ko];
                acc0 = __builtin_amdgcn_mfma_f32_16x16x32_bf16(hr0[ks], bf, acc0, 0, 0, 0);
                acc1 = __builtin_amdgcn_mfma_f32_16x16x32_bf16(hr1[ks], bf, acc1, 0, 0, 0);
            }
            const unsigned short* x0p = p.xall + ((size_t)t * BB + b0 + r) * H + ko;
            const unsigned short* x1p = p.xall + ((size_t)t * BB + b1 + r) * H + ko;
#pragma unroll
            for (int ks = 0; ks < 16; ++ks) {
                bf16x8 bf = *(const bf16x8*)&WA[r][512 + ks * 32 + ko];
                acc0 = __builtin_amdgcn_mfma_f32_16x16x32_bf16(*(const bf16x8*)&x0p[ks * 32], bf, acc0, 0, 0, 0);
                acc1 = __builtin_amdgcn_mfma_f32_16x16x32_bf16(*(const bf16x8*)&x1p[ks * 32], bf, acc1, 0, 0, 0);
            }
            const float bb = p.bbig[j0 + r];
#pragma unroll
            for (int i = 0; i < 4; ++i) {
                cst_f(p.Y + (size_t)(b0 + g * 4 + i) * 2560 + j0 + r, acc0[i] + bb);
                cst_f(p.Y + (size_t)(b1 + g * 4 + i) * 2560 + j0 + r, acc1[i] + bb);
            }
        }
        signal_flag(p.flags, bs);

        // ------- P2: attention + ctx-gates + LSTM for batch b = beta -------
        if (beta < 128) {
            const int b = beta;
            const float* yrow = p.Y + (size_t)b * 2560;
            wait_flags(p.flags, 0, 32, bs);          // qa producers ready
            cld_f_2(yrow + tid, yrow + 256 + tid, qa_s[tid], qa_s[tid + 256]);
            __syncthreads();
            // scores (2-way ILP on the serial FMA/tanh chain)
            const int s = tid >> 2, q = tid & 3;
            const unsigned short* kp = p.keysb + ((size_t)b * SS + s) * H + q * 128;
            const float* qp = qa_s + q * 128;
            const float* vp = va_s + q * 128;
            float a2 = 0.f, a2b = 0.f;
#pragma unroll 4
            for (int i = 0; i < 128; i += 2) {
                a2  += ftanh(qp[i] + b2f(kp[i])) * vp[i];
                a2b += ftanh(qp[i + 1] + b2f(kp[i + 1])) * vp[i + 1];
            }
            part[s][q] = a2 + a2b;
            __syncthreads();
            if (tid < 64) {
                float sc = part[tid][0] + part[tid][1] + part[tid][2] + part[tid][3] + p.bv[0];
                float m = sc;
                for (int o = 32; o; o >>= 1) m = fmaxf(m, __shfl_xor(m, o));
                const float e = __expf(sc - m);
                float ss = e;
                for (int o = 32; o; o >>= 1) ss += __shfl_xor(ss, o);
                const float w = e / ss;
                wbuf[tid] = w;
                p.attn[((size_t)b * TT + t) * SS + tid] = w;
            }
            wait_flags(p.flags, 32, NB, bs);         // gate producers ready
            // gates_ctx via fp8 encW weighted sum; 8 n per thread
            {
                float gc[8] = {0.f, 0.f, 0.f, 0.f, 0.f, 0.f, 0.f, 0.f};
                const unsigned char* ew = p.encW8 + (size_t)b * SS * 2048 + tid * 8;
#pragma unroll 8
                for (int s2 = 0; s2 < SS; ++s2) {
                    const float w2 = wbuf[s2];
                    const uint2 u = *(const uint2*)(ew + (size_t)s2 * 2048);
                    const f32x2 e01 = __builtin_amdgcn_cvt_pk_f32_fp8(u.x, 0);
                    const f32x2 e23 = __builtin_amdgcn_cvt_pk_f32_fp8(u.x, 1);
                    const f32x2 e45 = __builtin_amdgcn_cvt_pk_f32_fp8(u.y, 0);
                    const f32x2 e67 = __builtin_amdgcn_cvt_pk_f32_fp8(u.y, 1);
                    gc[0] += w2 * e01[0]; gc[1] += w2 * e01[1];
                    gc[2] += w2 * e23[0]; gc[3] += w2 * e23[1];
                    gc[4] += w2 * e45[0]; gc[5] += w2 * e45[1];
                    gc[6] += w2 * e67[0]; gc[7] += w2 * e67[1];
                }
                f32x4 y0, y1;
                cld_f4p(yrow + 512 + tid * 8, y0, y1);
#pragma unroll
                for (int i = 0; i < 4; ++i) {
                    gbuf[tid * 8 + i]     = gc[i] + y0[i];
                    gbuf[tid * 8 + 4 + i] = gc[4 + i] + y1[i];
                }
            }
            __syncthreads();
            // LSTM: cells 2*tid, 2*tid+1
            {
                const int last = (t == TT - 1);
                unsigned hpack = 0;
                float hn2[2], cn2[2];
#pragma unroll
                for (int u = 0; u < 2; ++u) {
                    const int j = tid * 2 + u;
                    const float ig = gbuf[j];
                    const float fg = gbuf[512 + j];
                    const float gg = gbuf[1024 + j];
                    const float og = gbuf[1536 + j];
                    const float co = cs[j];
                    const float cn = fsig(fg) * co + fsig(ig) * ftanh(gg);
                    const float hn = fsig(og) * ftanh(cn);
                    cs[j] = cn;
                    hn2[u] = hn; cn2[u] = cn;
                    hpack |= ((unsigned)f2b(hn)) << (16 * u);
                }
                cst_u32((unsigned*)&p.hbf[b * H + tid * 2], hpack);
                *(unsigned*)&p.hallb[((size_t)t * BB + b) * H + tid * 2] = hpack;
                if (last) {
#pragma unroll
                    for (int u = 0; u < 2; ++u) {
                        p.out_h[b * H + tid * 2 + u] = hn2[u];
                        p.out_c[b * H + tid * 2 + u] = cn2[u];
                    }
                }
            }
        }
        signal_flag(p.flags, bs + 1);
        wait_flags(p.flags, 0, NB, bs + 1);
        bs += 2;
    }
}

// ---------------------------------------------------------------------------
// In-place log-softmax over each row of 5000 logits.
// ---------------------------------------------------------------------------
__global__ __launch_bounds__(256)
void logsoftmax_rows(float* __restrict__ P)
{
    __shared__ float red[256];
    float* p = P + (size_t)blockIdx.x * V;
    const int tid = threadIdx.x;
    float m = -1e30f;
    for (int i = tid; i < V; i += 256) m = fmaxf(m, p[i]);
    red[tid] = m; __syncthreads();
    for (int sft = 128; sft; sft >>= 1) {
        if (tid < sft) red[tid] = fmaxf(red[tid], red[tid + sft]);
        __syncthreads();
    }
    m = red[0]; __syncthreads();
    float ssum = 0.f;
    for (int i = tid; i < V; i += 256) ssum += __expf(p[i] - m);
    red[tid] = ssum; __syncthreads();
    for (int sft = 128; sft; sft >>= 1) {
        if (tid < sft) red[tid] += red[tid + sft];
        __syncthreads();
    }
    const float lse = m + __logf(red[0]);
    for (int i = tid; i < V; i += 256) p[i] -= lse;
}

// ---------------------------------------------------------------------------
extern "C" void kernel_launch(void* const* d_in, const int* in_sizes, int n_in,
                              void* d_out, int out_size, void* d_ws, size_t ws_size,
                              hipStream_t stream)
{
    (void)in_sizes; (void)n_in; (void)out_size; (void)ws_size;
    const float* enc  = (const float*)d_in[0];
    const float* h0   = (const float*)d_in[1];
    const float* c0   = (const float*)d_in[2];
    const int*   tgt  = (const int*)  d_in[3];
    const float* emb  = (const float*)d_in[4];
    const float* Wa   = (const float*)d_in[5];
    const float* ba   = (const float*)d_in[6];
    const float* Ua   = (const float*)d_in[7];
    const float* bu   = (const float*)d_in[8];
    const float* Va   = (const float*)d_in[9];
    const float* bv   = (const float*)d_in[10];
    const float* Wih  = (const float*)d_in[11];
    const float* Whh  = (const float*)d_in[12];
    const float* bih  = (const float*)d_in[13];
    const float* bhh  = (const float*)d_in[14];
    const float* Wout = (const float*)d_in[15];
    const float* bout = (const float*)d_in[16];

    float* ws = (float*)d_ws;
    float* Y    = ws;                                      // 327,680 f32
    float* bbig = Y + 327680;                              // 2,560 f32
    unsigned* flags = (unsigned*)(bbig + 2560);            // 5,504 u32
    unsigned short* Wbig  = (unsigned short*)(flags + 5504);   // 2,621,440 u16
    unsigned short* Wc    = Wbig + 2621440;                // 1,048,576
    unsigned short* Uab   = Wc + 1048576;                  // 262,144
    unsigned short* Woutb = Uab + 262144;                  // 2,560,000
    unsigned short* encb  = Woutb + 2560000;               // 4,194,304
    unsigned short* keysb = encb + 4194304;                // 4,194,304
    unsigned short* xall  = keysb + 4194304;               // 3,407,872
    unsigned short* hallb = xall + 3407872;                // 3,407,872
    unsigned short* hbf   = hallb + 3407872;               // 65,536
    unsigned char*  encW8 = (unsigned char*)(hbf + 65536); // 16,777,216 u8

    float* out    = (float*)d_out;
    float* out_h  = out + (size_t)BB * TT * V;
    float* out_c  = out_h + BB * H;
    float* out_at = out_c + BB * H;

    hipMemsetAsync(flags, 0, 5504 * sizeof(unsigned), stream);

    prep_w<<<dim3(2048), dim3(256), 0, stream>>>(
        Wa, Whh, Wih, ba, bih, bhh, Ua, Wout, enc, Wbig, Wc, Uab, Woutb, encb, bbig);
    gather_x<<<dim3(512), dim3(256), 0, stream>>>(emb, tgt, xall);

    // keys_proj = enc @ Ua^T + bu  -> bf16 [8192,512]
    gemm_mfma<1, 0><<<dim3(4, 64), dim3(256), 0, stream>>>(
        encb, Uab, bu, nullptr, keysb, nullptr, BB * SS, H);
    // encW8 = enc @ Wc^T -> fp8 [8192,2048]  (L2-resident per-XCD slices)
    gemm_mfma<2, 0><<<dim3(16, 64), dim3(256), 0, stream>>>(
        encb, Wc, nullptr, nullptr, nullptr, encW8, BB * SS, 2048);

    PParams pp;
    pp.h0 = h0; pp.c0 = c0; pp.keysb = keysb; pp.encW8 = encW8;
    pp.Va = Va; pp.bv = bv; pp.bbig = bbig;
    pp.Wbig = Wbig; pp.xall = xall;
    pp.hbf = hbf; pp.Y = Y; pp.hallb = hallb;
    pp.attn = out_at; pp.out_h = out_h; pp.out_c = out_c;
    pp.flags = flags;
    persist<<<dim3(NB), dim3(256), 0, stream>>>(pp);

    // logits: hallb[6656,512] @ Woutb^T + bout -> out[b,t,:], then log-softmax
    gemm_mfma<0, 1><<<dim3(40, 52), dim3(256), 0, stream>>>(
        hallb, Woutb, bout, out, nullptr, nullptr, TT * BB, V);
    logsoftmax_rows<<<dim3(BB * TT), dim3(256), 0, stream>>>(out);
}

// Round 9
// 1444.401 us; speedup vs baseline: 7.5866x; 1.0144x over previous
//
#include <hip/hip_runtime.h>
#include <math.h>

#define H 512
#define V 5000
#define BB 128
#define SS 64
#define TT 52
#define NB 160   // persistent grid size

typedef __attribute__((ext_vector_type(8))) short bf16x8;
typedef __attribute__((ext_vector_type(4))) float f32x4;
typedef __attribute__((ext_vector_type(2))) float f32x2;

__device__ __forceinline__ unsigned short f2b(float f) {
    unsigned u = __float_as_uint(f);
    return (unsigned short)((u + 0x7fffu + ((u >> 16) & 1u)) >> 16);
}
__device__ __forceinline__ float b2f(unsigned short u) {
    return __uint_as_float((unsigned)u << 16);
}
__device__ __forceinline__ float ftanh(float x) {
    return 1.f - 2.f / (1.f + __expf(2.f * x));
}
__device__ __forceinline__ float fsig(float x) {
    return 1.f / (1.f + __expf(-x));
}
__device__ __forceinline__ unsigned char f2fp8(float f) {
    return (unsigned char)__builtin_amdgcn_cvt_pk_fp8_f32(f, f, 0, 0);
}

// ---------------------------------------------------------------------------
// Coherent (L1/L2-bypassing, L3-coherence-point) accesses; validated r4-r8.
// _nw variant issues without waiting -- MUST be followed by a waiting variant
// plus sched_barrier(0) before any consumer (MFMA hoist hazard, guide #18).
// ---------------------------------------------------------------------------
#define CLD16_BODY \
        "global_load_dwordx4 %0, %16, off sc0 sc1\n\t"              \
        "global_load_dwordx4 %1, %16, off offset:64 sc0 sc1\n\t"    \
        "global_load_dwordx4 %2, %16, off offset:128 sc0 sc1\n\t"   \
        "global_load_dwordx4 %3, %16, off offset:192 sc0 sc1\n\t"   \
        "global_load_dwordx4 %4, %16, off offset:256 sc0 sc1\n\t"   \
        "global_load_dwordx4 %5, %16, off offset:320 sc0 sc1\n\t"   \
        "global_load_dwordx4 %6, %16, off offset:384 sc0 sc1\n\t"   \
        "global_load_dwordx4 %7, %16, off offset:448 sc0 sc1\n\t"   \
        "global_load_dwordx4 %8, %16, off offset:512 sc0 sc1\n\t"   \
        "global_load_dwordx4 %9, %16, off offset:576 sc0 sc1\n\t"   \
        "global_load_dwordx4 %10, %16, off offset:640 sc0 sc1\n\t"  \
        "global_load_dwordx4 %11, %16, off offset:704 sc0 sc1\n\t"  \
        "global_load_dwordx4 %12, %16, off offset:768 sc0 sc1\n\t"  \
        "global_load_dwordx4 %13, %16, off offset:832 sc0 sc1\n\t"  \
        "global_load_dwordx4 %14, %16, off offset:896 sc0 sc1\n\t"  \
        "global_load_dwordx4 %15, %16, off offset:960 sc0 sc1"
#define CLD16_OUTS(r) \
          "=v"(r[0]), "=v"(r[1]), "=v"(r[2]), "=v"(r[3]),   \
          "=v"(r[4]), "=v"(r[5]), "=v"(r[6]), "=v"(r[7]),   \
          "=v"(r[8]), "=v"(r[9]), "=v"(r[10]), "=v"(r[11]), \
          "=v"(r[12]), "=v"(r[13]), "=v"(r[14]), "=v"(r[15])

__device__ __forceinline__ void cld_row16_nw(const unsigned short* p, bf16x8* r)
{
    asm volatile(CLD16_BODY : CLD16_OUTS(r) : "v"(p) : "memory");
}
__device__ __forceinline__ void cld_row16(const unsigned short* p, bf16x8* r)
{
    asm volatile(CLD16_BODY "\n\ts_waitcnt vmcnt(0)"
                 : CLD16_OUTS(r) : "v"(p) : "memory");
}
__device__ __forceinline__ void cld_f_2(const float* p0, const float* p1,
                                        float& a, float& b)
{
    asm volatile(
        "global_load_dword %0, %2, off sc0 sc1\n\t"
        "global_load_dword %1, %3, off sc0 sc1\n\t"
        "s_waitcnt vmcnt(0)"
        : "=v"(a), "=v"(b) : "v"(p0), "v"(p1) : "memory");
}
__device__ __forceinline__ void cld_f4p(const float* p, f32x4& a, f32x4& b)
{
    asm volatile(
        "global_load_dwordx4 %0, %2, off sc0 sc1\n\t"
        "global_load_dwordx4 %1, %2, off offset:16 sc0 sc1\n\t"
        "s_waitcnt vmcnt(0)"
        : "=v"(a), "=v"(b) : "v"(p) : "memory");
}
__device__ __forceinline__ void cst_f(float* p, float v)
{
    asm volatile("global_store_dword %0, %1, off sc0 sc1"
                 :: "v"(p), "v"(v) : "memory");
}
__device__ __forceinline__ void cst_u32(unsigned* p, unsigned v)
{
    asm volatile("global_store_dword %0, %1, off sc0 sc1"
                 :: "v"(p), "v"(v) : "memory");
}
__device__ __forceinline__ void cst_h(unsigned short* p, unsigned short v)
{
    unsigned vv = v;
    asm volatile("global_store_short %0, %1, off sc0 sc1"
                 :: "v"(p), "v"(vv) : "memory");
}

// ---------------------------------------------------------------------------
// prep kernels (unchanged from round 8)
// ---------------------------------------------------------------------------
__global__ __launch_bounds__(256)
void prep_w(const float* __restrict__ Wa, const float* __restrict__ Whh,
            const float* __restrict__ Wih,
            const float* __restrict__ ba, const float* __restrict__ bih,
            const float* __restrict__ bhh,
            const float* __restrict__ Ua, const float* __restrict__ Wout,
            const float* __restrict__ enc,
            unsigned short* __restrict__ Wbig, unsigned short* __restrict__ Wc,
            unsigned short* __restrict__ Uab, unsigned short* __restrict__ Woutb,
            unsigned short* __restrict__ encb, float* __restrict__ bbig)
{
    const int stride = gridDim.x * blockDim.x;
    const int t0 = blockIdx.x * blockDim.x + threadIdx.x;
    for (int idx = t0; idx < 2560 * 1024; idx += stride) {
        const int j = idx >> 10, k = idx & 1023;
        float v;
        if (j < H) v = (k < H) ? Wa[j * H + k] : 0.f;
        else { const int n = j - H; v = (k < H) ? Whh[n * H + k] : Wih[n * 2 * H + (k - H)]; }
        Wbig[idx] = f2b(v);
    }
    for (int idx = t0; idx < 2048 * 512; idx += stride) {
        const int n = idx >> 9, k = idx & 511;
        Wc[idx] = f2b(Wih[n * 2 * H + H + k]);
    }
    for (int idx = t0; idx < 512 * 512; idx += stride)   Uab[idx]   = f2b(Ua[idx]);
    for (int idx = t0; idx < V * 512; idx += stride)     Woutb[idx] = f2b(Wout[idx]);
    for (int idx = t0; idx < BB * SS * H; idx += stride) encb[idx]  = f2b(enc[idx]);
    for (int j = t0; j < 2560; j += stride)
        bbig[j] = (j < H) ? ba[j] : bih[j - H] + bhh[j - H];
}

__global__ __launch_bounds__(256)
void gather_x(const float* __restrict__ emb, const int* __restrict__ tgt,
              unsigned short* __restrict__ xall)
{
    const int stride = gridDim.x * blockDim.x;
    for (int idx = blockIdx.x * blockDim.x + threadIdx.x; idx < TT * BB * H; idx += stride) {
        const int k = idx & 511;
        const int row = idx >> 9;
        const int t = row >> 7, b = row & 127;
        const int tok = (t == 0) ? 0 : tgt[b * TT + t - 1];
        xall[idx] = f2b(emb[(size_t)tok * H + k]);
    }
}

// ---------------------------------------------------------------------------
// bf16 MFMA NT-GEMM, K=512 fixed (unchanged from round 8).
// ---------------------------------------------------------------------------
template<int OUT_MODE, int PERMUTE>
__global__ __launch_bounds__(256, 2)
void gemm_mfma(const unsigned short* __restrict__ A,
               const unsigned short* __restrict__ B,
               const float* __restrict__ bias,
               float* __restrict__ Cf, unsigned short* __restrict__ Cb,
               unsigned char* __restrict__ C8,
               int M, int N)
{
    __shared__ unsigned short As[128][72];
    __shared__ unsigned short Bs[128][72];
    const int tid = threadIdx.x;
    const int m0 = blockIdx.y * 128, n0 = blockIdx.x * 128;
    const int lane = tid & 63, wv = tid >> 6;
    const int qm = (wv >> 1) * 64, qn = (wv & 1) * 64;
    const int fr = lane & 15, fg = lane >> 4;
    f32x4 acc[4][4];
#pragma unroll
    for (int i = 0; i < 4; ++i)
#pragma unroll
        for (int j = 0; j < 4; ++j) acc[i][j] = (f32x4){0.f, 0.f, 0.f, 0.f};

    const int srow = tid >> 3, sc = (tid & 7) * 8;
    for (int k0 = 0; k0 < H; k0 += 64) {
#pragma unroll
        for (int u = 0; u < 4; ++u) {
            const int row = srow + u * 32;
            *(uint4*)&As[row][sc] = *(const uint4*)&A[(size_t)(m0 + row) * H + k0 + sc];
            int nr = n0 + row; if (nr > N - 1) nr = N - 1;
            *(uint4*)&Bs[row][sc] = *(const uint4*)&B[(size_t)nr * H + k0 + sc];
        }
        __syncthreads();
#pragma unroll
        for (int ks = 0; ks < 2; ++ks) {
            const int kk = ks * 32 + fg * 8;
            bf16x8 av[4], bv[4];
#pragma unroll
            for (int i = 0; i < 4; ++i) {
                av[i] = *(const bf16x8*)&As[qm + i * 16 + fr][kk];
                bv[i] = *(const bf16x8*)&Bs[qn + i * 16 + fr][kk];
            }
#pragma unroll
            for (int i = 0; i < 4; ++i)
#pragma unroll
                for (int j = 0; j < 4; ++j)
                    acc[i][j] = __builtin_amdgcn_mfma_f32_16x16x32_bf16(av[i], bv[j], acc[i][j], 0, 0, 0);
        }
        __syncthreads();
    }
#pragma unroll
    for (int i = 0; i < 4; ++i) {
        const int r0 = m0 + qm + i * 16 + fg * 4;
#pragma unroll
        for (int j = 0; j < 4; ++j) {
            const int col = n0 + qn + j * 16 + fr;
            if (col < N) {
                const float bi = bias ? bias[col] : 0.f;
#pragma unroll
                for (int v = 0; v < 4; ++v) {
                    const int r = r0 + v;
                    const float val = acc[i][j][v] + bi;
                    if (OUT_MODE == 1) {
                        Cb[(size_t)r * N + col] = f2b(val);
                    } else if (OUT_MODE == 2) {
                        C8[(size_t)r * N + col] = f2fp8(val);
                    } else {
                        const size_t orow = PERMUTE ? ((size_t)(r & (BB - 1)) * TT + (r >> 7))
                                                    : (size_t)r;
                        Cf[orow * (size_t)N + col] = val;
                    }
                }
            }
        }
    }
}

// ---------------------------------------------------------------------------
// Single-hop barrier primitives. flags[i*32] = block i's monotonic step.
// wait_flags: block-wide direct poll (trailing __syncthreads).
// wait_flags_wave32: WAVE-scope poll of 32 flags (lanes 0-31, lockstep
// reconvergence) -- lets each P1 wave start as soon as ITS h-producers are
// done instead of aggregating all-block skew.
// ---------------------------------------------------------------------------
__device__ __forceinline__ void signal_flag(unsigned* flags, unsigned step)
{
    __syncthreads();   // all my threads' phase stores drained
    if (threadIdx.x == 0)
        __hip_atomic_store(&flags[blockIdx.x * 32], step, __ATOMIC_RELAXED,
                           __HIP_MEMORY_SCOPE_AGENT);
}
__device__ __forceinline__ void wait_flags(unsigned* flags, int lo, int hi,
                                           unsigned step)
{
    for (int i = lo + (int)threadIdx.x; i < hi; i += 256) {
        while (__hip_atomic_load(&flags[i * 32], __ATOMIC_RELAXED,
                                 __HIP_MEMORY_SCOPE_AGENT) < step)
            __builtin_amdgcn_s_sleep(1);
    }
    __syncthreads();
}
__device__ __forceinline__ void wait_flags_wave32(unsigned* flags, int lo,
                                                  unsigned step)
{
    const int lane = threadIdx.x & 63;
    if (lane < 32) {
        while (__hip_atomic_load(&flags[(lo + lane) * 32], __ATOMIC_RELAXED,
                                 __HIP_MEMORY_SCOPE_AGENT) < step)
            __builtin_amdgcn_s_sleep(1);
    }
}

struct PParams {
    const float* h0;
    const float* c0;
    const unsigned short* keysb;  // [B*S][512] bf16 (read-only, L2-cached)
    const unsigned char* encW8;   // [B*S][2048] fp8 (read-only, L2-resident)
    const float* Va;
    const float* bv;
    const float* bbig;
    const unsigned short* Wbig;   // [2560][1024] bf16
    const unsigned short* xall;   // [T*B][512]   bf16 (read-only)
    unsigned short* hbf;          // [B][512] bf16   -- coherent (cross-block)
    float* Y;                     // [B][2560] f32   -- coherent (cross-block)
    unsigned short* hallb;        // [T*B][512] bf16 (consumed post-kernel)
    float* attn;                  // -> d_out attention block [B][T][S]
    float* out_h;
    float* out_c;
    unsigned* flags;
};

// ---------------------------------------------------------------------------
// Persistent recurrence kernel (160 blocks). Column remap:
//   blocks 128-159 -> qa cols 0-511 (no P2 duty => qa ready earliest)
//   blocks 0-127   -> gate cols 512+16*beta (P2 peers)
// Per step t (flag values: P1 sig = 2t+2, h sig = 2t+3):
//   per-WAVE wait on its 32 h-producer flags >= 2t+1  -> P1 -> signal 2t+2
//   P2 (blocks<128): wait qa flags[128,160) >= 2t+2 -> scores/softmax
//     -> wait gate flags[0,128) >= 2t+2 -> gates+LSTM -> signal 2t+3
// WAR on Y row b is safe: row b read only by P2 block b whose 2t+3 signal
// gates every wave that overwrites it (per-wave wait covers exactly that).
// ---------------------------------------------------------------------------
__global__ __launch_bounds__(256, 1)
void persist(PParams p)
{
    __shared__ unsigned short WA[16][1032];
    __shared__ float qa_s[H];
    __shared__ float va_s[H];
    __shared__ float part[SS][4];
    __shared__ float wbuf[SS];
    __shared__ float gbuf[4 * H];
    __shared__ float cs[H];

    const int tid  = threadIdx.x;
    const int beta = blockIdx.x;
    const int j0   = (beta < 128) ? (512 + beta * 16) : ((beta - 128) * 16);

    // ---- prologue: h0 -> bf16 (coherent), stage weight slice, init c ----
    for (int i = beta * 256 + tid; i < BB * H; i += NB * 256)
        cst_h(&p.hbf[i], f2b(p.h0[i]));
    for (int idx = tid; idx < 16 * 128; idx += 256) {
        const int r = idx >> 7, ch = idx & 127;
        *(uint4*)&WA[r][ch * 8] = *(const uint4*)&p.Wbig[(size_t)(j0 + r) * 1024 + ch * 8];
    }
    if (beta < 128) {
        for (int j = tid; j < H; j += 256) cs[j] = p.c0[beta * H + j];
        for (int i = tid; i < H; i += 256) va_s[i] = p.Va[i];
    }
    signal_flag(p.flags, 1);
    wait_flags(p.flags, 0, NB, 1);

    for (int t = 0; t < TT; ++t) {
        const unsigned sp1 = 2 * t + 2;   // P1-done value
        const unsigned sh  = 2 * t + 3;   // h-done value
        // ---------------- P1: Y[b][j0..j0+15] for all b ----------------
        {
            const int wv = tid >> 6, lane = tid & 63;
            const int r = lane & 15, g = lane >> 4;
            const int b0 = wv * 32, b1 = b0 + 16;
            const int ko = g * 8;
            // gate only on MY wave's 32 h-producers (blocks b0..b0+31)
            wait_flags_wave32(p.flags, b0, sp1 - 1);
            bf16x8 hr0[16], hr1[16];
            cld_row16_nw(p.hbf + (size_t)(b0 + r) * H + ko, hr0);
            cld_row16  (p.hbf + (size_t)(b1 + r) * H + ko, hr1);
            __builtin_amdgcn_sched_barrier(0);   // MFMA hoist fence (rule #18)
            f32x4 acc0 = {0.f, 0.f, 0.f, 0.f};
            f32x4 acc1 = {0.f, 0.f, 0.f, 0.f};
#pragma unroll
            for (int ks = 0; ks < 16; ++ks) {
                bf16x8 bf = *(const bf16x8*)&WA[r][ks * 32 + ko];
                acc0 = __builtin_amdgcn_mfma_f32_16x16x32_bf16(hr0[ks], bf, acc0, 0, 0, 0);
                acc1 = __builtin_amdgcn_mfma_f32_16x16x32_bf16(hr1[ks], bf, acc1, 0, 0, 0);
            }
            const unsigned short* x0p = p.xall + ((size_t)t * BB + b0 + r) * H + ko;
            const unsigned short* x1p = p.xall + ((size_t)t * BB + b1 + r) * H + ko;
#pragma unroll
            for (int ks = 0; ks < 16; ++ks) {
                bf16x8 bf = *(const bf16x8*)&WA[r][512 + ks * 32 + ko];
                acc0 = __builtin_amdgcn_mfma_f32_16x16x32_bf16(*(const bf16x8*)&x0p[ks * 32], bf, acc0, 0, 0, 0);
                acc1 = __builtin_amdgcn_mfma_f32_16x16x32_bf16(*(const bf16x8*)&x1p[ks * 32], bf, acc1, 0, 0, 0);
            }
            const float bb = p.bbig[j0 + r];
#pragma unroll
            for (int i = 0; i < 4; ++i) {
                cst_f(p.Y + (size_t)(b0 + g * 4 + i) * 2560 + j0 + r, acc0[i] + bb);
                cst_f(p.Y + (size_t)(b1 + g * 4 + i) * 2560 + j0 + r, acc1[i] + bb);
            }
        }
        signal_flag(p.flags, sp1);

        // ------- P2: attention + ctx-gates + LSTM for batch b = beta -------
        if (beta < 128) {
            const int b = beta;
            const float* yrow = p.Y + (size_t)b * 2560;
            wait_flags(p.flags, 128, NB, sp1);       // qa producers (dedicated)
            cld_f_2(yrow + tid, yrow + 256 + tid, qa_s[tid], qa_s[tid + 256]);
            __syncthreads();
            // scores (2-way ILP on the serial FMA/tanh chain)
            const int s = tid >> 2, q = tid & 3;
            const unsigned short* kp = p.keysb + ((size_t)b * SS + s) * H + q * 128;
            const float* qp = qa_s + q * 128;
            const float* vp = va_s + q * 128;
            float a2 = 0.f, a2b = 0.f;
#pragma unroll 4
            for (int i = 0; i < 128; i += 2) {
                a2  += ftanh(qp[i] + b2f(kp[i])) * vp[i];
                a2b += ftanh(qp[i + 1] + b2f(kp[i + 1])) * vp[i + 1];
            }
            part[s][q] = a2 + a2b;
            __syncthreads();
            if (tid < 64) {
                float sc = part[tid][0] + part[tid][1] + part[tid][2] + part[tid][3] + p.bv[0];
                float m = sc;
                for (int o = 32; o; o >>= 1) m = fmaxf(m, __shfl_xor(m, o));
                const float e = __expf(sc - m);
                float ss = e;
                for (int o = 32; o; o >>= 1) ss += __shfl_xor(ss, o);
                const float w = e / ss;
                wbuf[tid] = w;
                p.attn[((size_t)b * TT + t) * SS + tid] = w;
            }
            wait_flags(p.flags, 0, 128, sp1);        // gate producers (peers)
            // gates_ctx via fp8 encW weighted sum; 8 n per thread
            {
                float gc[8] = {0.f, 0.f, 0.f, 0.f, 0.f, 0.f, 0.f, 0.f};
                const unsigned char* ew = p.encW8 + (size_t)b * SS * 2048 + tid * 8;
#pragma unroll 8
                for (int s2 = 0; s2 < SS; ++s2) {
                    const float w2 = wbuf[s2];
                    const uint2 u = *(const uint2*)(ew + (size_t)s2 * 2048);
                    const f32x2 e01 = __builtin_amdgcn_cvt_pk_f32_fp8(u.x, 0);
                    const f32x2 e23 = __builtin_amdgcn_cvt_pk_f32_fp8(u.x, 1);
                    const f32x2 e45 = __builtin_amdgcn_cvt_pk_f32_fp8(u.y, 0);
                    const f32x2 e67 = __builtin_amdgcn_cvt_pk_f32_fp8(u.y, 1);
                    gc[0] += w2 * e01[0]; gc[1] += w2 * e01[1];
                    gc[2] += w2 * e23[0]; gc[3] += w2 * e23[1];
                    gc[4] += w2 * e45[0]; gc[5] += w2 * e45[1];
                    gc[6] += w2 * e67[0]; gc[7] += w2 * e67[1];
                }
                f32x4 y0, y1;
                cld_f4p(yrow + 512 + tid * 8, y0, y1);
#pragma unroll
                for (int i = 0; i < 4; ++i) {
                    gbuf[tid * 8 + i]     = gc[i] + y0[i];
                    gbuf[tid * 8 + 4 + i] = gc[4 + i] + y1[i];
                }
            }
            __syncthreads();
            // LSTM: cells 2*tid, 2*tid+1
            {
                const int last = (t == TT - 1);
                unsigned hpack = 0;
                float hn2[2], cn2[2];
#pragma unroll
                for (int u = 0; u < 2; ++u) {
                    const int j = tid * 2 + u;
                    const float ig = gbuf[j];
                    const float fg = gbuf[512 + j];
                    const float gg = gbuf[1024 + j];
                    const float og = gbuf[1536 + j];
                    const float co = cs[j];
                    const float cn = fsig(fg) * co + fsig(ig) * ftanh(gg);
                    const float hn = fsig(og) * ftanh(cn);
                    cs[j] = cn;
                    hn2[u] = hn; cn2[u] = cn;
                    hpack |= ((unsigned)f2b(hn)) << (16 * u);
                }
                cst_u32((unsigned*)&p.hbf[b * H + tid * 2], hpack);
                *(unsigned*)&p.hallb[((size_t)t * BB + b) * H + tid * 2] = hpack;
                if (last) {
#pragma unroll
                    for (int u = 0; u < 2; ++u) {
                        p.out_h[b * H + tid * 2 + u] = hn2[u];
                        p.out_c[b * H + tid * 2 + u] = cn2[u];
                    }
                }
            }
            signal_flag(p.flags, sh);
        }
    }
}

// ---------------------------------------------------------------------------
// In-place log-softmax over each row of 5000 logits.
// ---------------------------------------------------------------------------
__global__ __launch_bounds__(256)
void logsoftmax_rows(float* __restrict__ P)
{
    __shared__ float red[256];
    float* p = P + (size_t)blockIdx.x * V;
    const int tid = threadIdx.x;
    float m = -1e30f;
    for (int i = tid; i < V; i += 256) m = fmaxf(m, p[i]);
    red[tid] = m; __syncthreads();
    for (int sft = 128; sft; sft >>= 1) {
        if (tid < sft) red[tid] = fmaxf(red[tid], red[tid + sft]);
        __syncthreads();
    }
    m = red[0]; __syncthreads();
    float ssum = 0.f;
    for (int i = tid; i < V; i += 256) ssum += __expf(p[i] - m);
    red[tid] = ssum; __syncthreads();
    for (int sft = 128; sft; sft >>= 1) {
        if (tid < sft) red[tid] += red[tid + sft];
        __syncthreads();
    }
    const float lse = m + __logf(red[0]);
    for (int i = tid; i < V; i += 256) p[i] -= lse;
}

// ---------------------------------------------------------------------------
extern "C" void kernel_launch(void* const* d_in, const int* in_sizes, int n_in,
                              void* d_out, int out_size, void* d_ws, size_t ws_size,
                              hipStream_t stream)
{
    (void)in_sizes; (void)n_in; (void)out_size; (void)ws_size;
    const float* enc  = (const float*)d_in[0];
    const float* h0   = (const float*)d_in[1];
    const float* c0   = (const float*)d_in[2];
    const int*   tgt  = (const int*)  d_in[3];
    const float* emb  = (const float*)d_in[4];
    const float* Wa   = (const float*)d_in[5];
    const float* ba   = (const float*)d_in[6];
    const float* Ua   = (const float*)d_in[7];
    const float* bu   = (const float*)d_in[8];
    const float* Va   = (const float*)d_in[9];
    const float* bv   = (const float*)d_in[10];
    const float* Wih  = (const float*)d_in[11];
    const float* Whh  = (const float*)d_in[12];
    const float* bih  = (const float*)d_in[13];
    const float* bhh  = (const float*)d_in[14];
    const float* Wout = (const float*)d_in[15];
    const float* bout = (const float*)d_in[16];

    float* ws = (float*)d_ws;
    float* Y    = ws;                                      // 327,680 f32
    float* bbig = Y + 327680;                              // 2,560 f32
    unsigned* flags = (unsigned*)(bbig + 2560);            // 5,504 u32
    unsigned short* Wbig  = (unsigned short*)(flags + 5504);   // 2,621,440 u16
    unsigned short* Wc    = Wbig + 2621440;                // 1,048,576
    unsigned short* Uab   = Wc + 1048576;                  // 262,144
    unsigned short* Woutb = Uab + 262144;                  // 2,560,000
    unsigned short* encb  = Woutb + 2560000;               // 4,194,304
    unsigned short* keysb = encb + 4194304;                // 4,194,304
    unsigned short* xall  = keysb + 4194304;               // 3,407,872
    unsigned short* hallb = xall + 3407872;                // 3,407,872
    unsigned short* hbf   = hallb + 3407872;               // 65,536
    unsigned char*  encW8 = (unsigned char*)(hbf + 65536); // 16,777,216 u8

    float* out    = (float*)d_out;
    float* out_h  = out + (size_t)BB * TT * V;
    float* out_c  = out_h + BB * H;
    float* out_at = out_c + BB * H;

    hipMemsetAsync(flags, 0, 5504 * sizeof(unsigned), stream);

    prep_w<<<dim3(2048), dim3(256), 0, stream>>>(
        Wa, Whh, Wih, ba, bih, bhh, Ua, Wout, enc, Wbig, Wc, Uab, Woutb, encb, bbig);
    gather_x<<<dim3(512), dim3(256), 0, stream>>>(emb, tgt, xall);

    // keys_proj = enc @ Ua^T + bu  -> bf16 [8192,512]
    gemm_mfma<1, 0><<<dim3(4, 64), dim3(256), 0, stream>>>(
        encb, Uab, bu, nullptr, keysb, nullptr, BB * SS, H);
    // encW8 = enc @ Wc^T -> fp8 [8192,2048]  (L2-resident per-XCD slices)
    gemm_mfma<2, 0><<<dim3(16, 64), dim3(256), 0, stream>>>(
        encb, Wc, nullptr, nullptr, nullptr, encW8, BB * SS, 2048);

    PParams pp;
    pp.h0 = h0; pp.c0 = c0; pp.keysb = keysb; pp.encW8 = encW8;
    pp.Va = Va; pp.bv = bv; pp.bbig = bbig;
    pp.Wbig = Wbig; pp.xall = xall;
    pp.hbf = hbf; pp.Y = Y; pp.hallb = hallb;
    pp.attn = out_at; pp.out_h = out_h; pp.out_c = out_c;
    pp.flags = flags;
    persist<<<dim3(NB), dim3(256), 0, stream>>>(pp);

    // logits: hallb[6656,512] @ Woutb^T + bout -> out[b,t,:], then log-softmax
    gemm_mfma<0, 1><<<dim3(40, 52), dim3(256), 0, stream>>>(
        hallb, Woutb, bout, out, nullptr, nullptr, TT * BB, V);
    logsoftmax_rows<<<dim3(BB * TT), dim3(256), 0, stream>>>(out);
}